// Round 7
// baseline (965.526 us; speedup 1.0000x reference)
//
#include <hip/hip_runtime.h>
#include <cstdint>

// ---------------------------------------------------------------------------
// Problem constants
// ---------------------------------------------------------------------------
#define B_    128
#define CIN   1024
#define NPOS  196          // 14*14
#define DM    384
#define NH_   12
#define HD_   32
#define DFF_  1536
#define MT    25088        // B_*NPOS
#define SCALE_Q 0.17677669529663687f   // 1/sqrt(32)

typedef unsigned short u16;
typedef __attribute__((ext_vector_type(8))) short  short8;   // 8 bf16 (4 VGPR)
typedef __attribute__((ext_vector_type(4))) float  f32x4;    // MFMA C/D

__device__ __forceinline__ u16 f2bf(float f) {
  union { float f; uint32_t u; } v; v.f = f;
  uint32_t u = v.u;
  return (u16)((u + 0x7fffu + ((u >> 16) & 1u)) >> 16);
}
__device__ __forceinline__ float bf2f(u16 h) {
  union { uint32_t u; float f; } v; v.u = ((uint32_t)h) << 16;
  return v.f;
}

#define GLDS16(g, l)                                                           \
  __builtin_amdgcn_global_load_lds(                                            \
      (const __attribute__((address_space(1))) void*)(g),                      \
      (__attribute__((address_space(3))) void*)(l), 16, 0, 0)

// ---------------------------------------------------------------------------
// Generic bf16 MFMA GEMM:  out = epi( A[M x K] * W[N x K]^T )
// 128x128 tile, 4 waves (2x2 of 64x64), BK=64, 32 MFMA / K-step.
// MODE: 0 = bias+relu6 -> bf16   (fc1, mlp1)
//       1 = bias       -> f32    (fc2)
//       2 = plain      -> bf16   (qkv)
//       3 = bias+res   -> f32    (proj, mlp2)
//       4 = split-K partial -> f32 (lin head; W is f32, converted in staging)
// ---------------------------------------------------------------------------
template <int MODE>
__global__ __launch_bounds__(256) void gemm_k(
    const u16* __restrict__ A, const void* __restrict__ Wv,
    const float* __restrict__ bias, const float* __restrict__ res,
    void* __restrict__ outp,
    int M, int N, int K, int lda, int ldw, int nTN, int splitK)
{
  __shared__ __align__(16) u16 As[8 * 128 * 8];   // [s][r][8], s = k-slot (8 bf16)
  __shared__ __align__(16) u16 Bs[8 * 128 * 8];

  int bid = blockIdx.x;
  int split = 0, mT, nT;
  if (MODE == 4) { split = bid / nTN; nT = bid % nTN; mT = 0; }
  else           { mT = bid / nTN;    nT = bid % nTN; }

  const u16* Ab = A + (size_t)split * splitK;
  float* outF = (float*)outp + ((MODE == 4) ? (size_t)split * (size_t)M * N : (size_t)0);
  u16*   outU = (u16*)outp;

  int tid = threadIdx.x;
  int wv = tid >> 6, ln = tid & 63;
  int q = ln >> 4, c = ln & 15;
  int wr = wv >> 1, wc = wv & 1;
  int mBase = mT * 128, nBase = nT * 128;

  f32x4 acc[4][4];
#pragma unroll
  for (int i = 0; i < 4; i++)
#pragma unroll
    for (int j = 0; j < 4; j++) acc[i][j] = (f32x4){0.f, 0.f, 0.f, 0.f};

  const u16* Ag = Ab + (size_t)mBase * lda;
  const u16*  Wg16 = (const u16*)Wv + (size_t)split * splitK + (size_t)nBase * ldw;
  const float* Wg32 = (const float*)Wv + (size_t)split * splitK + (size_t)nBase * ldw;

  for (int k0 = 0; k0 < K; k0 += 64) {
    // ---- stage 16KB A-tile + 16KB W-tile (16 chunks each, 4/wave) ----
#pragma unroll
    for (int i = 0; i < 4; i++) {
      int ch = wv * 4 + i;             // chunk 0..15 (1024B each)
      int s = ch >> 1;                 // k-slot (8 bf16), 0..7
      int r = (ch & 1) * 64 + ln;      // tile row
      GLDS16(Ag + (size_t)r * lda + (k0 + s * 8), &As[ch * 512]);
      if constexpr (MODE == 4) {
        const float* wp = Wg32 + (size_t)r * ldw + (k0 + s * 8);
        float4 f0 = *(const float4*)wp, f1 = *(const float4*)(wp + 4);
        short8 pk;
        pk[0] = (short)f2bf(f0.x); pk[1] = (short)f2bf(f0.y);
        pk[2] = (short)f2bf(f0.z); pk[3] = (short)f2bf(f0.w);
        pk[4] = (short)f2bf(f1.x); pk[5] = (short)f2bf(f1.y);
        pk[6] = (short)f2bf(f1.z); pk[7] = (short)f2bf(f1.w);
        *(short8*)&Bs[ch * 512 + ln * 8] = pk;
      } else {
        GLDS16(Wg16 + (size_t)r * ldw + (k0 + s * 8), &Bs[ch * 512]);
      }
    }
    __syncthreads();
#pragma unroll
    for (int kk = 0; kk < 2; kk++) {
      short8 afr[4], bfr[4];
#pragma unroll
      for (int mt2 = 0; mt2 < 4; mt2++)
        afr[mt2] = *(const short8*)&As[(((kk * 4 + q) * 128) + wr * 64 + mt2 * 16 + c) * 8];
#pragma unroll
      for (int nt2 = 0; nt2 < 4; nt2++)
        bfr[nt2] = *(const short8*)&Bs[(((kk * 4 + q) * 128) + wc * 64 + nt2 * 16 + c) * 8];
#pragma unroll
      for (int mt2 = 0; mt2 < 4; mt2++)
#pragma unroll
        for (int nt2 = 0; nt2 < 4; nt2++)
          acc[mt2][nt2] = __builtin_amdgcn_mfma_f32_16x16x32_bf16(
              afr[mt2], bfr[nt2], acc[mt2][nt2], 0, 0, 0);
    }
    __syncthreads();
  }

  // ---- epilogue ----
#pragma unroll
  for (int mt2 = 0; mt2 < 4; mt2++) {
    int row0 = mBase + wr * 64 + mt2 * 16 + q * 4;
#pragma unroll
    for (int nt2 = 0; nt2 < 4; nt2++) {
      int col = nBase + wc * 64 + nt2 * 16 + c;
      float bv = (MODE == 0 || MODE == 1 || MODE == 3) ? bias[col] : 0.f;
      f32x4 v = acc[mt2][nt2];
#pragma unroll
      for (int e = 0; e < 4; e++) {
        int row = row0 + e;
        float x = v[e] + bv;
        if (MODE == 0) x = fminf(fmaxf(x, 0.f), 6.f);
        if (MODE == 3) x += res[(size_t)row * N + col];
        if (MODE == 0 || MODE == 2) outU[(size_t)row * N + col] = f2bf(x);
        else                        outF[(size_t)row * N + col] = x;
      }
    }
  }
}

// ---------------------------------------------------------------------------
// x (B, CIN, HW, HW) f32  ->  A_t (B*NPOS, CIN) bf16
// ---------------------------------------------------------------------------
__global__ __launch_bounds__(256) void transpose_cast_k(
    const float* __restrict__ x, u16* __restrict__ At)
{
  __shared__ float t[32][33];
  int c0 = blockIdx.x * 32, n0 = blockIdx.y * 32, b = blockIdx.z;
  int tx = threadIdx.x, ty = threadIdx.y;
  const float* xb = x + (size_t)b * CIN * NPOS;
#pragma unroll
  for (int i = 0; i < 4; i++) {
    int cc = c0 + ty + i * 8, nn = n0 + tx;
    t[ty + i * 8][tx] = (nn < NPOS) ? xb[(size_t)cc * NPOS + nn] : 0.f;
  }
  __syncthreads();
  u16* Ab = At + (size_t)b * NPOS * CIN;
#pragma unroll
  for (int i = 0; i < 4; i++) {
    int nn = n0 + ty + i * 8, cc = c0 + tx;
    if (nn < NPOS) Ab[(size_t)nn * CIN + cc] = f2bf(t[tx][ty + i * 8]);
  }
}

// ---------------------------------------------------------------------------
// depthwise 3x3 SAME conv + bias + identity residual (fp32)
// ---------------------------------------------------------------------------
__global__ __launch_bounds__(256) void conv_res_k(
    const float* __restrict__ T0, const float* __restrict__ pcw,
    const float* __restrict__ pcb, float* __restrict__ T1)
{
  int idx = blockIdx.x * 256 + threadIdx.x;
  if (idx >= B_ * NPOS * 96) return;
  int d4 = idx % 96; int rem = idx / 96;
  int n = rem % NPOS; int b = rem / NPOS;
  int hh = n / 14, ww = n % 14;
  int d0 = d4 * 4;
  float w9[4][9];
#pragma unroll
  for (int j = 0; j < 4; j++)
#pragma unroll
    for (int t = 0; t < 9; t++) w9[j][t] = pcw[(d0 + j) * 9 + t];
  const float* base = T0 + (size_t)b * NPOS * DM;
  float4 ctr = *(const float4*)(base + (size_t)n * DM + d0);
  float ax = ctr.x + pcb[d0], ay = ctr.y + pcb[d0 + 1];
  float az = ctr.z + pcb[d0 + 2], aw = ctr.w + pcb[d0 + 3];
#pragma unroll
  for (int kh = 0; kh < 3; kh++) {
    int h2 = hh + kh - 1;
    if (h2 < 0 || h2 >= 14) continue;
#pragma unroll
    for (int kw = 0; kw < 3; kw++) {
      int w2 = ww + kw - 1;
      if (w2 < 0 || w2 >= 14) continue;
      float4 v = *(const float4*)(base + (size_t)(h2 * 14 + w2) * DM + d0);
      int t = kh * 3 + kw;
      ax += v.x * w9[0][t]; ay += v.y * w9[1][t];
      az += v.z * w9[2][t]; aw += v.w * w9[3][t];
    }
  }
  float4 o = {ax, ay, az, aw};
  *(float4*)(T1 + (size_t)b * NPOS * DM + (size_t)n * DM + d0) = o;
}

// ---------------------------------------------------------------------------
// LayerNorm(384) f32 -> bf16, one wave per row (float2-vectorized)
// ---------------------------------------------------------------------------
__global__ __launch_bounds__(256) void ln_k(
    const float* __restrict__ in, const float* __restrict__ w,
    const float* __restrict__ bb, u16* __restrict__ out)
{
  int row = blockIdx.x * 4 + (threadIdx.x >> 6);
  int ln = threadIdx.x & 63;
  const float2* r = (const float2*)(in + (size_t)row * DM);
  float2 v[3]; float s = 0.f, sq = 0.f;
#pragma unroll
  for (int j = 0; j < 3; j++) {
    v[j] = r[ln + 64 * j];
    s += v[j].x + v[j].y; sq += v[j].x * v[j].x + v[j].y * v[j].y;
  }
#pragma unroll
  for (int o = 1; o < 64; o <<= 1) { s += __shfl_xor(s, o, 64); sq += __shfl_xor(sq, o, 64); }
  float mu = s * (1.f / 384.f);
  float var = sq * (1.f / 384.f) - mu * mu;
  float rs = rsqrtf(var + 1e-5f);
  uint32_t* orow = (uint32_t*)(out + (size_t)row * DM);
#pragma unroll
  for (int j = 0; j < 3; j++) {
    int d = (ln + 64 * j) * 2;
    float a = (v[j].x - mu) * rs * w[d] + bb[d];
    float bq = (v[j].y - mu) * rs * w[d + 1] + bb[d + 1];
    orow[ln + 64 * j] = (uint32_t)f2bf(a) | ((uint32_t)f2bf(bq) << 16);
  }
}

// ---------------------------------------------------------------------------
// Fused attention per (b,h), flash-style online softmax over 7 j-chunks of 32.
//   K staged once into LDS fragment layout Ks[4][196][8] via global_load_lds.
//   rpe table staged once into Ts[49][32]; scores via MFMA reusing Q A-frag.
//   Per chunk: 2 QK MFMA -> bias -> online max/sum rescale -> P chunk (1KB
//   per wave, A-frag layout) -> 2 PV MFMA. Only 2 score tiles live at once
//   -> VGPR well under the 128 wave-slot quantum.
// LDS = 12544(Ks) + 14848(Vt) + 4096(Pc) + 3136(Ts) + 6272(Rw) = 40896 B
//   -> padded 40960 -> 4 blocks/CU (163840 = exactly the 160 KiB pool).
// ---------------------------------------------------------------------------
__global__ __launch_bounds__(256, 4) void attn_k(
    const u16* __restrict__ QKV, const float* __restrict__ tabG,
    u16* __restrict__ AO)
{
  __shared__ __align__(16) u16 Ks[4 * 196 * 8];     // [s][j][e] K fragments
  __shared__ __align__(16) u16 Vt[32 * 232];        // [d][j], pad j>=196 zero
  __shared__ __align__(16) u16 Pc4[4][4 * 16 * 8];  // per-wave P chunk (16x32)
  __shared__ __align__(16) u16 Ts[49 * 32];         // rpe table, [t][k] bf16
  __shared__ __align__(16) u16 Rw4[4][16 * 49];     // per-wave rpe scores bf16
  int bh = blockIdx.x; int b = bh / NH_, h = bh % NH_;
  int tid = threadIdx.x;
  int wv = tid >> 6, ln = tid & 63;
  int q = ln >> 4, c = ln & 15;
  size_t rowbase = (size_t)b * NPOS * 1152 + h * 32;

  // ---- stage K fragments via global_load_lds (wave-uniform dest) ----
  for (int cb = wv * 64; cb < 784; cb += 256) {
    int ch = cb + ln;
    if (ch < 784) {
      int s = ch / 196, j = ch - s * 196;
      GLDS16(QKV + rowbase + 384 + (size_t)j * 1152 + s * 8, &Ks[cb * 8]);
    }
  }
  // ---- stage rpe table transposed to [t][k] bf16 (once per block) ----
  for (int t = tid; t < 49 * 32; t += 256) {
    int tt = t >> 5, k = t & 31;
    Ts[t] = f2bf(tabG[k * 49 + tt]);
  }
  // ---- stage V transposed (vectorized): 784 chunks of 8 d-values ----
  for (int t = tid; t < 784; t += 256) {
    int nn = t >> 2, d0 = (t & 3) * 8;
    short8 v = *(const short8*)(QKV + rowbase + 768 + (size_t)nn * 1152 + d0);
#pragma unroll
    for (int j = 0; j < 8; j++) Vt[(d0 + j) * 232 + nn] = (u16)v[j];
  }
  for (int t = tid; t < 32 * 36; t += 256) {
    int d = t / 36, jj = t - d * 36;
    Vt[d * 232 + 196 + jj] = 0;
  }
  __syncthreads();

  u16* Pw = Pc4[wv];
  u16* Rw = Rw4[wv];

  for (int mt = wv; mt < 13; mt += 4) {
    int mb = mt * 16;
    int irow = mb + c; if (irow > 195) irow = 195;
    short8 afrag = *(const short8*)(QKV + rowbase + (size_t)irow * 1152 + q * 8);
    int i0 = mb + q * 4;

    // ---- rpe scores via MFMA -> Rw (table frags transient from LDS) ----
#pragma unroll
    for (int nt = 0; nt < 4; nt++) {
      int t = nt * 16 + c;
      int tt = t < 49 ? t : 48;
      short8 tb = *(const short8*)&Ts[tt * 32 + q * 8];
      f32x4 z = {0.f, 0.f, 0.f, 0.f};
      f32x4 rr = __builtin_amdgcn_mfma_f32_16x16x32_bf16(afrag, tb, z, 0, 0, 0);
      if (t < 49) {
#pragma unroll
        for (int e = 0; e < 4; e++)
          Rw[(q * 4 + e) * 49 + t] = f2bf(rr[e] * SCALE_Q);
      }
    }

    // row geometry (hoisted)
    int ri4[4], ci4[4];
#pragma unroll
    for (int e = 0; e < 4; e++) {
      int i = i0 + e; int ri = i / 14;
      ri4[e] = ri; ci4[e] = i - ri * 14;
    }

    float m[4], l[4];
    f32x4 oacc[2];
#pragma unroll
    for (int e = 0; e < 4; e++) { m[e] = -INFINITY; l[e] = 0.f; }
    oacc[0] = (f32x4){0.f, 0.f, 0.f, 0.f};
    oacc[1] = (f32x4){0.f, 0.f, 0.f, 0.f};

    // ---- online softmax over 7 chunks of 32 j ----
#pragma unroll 2
    for (int ck = 0; ck < 7; ck++) {
      // 2 QK MFMAs from Ks LDS
      f32x4 s01[2];
#pragma unroll
      for (int t = 0; t < 2; t++) {
        int j = (ck * 2 + t) * 16 + c;
        int jc = j > 195 ? 195 : j;
        short8 bfrag = *(const short8*)&Ks[(q * 196 + jc) * 8];
        f32x4 z = {0.f, 0.f, 0.f, 0.f};
        s01[t] = __builtin_amdgcn_mfma_f32_16x16x32_bf16(afrag, bfrag, z, 0, 0, 0);
      }
      // bias + mask
#pragma unroll
      for (int t = 0; t < 2; t++) {
        int j = (ck * 2 + t) * 16 + c;
        bool jok = (j < 196);
        int rj = j / 14, cj = j - rj * 14;
#pragma unroll
        for (int e = 0; e < 4; e++) {
          float sv = -1e30f;
          if (jok && (i0 + e) < 196) {
            int dr = ri4[e] - rj, dc = ci4[e] - cj;
            int adr = dr < 0 ? -dr : dr, adc = dc < 0 ? -dc : dc;
            int tr = adr <= 1 ? adr : (adr <= 3 ? 2 : 3);
            int tc = adc <= 1 ? adc : (adc <= 3 ? 2 : 3);
            int fr = dr < 0 ? -tr : tr, fc = dc < 0 ? -tc : tc;
            int bucket = fr * 7 + fc + 24;
            sv = s01[t][e] * SCALE_Q + bf2f(Rw[(q * 4 + e) * 49 + bucket]);
          }
          s01[t][e] = sv;
        }
      }
      // chunk max (16-lane group reduce) + online update
#pragma unroll
      for (int e = 0; e < 4; e++) {
        float mc = fmaxf(s01[0][e], s01[1][e]);
#pragma unroll
        for (int o = 1; o < 16; o <<= 1) mc = fmaxf(mc, __shfl_xor(mc, o, 64));
        float mn = fmaxf(m[e], mc);
        float sc = __expf(m[e] - mn);
        m[e] = mn;
        float p0 = __expf(s01[0][e] - mn);
        float p1 = __expf(s01[1][e] - mn);
        l[e] = l[e] * sc + p0 + p1;
        oacc[0][e] *= sc; oacc[1][e] *= sc;
        s01[0][e] = p0; s01[1][e] = p1;
      }
      // write P chunk in A-frag layout: slot = t*2 + (c>>3), row q*4+e, col c&7
#pragma unroll
      for (int t = 0; t < 2; t++) {
        int sl = t * 2 + (c >> 3);
#pragma unroll
        for (int e = 0; e < 4; e++)
          Pw[(sl * 16 + q * 4 + e) * 8 + (c & 7)] = f2bf(s01[t][e]);
      }
      // PV: 2 MFMAs (d halves), k = this chunk's 32 j
#pragma unroll
      for (int n2 = 0; n2 < 2; n2++) {
        short8 pa = *(const short8*)&Pw[(q * 16 + c) * 8];
        short8 vb = *(const short8*)&Vt[(n2 * 16 + c) * 232 + ck * 32 + q * 8];
        oacc[n2] = __builtin_amdgcn_mfma_f32_16x16x32_bf16(pa, vb, oacc[n2], 0, 0, 0);
      }
    }

    // final 1/l and store
    float inv[4];
#pragma unroll
    for (int e = 0; e < 4; e++) {
      float s2 = l[e];
#pragma unroll
      for (int o = 1; o < 16; o <<= 1) s2 += __shfl_xor(s2, o, 64);
      inv[e] = 1.f / s2;
    }
#pragma unroll
    for (int n2 = 0; n2 < 2; n2++) {
#pragma unroll
      for (int e = 0; e < 4; e++) {
        int i = i0 + e;
        if (i < 196) {
          int d = n2 * 16 + c;
          AO[((size_t)b * NPOS + i) * DM + h * 32 + d] = f2bf(oacc[n2][e] * inv[e]);
        }
      }
    }
  }
}

// ---------------------------------------------------------------------------
// BN1 over (batch, dmodel) per position n: two-stage stats
// ---------------------------------------------------------------------------
__global__ __launch_bounds__(256) void bn1_partial_k(
    const float* __restrict__ T3, float* __restrict__ part)
{
  int n = blockIdx.x >> 3, g = blockIdx.x & 7;
  int tid = threadIdx.x;
  float s = 0.f, sq = 0.f;
  for (int b2 = g * 16; b2 < g * 16 + 16; b2++) {
    const float* p = T3 + ((size_t)b2 * NPOS + n) * DM;
    for (int d = tid; d < DM; d += 256) { float v = p[d]; s += v; sq += v * v; }
  }
#pragma unroll
  for (int o = 1; o < 64; o <<= 1) { s += __shfl_xor(s, o, 64); sq += __shfl_xor(sq, o, 64); }
  __shared__ float ls[4], lq[4];
  int wv = tid >> 6, ln = tid & 63;
  if (ln == 0) { ls[wv] = s; lq[wv] = sq; }
  __syncthreads();
  if (tid == 0) {
    part[blockIdx.x * 2]     = ls[0] + ls[1] + ls[2] + ls[3];
    part[blockIdx.x * 2 + 1] = lq[0] + lq[1] + lq[2] + lq[3];
  }
}

__global__ __launch_bounds__(256) void bn1_finish_k(
    const float* __restrict__ part, const float* __restrict__ bw,
    const float* __restrict__ bbb, float* __restrict__ scaleArr,
    float* __restrict__ shiftArr)
{
  int n = threadIdx.x;
  if (n >= NPOS) return;
  float S = 0.f, Q = 0.f;
#pragma unroll
  for (int g = 0; g < 8; g++) { S += part[(n * 8 + g) * 2]; Q += part[(n * 8 + g) * 2 + 1]; }
  float mu = S / 49152.f;
  float var = Q / 49152.f - mu * mu;
  float rs = rsqrtf(var + 2e-5f);
  float sc = rs * bw[n];
  scaleArr[n] = sc;
  shiftArr[n] = bbb[n] - mu * sc;
}

__global__ __launch_bounds__(256) void bn1_apply_k(
    const float* __restrict__ T3, const float* __restrict__ scaleArr,
    const float* __restrict__ shiftArr, u16* __restrict__ outb)
{
  int idx = blockIdx.x * 256 + threadIdx.x;           // float4 index
  if (idx >= MT * DM / 4) return;
  int n = (idx / 96) % NPOS;
  float4 v = *(const float4*)(T3 + (size_t)idx * 4);
  float sc = scaleArr[n], sh = shiftArr[n];
  uint32_t p0 = (uint32_t)f2bf(v.x * sc + sh) | ((uint32_t)f2bf(v.y * sc + sh) << 16);
  uint32_t p1 = (uint32_t)f2bf(v.z * sc + sh) | ((uint32_t)f2bf(v.w * sc + sh) << 16);
  ((uint2*)outb)[idx] = make_uint2(p0, p1);
}

// ---------------------------------------------------------------------------
// split-K reduce for lin head + bias
// ---------------------------------------------------------------------------
__global__ __launch_bounds__(256) void lin_reduce_k(
    const float* __restrict__ part, const float* __restrict__ lb,
    float* __restrict__ y)
{
  int idx = blockIdx.x * 256 + threadIdx.x;
  if (idx >= 128 * DM) return;
  int col = idx % DM;
  float s = lb[col];
#pragma unroll
  for (int sp = 0; sp < 49; sp++) s += part[(size_t)sp * (128 * DM) + idx];
  y[idx] = s;
}

// ---------------------------------------------------------------------------
// BN2 over batch (128) per feature col, in-place on y
// ---------------------------------------------------------------------------
__global__ __launch_bounds__(64) void bn2_k(
    float* __restrict__ y, const float* __restrict__ w,
    const float* __restrict__ bb)
{
  int col = blockIdx.x; int ln = threadIdx.x;
  float v0 = y[(size_t)ln * DM + col];
  float v1 = y[(size_t)(ln + 64) * DM + col];
  float s = v0 + v1, sq = v0 * v0 + v1 * v1;
#pragma unroll
  for (int o = 1; o < 64; o <<= 1) { s += __shfl_xor(s, o, 64); sq += __shfl_xor(sq, o, 64); }
  float mu = s / 128.f;
  float var = sq / 128.f - mu * mu;
  float rs = rsqrtf(var + 2e-5f);
  float sc = rs * w[col], sh = bb[col] - mu * sc;
  y[(size_t)ln * DM + col] = v0 * sc + sh;
  y[(size_t)(ln + 64) * DM + col] = v1 * sc + sh;
}

// ---------------------------------------------------------------------------
// merged f32 -> bf16 cast for the six small weight matrices
// segment boundaries in float4 units
// ---------------------------------------------------------------------------
__global__ __launch_bounds__(256) void castall_k(
    const float* __restrict__ s0, u16* __restrict__ d0,
    const float* __restrict__ s1, u16* __restrict__ d1,
    const float* __restrict__ s2, u16* __restrict__ d2,
    const float* __restrict__ s3, u16* __restrict__ d3,
    const float* __restrict__ s4, u16* __restrict__ d4,
    const float* __restrict__ s5, u16* __restrict__ d5)
{
  const int b0 = 262144, b1 = b0 + 98304, b2 = b1 + 110592,
            b3 = b2 + 36864, b4 = b3 + 147456, b5 = b4 + 147456; // 802816
  int idx = blockIdx.x * 256 + threadIdx.x;
  int stride = gridDim.x * 256;
  for (; idx < b5; idx += stride) {
    const float* s; u16* d; int l;
    if      (idx < b0) { s = s0; d = d0; l = idx; }
    else if (idx < b1) { s = s1; d = d1; l = idx - b0; }
    else if (idx < b2) { s = s2; d = d2; l = idx - b1; }
    else if (idx < b3) { s = s3; d = d3; l = idx - b2; }
    else if (idx < b4) { s = s4; d = d4; l = idx - b3; }
    else               { s = s5; d = d5; l = idx - b4; }
    float4 v = *(const float4*)(s + (size_t)l * 4);
    uint32_t p0 = (uint32_t)f2bf(v.x) | ((uint32_t)f2bf(v.y) << 16);
    uint32_t p1 = (uint32_t)f2bf(v.z) | ((uint32_t)f2bf(v.w) << 16);
    ((uint2*)d)[l] = make_uint2(p0, p1);
  }
}

// ---------------------------------------------------------------------------
// Orchestration
// ---------------------------------------------------------------------------
extern "C" void kernel_launch(void* const* d_in, const int* in_sizes, int n_in,
                              void* d_out, int out_size, void* d_ws, size_t ws_size,
                              hipStream_t stream)
{
  (void)in_sizes; (void)n_in; (void)out_size;
  const float* x    = (const float*)d_in[0];
  const float* fc1w = (const float*)d_in[1];
  const float* fc1b = (const float*)d_in[2];
  const float* fc2w = (const float*)d_in[3];
  const float* fc2b = (const float*)d_in[4];
  const float* pcw  = (const float*)d_in[5];
  const float* pcb  = (const float*)d_in[6];
  const float* ln1w = (const float*)d_in[7];
  const float* ln1b = (const float*)d_in[8];
  const float* qkvw = (const float*)d_in[9];
  const float* rpet = (const float*)d_in[10];
  const float* projw= (const float*)d_in[11];
  const float* projb= (const float*)d_in[12];
  const float* ln2w = (const float*)d_in[13];
  const float* ln2b = (const float*)d_in[14];
  const float* m1w  = (const float*)d_in[15];
  const float* m1b  = (const float*)d_in[16];
  const float* m2w  = (const float*)d_in[17];
  const float* m2b  = (const float*)d_in[18];
  const float* bn1w = (const float*)d_in[19];
  const float* bn1b = (const float*)d_in[20];
  const float* linw = (const float*)d_in[21];
  const float* linb = (const float*)d_in[22];
  const float* bn2w = (const float*)d_in[23];
  const float* bn2b = (const float*)d_in[24];
  float* y = (float*)d_out;

  // -------- aliased workspace layout (regions share by liveness) ----------
  const size_t RA = 0;                      // At / MLP1
  const size_t RB = 77070336;               // U / QKV / T3nb
  const size_t RC = RB + 57802752;          // H / AO / H2
  const size_t RD = RC + 19267584;          // T0 / T2
  const size_t RE = RD + 38535168;          // T1 / T3
  const size_t RF = RE + 38535168;          // PART (lin split-K)
  const size_t RG = RF + 9633792;           // small bf16 weights
  const size_t RS = RG + 6422528;           // bn1 scale/shift + partials
  const size_t NEED = RS + 2048 + 16384;
  if (ws_size < NEED) return;

  char* ws = (char*)d_ws;
  u16*   At    = (u16*)(ws + RA);
  u16*   MLP1  = (u16*)(ws + RA);
  u16*   U     = (u16*)(ws + RB);
  u16*   QKV   = (u16*)(ws + RB);
  u16*   T3nb  = (u16*)(ws + RB);
  u16*   H     = (u16*)(ws + RC);
  u16*   AO    = (u16*)(ws + RC);
  u16*   H2    = (u16*)(ws + RC);
  float* T0    = (float*)(ws + RD);
  float* T2    = (float*)(ws + RD);
  float* T1    = (float*)(ws + RE);
  float* T3    = (float*)(ws + RE);
  float* PART  = (float*)(ws + RF);
  u16*   wb_fc1 = (u16*)(ws + RG);
  u16*   wb_fc2 = wb_fc1 + 1048576;
  u16*   wb_qkv = wb_fc2 + 393216;
  u16*   wb_proj= wb_qkv + 442368;
  u16*   wb_m1  = wb_proj + 147456;
  u16*   wb_m2  = wb_m1 + 589824;
  float* bnS   = (float*)(ws + RS);
  float* bnSh  = bnS + 196;
  float* bnP   = (float*)(ws + RS + 2048);

  // weight casts (f32 -> bf16), one merged kernel
  castall_k<<<1024, 256, 0, stream>>>(fc1w, wb_fc1, fc2w, wb_fc2, qkvw, wb_qkv,
                                      projw, wb_proj, m1w, wb_m1, m2w, wb_m2);

  // x (B,CIN,N) -> At (B*N, CIN) bf16
  transpose_cast_k<<<dim3(32, 7, 128), dim3(32, 8), 0, stream>>>(x, At);

  // embed fc1: U = relu6(At @ fc1w^T + b)   [25088 x 1024]
  gemm_k<0><<<196 * 8, 256, 0, stream>>>(At, wb_fc1, fc1b, nullptr, U,
                                          MT, 1024, 1024, 1024, 1024, 8, 0);
  // embed fc2: T0 = U @ fc2w^T + b          [25088 x 384] f32
  gemm_k<1><<<196 * 3, 256, 0, stream>>>(U, wb_fc2, fc2b, nullptr, T0,
                                          MT, 384, 1024, 1024, 1024, 3, 0);
  // depthwise conv + bias + residual -> T1
  conv_res_k<<<(B_ * NPOS * 96 + 255) / 256, 256, 0, stream>>>(T0, pcw, pcb, T1);
  // LN1 -> H (bf16)
  ln_k<<<MT / 4, 256, 0, stream>>>(T1, ln1w, ln1b, H);
  // qkv: QKV = H @ qkvw^T (no bias)          [25088 x 1152] bf16
  gemm_k<2><<<196 * 9, 256, 0, stream>>>(H, wb_qkv, nullptr, nullptr, QKV,
                                          MT, 1152, 384, 384, 384, 9, 0);
  // fused attention (rpe in-kernel, flash-style) -> AO (bf16)
  attn_k<<<1536, 256, 0, stream>>>(QKV, rpet, AO);
  // proj + residual(T1) -> T2 (f32)
  gemm_k<3><<<196 * 3, 256, 0, stream>>>(AO, wb_proj, projb, T1, T2,
                                          MT, 384, 384, 384, 384, 3, 0);
  // LN2 -> H2 (bf16)
  ln_k<<<MT / 4, 256, 0, stream>>>(T2, ln2w, ln2b, H2);
  // mlp fc1: MLP1 = relu6(H2 @ m1w^T + b)    [25088 x 1536] bf16
  gemm_k<0><<<196 * 12, 256, 0, stream>>>(H2, wb_m1, m1b, nullptr, MLP1,
                                           MT, 1536, 384, 384, 384, 12, 0);
  // mlp fc2 + residual(T2) -> T3 (f32)
  gemm_k<3><<<196 * 3, 256, 0, stream>>>(MLP1, wb_m2, m2b, T2, T3,
                                          MT, 384, 1536, 1536, 1536, 3, 0);
  // BN1 (per position) -> T3nb (bf16)
  bn1_partial_k<<<196 * 8, 256, 0, stream>>>(T3, bnP);
  bn1_finish_k<<<1, 256, 0, stream>>>(bnP, bn1w, bn1b, bnS, bnSh);
  bn1_apply_k<<<(MT * DM / 4 + 255) / 256, 256, 0, stream>>>(T3, bnS, bnSh, T3nb);
  // lin head: y = T3nb(128 x 75264) @ linw^T, split-K 49 x 1536 (W f32 direct)
  gemm_k<4><<<3 * 49, 256, 0, stream>>>(T3nb, linw, nullptr, nullptr, PART,
                                         128, 384, 1536, 75264, 75264, 3, 1536);
  lin_reduce_k<<<192, 256, 0, stream>>>(PART, linb, y);
  // BN2 (per feature over batch), in place on d_out
  bn2_k<<<384, 64, 0, stream>>>(y, bn2w, bn2b);
}

// Round 8
// 802.426 us; speedup vs baseline: 1.2033x; 1.2033x over previous
//
#include <hip/hip_runtime.h>
#include <cstdint>

// ---------------------------------------------------------------------------
// Problem constants
// ---------------------------------------------------------------------------
#define B_    128
#define CIN   1024
#define NPOS  196          // 14*14
#define DM    384
#define NH_   12
#define HD_   32
#define DFF_  1536
#define MT    25088        // B_*NPOS
#define SCALE_Q 0.17677669529663687f   // 1/sqrt(32)

typedef unsigned short u16;
typedef __attribute__((ext_vector_type(8))) short  short8;   // 8 bf16 (4 VGPR)
typedef __attribute__((ext_vector_type(4))) float  f32x4;    // MFMA C/D

__device__ __forceinline__ u16 f2bf(float f) {
  union { float f; uint32_t u; } v; v.f = f;
  uint32_t u = v.u;
  return (u16)((u + 0x7fffu + ((u >> 16) & 1u)) >> 16);
}
__device__ __forceinline__ float bf2f(u16 h) {
  union { uint32_t u; float f; } v; v.u = ((uint32_t)h) << 16;
  return v.f;
}

#define GLDS16(g, l)                                                           \
  __builtin_amdgcn_global_load_lds(                                            \
      (const __attribute__((address_space(1))) void*)(g),                      \
      (__attribute__((address_space(3))) void*)(l), 16, 0, 0)

// ---------------------------------------------------------------------------
// Generic bf16 MFMA GEMM:  out = epi( A[M x K] * W[N x K]^T )
// 128x128 tile, 4 waves (2x2 of 64x64), BK=64, 32 MFMA / K-step.
// MODE: 0 = bias+relu6 -> bf16   (fc1, mlp1)
//       1 = bias       -> f32    (fc2)
//       2 = plain      -> bf16   (qkv)
//       3 = bias+res   -> f32    (proj, mlp2)
//       4 = split-K partial -> f32 (lin head; W is f32, converted in staging)
// ---------------------------------------------------------------------------
template <int MODE>
__global__ __launch_bounds__(256) void gemm_k(
    const u16* __restrict__ A, const void* __restrict__ Wv,
    const float* __restrict__ bias, const float* __restrict__ res,
    void* __restrict__ outp,
    int M, int N, int K, int lda, int ldw, int nTN, int splitK)
{
  __shared__ __align__(16) u16 As[8 * 128 * 8];   // [s][r][8], s = k-slot (8 bf16)
  __shared__ __align__(16) u16 Bs[8 * 128 * 8];

  int bid = blockIdx.x;
  int split = 0, mT, nT;
  if (MODE == 4) { split = bid / nTN; nT = bid % nTN; mT = 0; }
  else           { mT = bid / nTN;    nT = bid % nTN; }

  const u16* Ab = A + (size_t)split * splitK;
  float* outF = (float*)outp + ((MODE == 4) ? (size_t)split * (size_t)M * N : (size_t)0);
  u16*   outU = (u16*)outp;

  int tid = threadIdx.x;
  int wv = tid >> 6, ln = tid & 63;
  int q = ln >> 4, c = ln & 15;
  int wr = wv >> 1, wc = wv & 1;
  int mBase = mT * 128, nBase = nT * 128;

  f32x4 acc[4][4];
#pragma unroll
  for (int i = 0; i < 4; i++)
#pragma unroll
    for (int j = 0; j < 4; j++) acc[i][j] = (f32x4){0.f, 0.f, 0.f, 0.f};

  const u16* Ag = Ab + (size_t)mBase * lda;
  const u16*  Wg16 = (const u16*)Wv + (size_t)split * splitK + (size_t)nBase * ldw;
  const float* Wg32 = (const float*)Wv + (size_t)split * splitK + (size_t)nBase * ldw;

  for (int k0 = 0; k0 < K; k0 += 64) {
    // ---- stage 16KB A-tile + 16KB W-tile (16 chunks each, 4/wave) ----
#pragma unroll
    for (int i = 0; i < 4; i++) {
      int ch = wv * 4 + i;             // chunk 0..15 (1024B each)
      int s = ch >> 1;                 // k-slot (8 bf16), 0..7
      int r = (ch & 1) * 64 + ln;      // tile row
      GLDS16(Ag + (size_t)r * lda + (k0 + s * 8), &As[ch * 512]);
      if constexpr (MODE == 4) {
        const float* wp = Wg32 + (size_t)r * ldw + (k0 + s * 8);
        float4 f0 = *(const float4*)wp, f1 = *(const float4*)(wp + 4);
        short8 pk;
        pk[0] = (short)f2bf(f0.x); pk[1] = (short)f2bf(f0.y);
        pk[2] = (short)f2bf(f0.z); pk[3] = (short)f2bf(f0.w);
        pk[4] = (short)f2bf(f1.x); pk[5] = (short)f2bf(f1.y);
        pk[6] = (short)f2bf(f1.z); pk[7] = (short)f2bf(f1.w);
        *(short8*)&Bs[ch * 512 + ln * 8] = pk;
      } else {
        GLDS16(Wg16 + (size_t)r * ldw + (k0 + s * 8), &Bs[ch * 512]);
      }
    }
    __syncthreads();
#pragma unroll
    for (int kk = 0; kk < 2; kk++) {
      short8 afr[4], bfr[4];
#pragma unroll
      for (int mt2 = 0; mt2 < 4; mt2++)
        afr[mt2] = *(const short8*)&As[(((kk * 4 + q) * 128) + wr * 64 + mt2 * 16 + c) * 8];
#pragma unroll
      for (int nt2 = 0; nt2 < 4; nt2++)
        bfr[nt2] = *(const short8*)&Bs[(((kk * 4 + q) * 128) + wc * 64 + nt2 * 16 + c) * 8];
#pragma unroll
      for (int mt2 = 0; mt2 < 4; mt2++)
#pragma unroll
        for (int nt2 = 0; nt2 < 4; nt2++)
          acc[mt2][nt2] = __builtin_amdgcn_mfma_f32_16x16x32_bf16(
              afr[mt2], bfr[nt2], acc[mt2][nt2], 0, 0, 0);
    }
    __syncthreads();
  }

  // ---- epilogue ----
#pragma unroll
  for (int mt2 = 0; mt2 < 4; mt2++) {
    int row0 = mBase + wr * 64 + mt2 * 16 + q * 4;
#pragma unroll
    for (int nt2 = 0; nt2 < 4; nt2++) {
      int col = nBase + wc * 64 + nt2 * 16 + c;
      float bv = (MODE == 0 || MODE == 1 || MODE == 3) ? bias[col] : 0.f;
      f32x4 v = acc[mt2][nt2];
#pragma unroll
      for (int e = 0; e < 4; e++) {
        int row = row0 + e;
        float x = v[e] + bv;
        if (MODE == 0) x = fminf(fmaxf(x, 0.f), 6.f);
        if (MODE == 3) x += res[(size_t)row * N + col];
        if (MODE == 0 || MODE == 2) outU[(size_t)row * N + col] = f2bf(x);
        else                        outF[(size_t)row * N + col] = x;
      }
    }
  }
}

// ---------------------------------------------------------------------------
// x (B, CIN, HW, HW) f32  ->  A_t (B*NPOS, CIN) bf16
// ---------------------------------------------------------------------------
__global__ __launch_bounds__(256) void transpose_cast_k(
    const float* __restrict__ x, u16* __restrict__ At)
{
  __shared__ float t[32][33];
  int c0 = blockIdx.x * 32, n0 = blockIdx.y * 32, b = blockIdx.z;
  int tx = threadIdx.x, ty = threadIdx.y;
  const float* xb = x + (size_t)b * CIN * NPOS;
#pragma unroll
  for (int i = 0; i < 4; i++) {
    int cc = c0 + ty + i * 8, nn = n0 + tx;
    t[ty + i * 8][tx] = (nn < NPOS) ? xb[(size_t)cc * NPOS + nn] : 0.f;
  }
  __syncthreads();
  u16* Ab = At + (size_t)b * NPOS * CIN;
#pragma unroll
  for (int i = 0; i < 4; i++) {
    int nn = n0 + ty + i * 8, cc = c0 + tx;
    if (nn < NPOS) Ab[(size_t)nn * CIN + cc] = f2bf(t[tx][ty + i * 8]);
  }
}

// ---------------------------------------------------------------------------
// depthwise 3x3 SAME conv + bias + identity residual (fp32)
// ---------------------------------------------------------------------------
__global__ __launch_bounds__(256) void conv_res_k(
    const float* __restrict__ T0, const float* __restrict__ pcw,
    const float* __restrict__ pcb, float* __restrict__ T1)
{
  int idx = blockIdx.x * 256 + threadIdx.x;
  if (idx >= B_ * NPOS * 96) return;
  int d4 = idx % 96; int rem = idx / 96;
  int n = rem % NPOS; int b = rem / NPOS;
  int hh = n / 14, ww = n % 14;
  int d0 = d4 * 4;
  float w9[4][9];
#pragma unroll
  for (int j = 0; j < 4; j++)
#pragma unroll
    for (int t = 0; t < 9; t++) w9[j][t] = pcw[(d0 + j) * 9 + t];
  const float* base = T0 + (size_t)b * NPOS * DM;
  float4 ctr = *(const float4*)(base + (size_t)n * DM + d0);
  float ax = ctr.x + pcb[d0], ay = ctr.y + pcb[d0 + 1];
  float az = ctr.z + pcb[d0 + 2], aw = ctr.w + pcb[d0 + 3];
#pragma unroll
  for (int kh = 0; kh < 3; kh++) {
    int h2 = hh + kh - 1;
    if (h2 < 0 || h2 >= 14) continue;
#pragma unroll
    for (int kw = 0; kw < 3; kw++) {
      int w2 = ww + kw - 1;
      if (w2 < 0 || w2 >= 14) continue;
      float4 v = *(const float4*)(base + (size_t)(h2 * 14 + w2) * DM + d0);
      int t = kh * 3 + kw;
      ax += v.x * w9[0][t]; ay += v.y * w9[1][t];
      az += v.z * w9[2][t]; aw += v.w * w9[3][t];
    }
  }
  float4 o = {ax, ay, az, aw};
  *(float4*)(T1 + (size_t)b * NPOS * DM + (size_t)n * DM + d0) = o;
}

// ---------------------------------------------------------------------------
// LayerNorm(384) f32 -> bf16, one wave per row (float2-vectorized)
// ---------------------------------------------------------------------------
__global__ __launch_bounds__(256) void ln_k(
    const float* __restrict__ in, const float* __restrict__ w,
    const float* __restrict__ bb, u16* __restrict__ out)
{
  int row = blockIdx.x * 4 + (threadIdx.x >> 6);
  int ln = threadIdx.x & 63;
  const float2* r = (const float2*)(in + (size_t)row * DM);
  float2 v[3]; float s = 0.f, sq = 0.f;
#pragma unroll
  for (int j = 0; j < 3; j++) {
    v[j] = r[ln + 64 * j];
    s += v[j].x + v[j].y; sq += v[j].x * v[j].x + v[j].y * v[j].y;
  }
#pragma unroll
  for (int o = 1; o < 64; o <<= 1) { s += __shfl_xor(s, o, 64); sq += __shfl_xor(sq, o, 64); }
  float mu = s * (1.f / 384.f);
  float var = sq * (1.f / 384.f) - mu * mu;
  float rs = rsqrtf(var + 1e-5f);
  uint32_t* orow = (uint32_t*)(out + (size_t)row * DM);
#pragma unroll
  for (int j = 0; j < 3; j++) {
    int d = (ln + 64 * j) * 2;
    float a = (v[j].x - mu) * rs * w[d] + bb[d];
    float bq = (v[j].y - mu) * rs * w[d + 1] + bb[d + 1];
    orow[ln + 64 * j] = (uint32_t)f2bf(a) | ((uint32_t)f2bf(bq) << 16);
  }
}

// ---------------------------------------------------------------------------
// Fused attention per (b,h), flash-style online softmax over 7 j-chunks of 32.
//   K staged once into LDS fragment layout Ks[4][196][8] via global_load_lds.
//   rpe table staged once into Ts[49][32]; scores via MFMA reusing Q A-frag.
//   Per chunk: 2 QK MFMA -> bias -> online max/sum rescale -> P chunk (1KB
//   per wave, A-frag layout) -> 2 PV MFMA.
//   NOTE: no min-waves launch_bounds — r7's (256,4) forced a 64-VGPR target
//   and the compiler spilled ~300 MB/dispatch to scratch (FETCH 236 MB,
//   WRITE 134 MB). Natural allocation stays under 128 without spills.
// LDS = 12544(Ks) + 14848(Vt) + 4096(Pc) + 3136(Ts) + 6272(Rw) = 40896 B
//   -> padded 40960 -> 4 blocks/CU.
// ---------------------------------------------------------------------------
__global__ __launch_bounds__(256) void attn_k(
    const u16* __restrict__ QKV, const float* __restrict__ tabG,
    u16* __restrict__ AO)
{
  __shared__ __align__(16) u16 Ks[4 * 196 * 8];     // [s][j][e] K fragments
  __shared__ __align__(16) u16 Vt[32 * 232];        // [d][j], pad j>=196 zero
  __shared__ __align__(16) u16 Pc4[4][4 * 16 * 8];  // per-wave P chunk (16x32)
  __shared__ __align__(16) u16 Ts[49 * 32];         // rpe table, [t][k] bf16
  __shared__ __align__(16) u16 Rw4[4][16 * 49];     // per-wave rpe scores bf16
  int bh = blockIdx.x; int b = bh / NH_, h = bh % NH_;
  int tid = threadIdx.x;
  int wv = tid >> 6, ln = tid & 63;
  int q = ln >> 4, c = ln & 15;
  size_t rowbase = (size_t)b * NPOS * 1152 + h * 32;

  // ---- stage K fragments via global_load_lds (wave-uniform dest) ----
  for (int cb = wv * 64; cb < 784; cb += 256) {
    int ch = cb + ln;
    if (ch < 784) {
      int s = ch / 196, j = ch - s * 196;
      GLDS16(QKV + rowbase + 384 + (size_t)j * 1152 + s * 8, &Ks[cb * 8]);
    }
  }
  // ---- stage rpe table transposed to [t][k] bf16 (once per block) ----
  for (int t = tid; t < 49 * 32; t += 256) {
    int tt = t >> 5, k = t & 31;
    Ts[t] = f2bf(tabG[k * 49 + tt]);
  }
  // ---- stage V transposed (vectorized): 784 chunks of 8 d-values ----
  for (int t = tid; t < 784; t += 256) {
    int nn = t >> 2, d0 = (t & 3) * 8;
    short8 v = *(const short8*)(QKV + rowbase + 768 + (size_t)nn * 1152 + d0);
#pragma unroll
    for (int j = 0; j < 8; j++) Vt[(d0 + j) * 232 + nn] = (u16)v[j];
  }
  for (int t = tid; t < 32 * 36; t += 256) {
    int d = t / 36, jj = t - d * 36;
    Vt[d * 232 + 196 + jj] = 0;
  }
  __syncthreads();

  u16* Pw = Pc4[wv];
  u16* Rw = Rw4[wv];

  for (int mt = wv; mt < 13; mt += 4) {
    int mb = mt * 16;
    int irow = mb + c; if (irow > 195) irow = 195;
    short8 afrag = *(const short8*)(QKV + rowbase + (size_t)irow * 1152 + q * 8);
    int i0 = mb + q * 4;

    // ---- rpe scores via MFMA -> Rw (table frags transient from LDS) ----
#pragma unroll
    for (int nt = 0; nt < 4; nt++) {
      int t = nt * 16 + c;
      int tt = t < 49 ? t : 48;
      short8 tb = *(const short8*)&Ts[tt * 32 + q * 8];
      f32x4 z = {0.f, 0.f, 0.f, 0.f};
      f32x4 rr = __builtin_amdgcn_mfma_f32_16x16x32_bf16(afrag, tb, z, 0, 0, 0);
      if (t < 49) {
#pragma unroll
        for (int e = 0; e < 4; e++)
          Rw[(q * 4 + e) * 49 + t] = f2bf(rr[e] * SCALE_Q);
      }
    }

    // row geometry (hoisted)
    int ri4[4], ci4[4];
#pragma unroll
    for (int e = 0; e < 4; e++) {
      int i = i0 + e; int ri = i / 14;
      ri4[e] = ri; ci4[e] = i - ri * 14;
    }

    float m[4], l[4];
    f32x4 oacc[2];
#pragma unroll
    for (int e = 0; e < 4; e++) { m[e] = -INFINITY; l[e] = 0.f; }
    oacc[0] = (f32x4){0.f, 0.f, 0.f, 0.f};
    oacc[1] = (f32x4){0.f, 0.f, 0.f, 0.f};

    // ---- online softmax over 7 chunks of 32 j ----
    for (int ck = 0; ck < 7; ck++) {
      // 2 QK MFMAs from Ks LDS
      f32x4 s01[2];
#pragma unroll
      for (int t = 0; t < 2; t++) {
        int j = (ck * 2 + t) * 16 + c;
        int jc = j > 195 ? 195 : j;
        short8 bfrag = *(const short8*)&Ks[(q * 196 + jc) * 8];
        f32x4 z = {0.f, 0.f, 0.f, 0.f};
        s01[t] = __builtin_amdgcn_mfma_f32_16x16x32_bf16(afrag, bfrag, z, 0, 0, 0);
      }
      // bias + mask
#pragma unroll
      for (int t = 0; t < 2; t++) {
        int j = (ck * 2 + t) * 16 + c;
        bool jok = (j < 196);
        int rj = j / 14, cj = j - rj * 14;
#pragma unroll
        for (int e = 0; e < 4; e++) {
          float sv = -1e30f;
          if (jok && (i0 + e) < 196) {
            int dr = ri4[e] - rj, dc = ci4[e] - cj;
            int adr = dr < 0 ? -dr : dr, adc = dc < 0 ? -dc : dc;
            int tr = adr <= 1 ? adr : (adr <= 3 ? 2 : 3);
            int tc = adc <= 1 ? adc : (adc <= 3 ? 2 : 3);
            int fr = dr < 0 ? -tr : tr, fc = dc < 0 ? -tc : tc;
            int bucket = fr * 7 + fc + 24;
            sv = s01[t][e] * SCALE_Q + bf2f(Rw[(q * 4 + e) * 49 + bucket]);
          }
          s01[t][e] = sv;
        }
      }
      // chunk max (16-lane group reduce) + online update
#pragma unroll
      for (int e = 0; e < 4; e++) {
        float mc = fmaxf(s01[0][e], s01[1][e]);
#pragma unroll
        for (int o = 1; o < 16; o <<= 1) mc = fmaxf(mc, __shfl_xor(mc, o, 64));
        float mn = fmaxf(m[e], mc);
        float sc = __expf(m[e] - mn);
        m[e] = mn;
        float p0 = __expf(s01[0][e] - mn);
        float p1 = __expf(s01[1][e] - mn);
        l[e] = l[e] * sc + p0 + p1;
        oacc[0][e] *= sc; oacc[1][e] *= sc;
        s01[0][e] = p0; s01[1][e] = p1;
      }
      // write P chunk in A-frag layout: slot = t*2 + (c>>3), row q*4+e, col c&7
#pragma unroll
      for (int t = 0; t < 2; t++) {
        int sl = t * 2 + (c >> 3);
#pragma unroll
        for (int e = 0; e < 4; e++)
          Pw[(sl * 16 + q * 4 + e) * 8 + (c & 7)] = f2bf(s01[t][e]);
      }
      // PV: 2 MFMAs (d halves), k = this chunk's 32 j
#pragma unroll
      for (int n2 = 0; n2 < 2; n2++) {
        short8 pa = *(const short8*)&Pw[(q * 16 + c) * 8];
        short8 vb = *(const short8*)&Vt[(n2 * 16 + c) * 232 + ck * 32 + q * 8];
        oacc[n2] = __builtin_amdgcn_mfma_f32_16x16x32_bf16(pa, vb, oacc[n2], 0, 0, 0);
      }
    }

    // final 1/l and store
    float inv[4];
#pragma unroll
    for (int e = 0; e < 4; e++) {
      float s2 = l[e];
#pragma unroll
      for (int o = 1; o < 16; o <<= 1) s2 += __shfl_xor(s2, o, 64);
      inv[e] = 1.f / s2;
    }
#pragma unroll
    for (int n2 = 0; n2 < 2; n2++) {
#pragma unroll
      for (int e = 0; e < 4; e++) {
        int i = i0 + e;
        if (i < 196) {
          int d = n2 * 16 + c;
          AO[((size_t)b * NPOS + i) * DM + h * 32 + d] = f2bf(oacc[n2][e] * inv[e]);
        }
      }
    }
  }
}

// ---------------------------------------------------------------------------
// BN1 over (batch, dmodel) per position n: two-stage stats
// ---------------------------------------------------------------------------
__global__ __launch_bounds__(256) void bn1_partial_k(
    const float* __restrict__ T3, float* __restrict__ part)
{
  int n = blockIdx.x >> 3, g = blockIdx.x & 7;
  int tid = threadIdx.x;
  float s = 0.f, sq = 0.f;
  for (int b2 = g * 16; b2 < g * 16 + 16; b2++) {
    const float* p = T3 + ((size_t)b2 * NPOS + n) * DM;
    for (int d = tid; d < DM; d += 256) { float v = p[d]; s += v; sq += v * v; }
  }
#pragma unroll
  for (int o = 1; o < 64; o <<= 1) { s += __shfl_xor(s, o, 64); sq += __shfl_xor(sq, o, 64); }
  __shared__ float ls[4], lq[4];
  int wv = tid >> 6, ln = tid & 63;
  if (ln == 0) { ls[wv] = s; lq[wv] = sq; }
  __syncthreads();
  if (tid == 0) {
    part[blockIdx.x * 2]     = ls[0] + ls[1] + ls[2] + ls[3];
    part[blockIdx.x * 2 + 1] = lq[0] + lq[1] + lq[2] + lq[3];
  }
}

__global__ __launch_bounds__(256) void bn1_finish_k(
    const float* __restrict__ part, const float* __restrict__ bw,
    const float* __restrict__ bbb, float* __restrict__ scaleArr,
    float* __restrict__ shiftArr)
{
  int n = threadIdx.x;
  if (n >= NPOS) return;
  float S = 0.f, Q = 0.f;
#pragma unroll
  for (int g = 0; g < 8; g++) { S += part[(n * 8 + g) * 2]; Q += part[(n * 8 + g) * 2 + 1]; }
  float mu = S / 49152.f;
  float var = Q / 49152.f - mu * mu;
  float rs = rsqrtf(var + 2e-5f);
  float sc = rs * bw[n];
  scaleArr[n] = sc;
  shiftArr[n] = bbb[n] - mu * sc;
}

__global__ __launch_bounds__(256) void bn1_apply_k(
    const float* __restrict__ T3, const float* __restrict__ scaleArr,
    const float* __restrict__ shiftArr, u16* __restrict__ outb)
{
  int idx = blockIdx.x * 256 + threadIdx.x;           // float4 index
  if (idx >= MT * DM / 4) return;
  int n = (idx / 96) % NPOS;
  float4 v = *(const float4*)(T3 + (size_t)idx * 4);
  float sc = scaleArr[n], sh = shiftArr[n];
  uint32_t p0 = (uint32_t)f2bf(v.x * sc + sh) | ((uint32_t)f2bf(v.y * sc + sh) << 16);
  uint32_t p1 = (uint32_t)f2bf(v.z * sc + sh) | ((uint32_t)f2bf(v.w * sc + sh) << 16);
  ((uint2*)outb)[idx] = make_uint2(p0, p1);
}

// ---------------------------------------------------------------------------
// split-K reduce for lin head + bias
// ---------------------------------------------------------------------------
__global__ __launch_bounds__(256) void lin_reduce_k(
    const float* __restrict__ part, const float* __restrict__ lb,
    float* __restrict__ y)
{
  int idx = blockIdx.x * 256 + threadIdx.x;
  if (idx >= 128 * DM) return;
  int col = idx % DM;
  float s = lb[col];
#pragma unroll
  for (int sp = 0; sp < 49; sp++) s += part[(size_t)sp * (128 * DM) + idx];
  y[idx] = s;
}

// ---------------------------------------------------------------------------
// BN2 over batch (128) per feature col, in-place on y
// ---------------------------------------------------------------------------
__global__ __launch_bounds__(64) void bn2_k(
    float* __restrict__ y, const float* __restrict__ w,
    const float* __restrict__ bb)
{
  int col = blockIdx.x; int ln = threadIdx.x;
  float v0 = y[(size_t)ln * DM + col];
  float v1 = y[(size_t)(ln + 64) * DM + col];
  float s = v0 + v1, sq = v0 * v0 + v1 * v1;
#pragma unroll
  for (int o = 1; o < 64; o <<= 1) { s += __shfl_xor(s, o, 64); sq += __shfl_xor(sq, o, 64); }
  float mu = s / 128.f;
  float var = sq / 128.f - mu * mu;
  float rs = rsqrtf(var + 2e-5f);
  float sc = rs * w[col], sh = bb[col] - mu * sc;
  y[(size_t)ln * DM + col] = v0 * sc + sh;
  y[(size_t)(ln + 64) * DM + col] = v1 * sc + sh;
}

// ---------------------------------------------------------------------------
// merged f32 -> bf16 cast for the six small weight matrices
// segment boundaries in float4 units
// ---------------------------------------------------------------------------
__global__ __launch_bounds__(256) void castall_k(
    const float* __restrict__ s0, u16* __restrict__ d0,
    const float* __restrict__ s1, u16* __restrict__ d1,
    const float* __restrict__ s2, u16* __restrict__ d2,
    const float* __restrict__ s3, u16* __restrict__ d3,
    const float* __restrict__ s4, u16* __restrict__ d4,
    const float* __restrict__ s5, u16* __restrict__ d5)
{
  const int b0 = 262144, b1 = b0 + 98304, b2 = b1 + 110592,
            b3 = b2 + 36864, b4 = b3 + 147456, b5 = b4 + 147456; // 802816
  int idx = blockIdx.x * 256 + threadIdx.x;
  int stride = gridDim.x * 256;
  for (; idx < b5; idx += stride) {
    const float* s; u16* d; int l;
    if      (idx < b0) { s = s0; d = d0; l = idx; }
    else if (idx < b1) { s = s1; d = d1; l = idx - b0; }
    else if (idx < b2) { s = s2; d = d2; l = idx - b1; }
    else if (idx < b3) { s = s3; d = d3; l = idx - b2; }
    else if (idx < b4) { s = s4; d = d4; l = idx - b3; }
    else               { s = s5; d = d5; l = idx - b4; }
    float4 v = *(const float4*)(s + (size_t)l * 4);
    uint32_t p0 = (uint32_t)f2bf(v.x) | ((uint32_t)f2bf(v.y) << 16);
    uint32_t p1 = (uint32_t)f2bf(v.z) | ((uint32_t)f2bf(v.w) << 16);
    ((uint2*)d)[l] = make_uint2(p0, p1);
  }
}

// ---------------------------------------------------------------------------
// Orchestration
// ---------------------------------------------------------------------------
extern "C" void kernel_launch(void* const* d_in, const int* in_sizes, int n_in,
                              void* d_out, int out_size, void* d_ws, size_t ws_size,
                              hipStream_t stream)
{
  (void)in_sizes; (void)n_in; (void)out_size;
  const float* x    = (const float*)d_in[0];
  const float* fc1w = (const float*)d_in[1];
  const float* fc1b = (const float*)d_in[2];
  const float* fc2w = (const float*)d_in[3];
  const float* fc2b = (const float*)d_in[4];
  const float* pcw  = (const float*)d_in[5];
  const float* pcb  = (const float*)d_in[6];
  const float* ln1w = (const float*)d_in[7];
  const float* ln1b = (const float*)d_in[8];
  const float* qkvw = (const float*)d_in[9];
  const float* rpet = (const float*)d_in[10];
  const float* projw= (const float*)d_in[11];
  const float* projb= (const float*)d_in[12];
  const float* ln2w = (const float*)d_in[13];
  const float* ln2b = (const float*)d_in[14];
  const float* m1w  = (const float*)d_in[15];
  const float* m1b  = (const float*)d_in[16];
  const float* m2w  = (const float*)d_in[17];
  const float* m2b  = (const float*)d_in[18];
  const float* bn1w = (const float*)d_in[19];
  const float* bn1b = (const float*)d_in[20];
  const float* linw = (const float*)d_in[21];
  const float* linb = (const float*)d_in[22];
  const float* bn2w = (const float*)d_in[23];
  const float* bn2b = (const float*)d_in[24];
  float* y = (float*)d_out;

  // -------- aliased workspace layout (regions share by liveness) ----------
  const size_t RA = 0;                      // At / MLP1
  const size_t RB = 77070336;               // U / QKV / T3nb
  const size_t RC = RB + 57802752;          // H / AO / H2
  const size_t RD = RC + 19267584;          // T0 / T2
  const size_t RE = RD + 38535168;          // T1 / T3
  const size_t RF = RE + 38535168;          // PART (lin split-K)
  const size_t RG = RF + 9633792;           // small bf16 weights
  const size_t RS = RG + 6422528;           // bn1 scale/shift + partials
  const size_t NEED = RS + 2048 + 16384;
  if (ws_size < NEED) return;

  char* ws = (char*)d_ws;
  u16*   At    = (u16*)(ws + RA);
  u16*   MLP1  = (u16*)(ws + RA);
  u16*   U     = (u16*)(ws + RB);
  u16*   QKV   = (u16*)(ws + RB);
  u16*   T3nb  = (u16*)(ws + RB);
  u16*   H     = (u16*)(ws + RC);
  u16*   AO    = (u16*)(ws + RC);
  u16*   H2    = (u16*)(ws + RC);
  float* T0    = (float*)(ws + RD);
  float* T2    = (float*)(ws + RD);
  float* T1    = (float*)(ws + RE);
  float* T3    = (float*)(ws + RE);
  float* PART  = (float*)(ws + RF);
  u16*   wb_fc1 = (u16*)(ws + RG);
  u16*   wb_fc2 = wb_fc1 + 1048576;
  u16*   wb_qkv = wb_fc2 + 393216;
  u16*   wb_proj= wb_qkv + 442368;
  u16*   wb_m1  = wb_proj + 147456;
  u16*   wb_m2  = wb_m1 + 589824;
  float* bnS   = (float*)(ws + RS);
  float* bnSh  = bnS + 196;
  float* bnP   = (float*)(ws + RS + 2048);

  // weight casts (f32 -> bf16), one merged kernel
  castall_k<<<1024, 256, 0, stream>>>(fc1w, wb_fc1, fc2w, wb_fc2, qkvw, wb_qkv,
                                      projw, wb_proj, m1w, wb_m1, m2w, wb_m2);

  // x (B,CIN,N) -> At (B*N, CIN) bf16
  transpose_cast_k<<<dim3(32, 7, 128), dim3(32, 8), 0, stream>>>(x, At);

  // embed fc1: U = relu6(At @ fc1w^T + b)   [25088 x 1024]
  gemm_k<0><<<196 * 8, 256, 0, stream>>>(At, wb_fc1, fc1b, nullptr, U,
                                          MT, 1024, 1024, 1024, 1024, 8, 0);
  // embed fc2: T0 = U @ fc2w^T + b          [25088 x 384] f32
  gemm_k<1><<<196 * 3, 256, 0, stream>>>(U, wb_fc2, fc2b, nullptr, T0,
                                          MT, 384, 1024, 1024, 1024, 3, 0);
  // depthwise conv + bias + residual -> T1
  conv_res_k<<<(B_ * NPOS * 96 + 255) / 256, 256, 0, stream>>>(T0, pcw, pcb, T1);
  // LN1 -> H (bf16)
  ln_k<<<MT / 4, 256, 0, stream>>>(T1, ln1w, ln1b, H);
  // qkv: QKV = H @ qkvw^T (no bias)          [25088 x 1152] bf16
  gemm_k<2><<<196 * 9, 256, 0, stream>>>(H, wb_qkv, nullptr, nullptr, QKV,
                                          MT, 1152, 384, 384, 384, 9, 0);
  // fused attention (rpe in-kernel, flash-style) -> AO (bf16)
  attn_k<<<1536, 256, 0, stream>>>(QKV, rpet, AO);
  // proj + residual(T1) -> T2 (f32)
  gemm_k<3><<<196 * 3, 256, 0, stream>>>(AO, wb_proj, projb, T1, T2,
                                          MT, 384, 384, 384, 384, 3, 0);
  // LN2 -> H2 (bf16)
  ln_k<<<MT / 4, 256, 0, stream>>>(T2, ln2w, ln2b, H2);
  // mlp fc1: MLP1 = relu6(H2 @ m1w^T + b)    [25088 x 1536] bf16
  gemm_k<0><<<196 * 12, 256, 0, stream>>>(H2, wb_m1, m1b, nullptr, MLP1,
                                           MT, 1536, 384, 384, 384, 12, 0);
  // mlp fc2 + residual(T2) -> T3 (f32)
  gemm_k<3><<<196 * 3, 256, 0, stream>>>(MLP1, wb_m2, m2b, T2, T3,
                                          MT, 384, 1536, 1536, 1536, 3, 0);
  // BN1 (per position) -> T3nb (bf16)
  bn1_partial_k<<<196 * 8, 256, 0, stream>>>(T3, bnP);
  bn1_finish_k<<<1, 256, 0, stream>>>(bnP, bn1w, bn1b, bnS, bnSh);
  bn1_apply_k<<<(MT * DM / 4 + 255) / 256, 256, 0, stream>>>(T3, bnS, bnSh, T3nb);
  // lin head: y = T3nb(128 x 75264) @ linw^T, split-K 49 x 1536 (W f32 direct)
  gemm_k<4><<<3 * 49, 256, 0, stream>>>(T3nb, linw, nullptr, nullptr, PART,
                                         128, 384, 1536, 75264, 75264, 3, 1536);
  lin_reduce_k<<<192, 256, 0, stream>>>(PART, linb, y);
  // BN2 (per feature over batch), in place on d_out
  bn2_k<<<384, 64, 0, stream>>>(y, bn2w, bn2b);
}

// Round 9
// 784.400 us; speedup vs baseline: 1.2309x; 1.0230x over previous
//
#include <hip/hip_runtime.h>
#include <cstdint>

// ---------------------------------------------------------------------------
// Problem constants
// ---------------------------------------------------------------------------
#define B_    128
#define CIN   1024
#define NPOS  196          // 14*14
#define DM    384
#define NH_   12
#define HD_   32
#define DFF_  1536
#define MT    25088        // B_*NPOS
#define SCALE_Q 0.17677669529663687f   // 1/sqrt(32)

typedef unsigned short u16;
typedef __attribute__((ext_vector_type(8))) short  short8;   // 8 bf16 (4 VGPR)
typedef __attribute__((ext_vector_type(4))) float  f32x4;    // MFMA C/D

__device__ __forceinline__ u16 f2bf(float f) {
  union { float f; uint32_t u; } v; v.f = f;
  uint32_t u = v.u;
  return (u16)((u + 0x7fffu + ((u >> 16) & 1u)) >> 16);
}
__device__ __forceinline__ float bf2f(u16 h) {
  union { uint32_t u; float f; } v; v.u = ((uint32_t)h) << 16;
  return v.f;
}

#define GLDS16(g, l)                                                           \
  __builtin_amdgcn_global_load_lds(                                            \
      (const __attribute__((address_space(1))) void*)(g),                      \
      (__attribute__((address_space(3))) void*)(l), 16, 0, 0)

// ---------------------------------------------------------------------------
// Generic bf16 MFMA GEMM:  out = epi( A[M x K] * W[N x K]^T )
// 128x128 tile, 4 waves (2x2 of 64x64), BK=64, 32 MFMA / K-step.
// r9: (a) bijective XCD-chunked blockIdx swizzle (each XCD gets a contiguous
//     work range -> A-band reuse inside one L2; r8 FETCH was 4x the A size);
//     (b) 2-phase double-buffered LDS pipeline: issue next tile's
//     global_load_lds BEFORE compute, raw s_barrier + explicit counted
//     s_waitcnt AFTER the MFMA block so load latency overlaps MFMA
//     (the compiler's own __syncthreads drain would serialize it).
// MODE: 0 = bias+relu6 -> bf16   (fc1, mlp1)
//       1 = bias       -> f32    (fc2)
//       2 = plain      -> bf16   (qkv)
//       3 = bias+res   -> f32    (proj, mlp2)
//       4 = split-K partial -> f32 (lin head; W is f32, converted in staging)
// ---------------------------------------------------------------------------
template <int MODE>
__global__ __launch_bounds__(256) void gemm_k(
    const u16* __restrict__ A, const void* __restrict__ Wv,
    const float* __restrict__ bias, const float* __restrict__ res,
    void* __restrict__ outp,
    int M, int N, int K, int lda, int ldw, int nTN, int splitK)
{
  __shared__ __align__(16) u16 As[2][8 * 128 * 8];   // dbuf [s][r][8]
  __shared__ __align__(16) u16 Bs[2][8 * 128 * 8];

  // ---- bijective XCD-chunked swizzle (m204 variant; works for any nwg) ----
  int nwg = gridDim.x;
  int bid0 = blockIdx.x;
  int qq = nwg >> 3, rr = nwg & 7;
  int xcd = bid0 & 7, idx = bid0 >> 3;
  int bid = (xcd < rr ? xcd * (qq + 1) : rr * (qq + 1) + (xcd - rr) * qq) + idx;

  int split = 0, mT, nT;
  if (MODE == 4) { split = bid / nTN; nT = bid % nTN; mT = 0; }
  else           { mT = bid / nTN;    nT = bid % nTN; }

  const u16* Ab = A + (size_t)split * splitK;
  float* outF = (float*)outp + ((MODE == 4) ? (size_t)split * (size_t)M * N : (size_t)0);
  u16*   outU = (u16*)outp;

  int tid = threadIdx.x;
  int wv = tid >> 6, ln = tid & 63;
  int q = ln >> 4, c = ln & 15;
  int wr = wv >> 1, wc = wv & 1;
  int mBase = mT * 128, nBase = nT * 128;

  f32x4 acc[4][4];
#pragma unroll
  for (int i = 0; i < 4; i++)
#pragma unroll
    for (int j = 0; j < 4; j++) acc[i][j] = (f32x4){0.f, 0.f, 0.f, 0.f};

  const u16* Ag = Ab + (size_t)mBase * lda;
  const u16*  Wg16 = (const u16*)Wv + (size_t)split * splitK + (size_t)nBase * ldw;
  const float* Wg32 = (const float*)Wv + (size_t)split * splitK + (size_t)nBase * ldw;

  auto STAGE = [&](int t, int buf) {
    int k0 = t * 64;
#pragma unroll
    for (int i = 0; i < 4; i++) {
      int ch = wv * 4 + i;             // chunk 0..15 (1024B each)
      int s = ch >> 1;                 // k-slot (8 bf16), 0..7
      int r = (ch & 1) * 64 + ln;      // tile row
      GLDS16(Ag + (size_t)r * lda + (k0 + s * 8), &As[buf][ch * 512]);
      if constexpr (MODE == 4) {
        const float* wp = Wg32 + (size_t)r * ldw + (k0 + s * 8);
        float4 f0 = *(const float4*)wp, f1 = *(const float4*)(wp + 4);
        short8 pk;
        pk[0] = (short)f2bf(f0.x); pk[1] = (short)f2bf(f0.y);
        pk[2] = (short)f2bf(f0.z); pk[3] = (short)f2bf(f0.w);
        pk[4] = (short)f2bf(f1.x); pk[5] = (short)f2bf(f1.y);
        pk[6] = (short)f2bf(f1.z); pk[7] = (short)f2bf(f1.w);
        *(short8*)&Bs[buf][ch * 512 + ln * 8] = pk;
      } else {
        GLDS16(Wg16 + (size_t)r * ldw + (k0 + s * 8), &Bs[buf][ch * 512]);
      }
    }
  };

  int NT = K >> 6;   // K-steps of 64 (all K are multiples of 64)
  // ---- prologue: stage tile 0, wait, barrier ----
  STAGE(0, 0);
  if constexpr (MODE == 4)
    asm volatile("s_waitcnt vmcnt(0) lgkmcnt(0)" ::: "memory");
  else
    asm volatile("s_waitcnt vmcnt(0)" ::: "memory");
  __builtin_amdgcn_s_barrier();

  int cur = 0;
  for (int t = 0; t < NT; ++t) {
    // issue next tile's staging into the other buffer (in flight during MFMA)
    if (t + 1 < NT) STAGE(t + 1, cur ^ 1);
    __builtin_amdgcn_sched_barrier(0);   // keep stage-issue ahead of compute
#pragma unroll
    for (int kk = 0; kk < 2; kk++) {
      short8 afr[4], bfr[4];
#pragma unroll
      for (int mt2 = 0; mt2 < 4; mt2++)
        afr[mt2] = *(const short8*)&As[cur][(((kk * 4 + q) * 128) + wr * 64 + mt2 * 16 + c) * 8];
#pragma unroll
      for (int nt2 = 0; nt2 < 4; nt2++)
        bfr[nt2] = *(const short8*)&Bs[cur][(((kk * 4 + q) * 128) + wc * 64 + nt2 * 16 + c) * 8];
#pragma unroll
      for (int mt2 = 0; mt2 < 4; mt2++)
#pragma unroll
        for (int nt2 = 0; nt2 < 4; nt2++)
          acc[mt2][nt2] = __builtin_amdgcn_mfma_f32_16x16x32_bf16(
              afr[mt2], bfr[nt2], acc[mt2][nt2], 0, 0, 0);
    }
    if (t + 1 < NT) {
      if constexpr (MODE == 4)
        asm volatile("s_waitcnt vmcnt(0) lgkmcnt(0)" ::: "memory");
      else
        asm volatile("s_waitcnt vmcnt(0)" ::: "memory");
      __builtin_amdgcn_s_barrier();
      cur ^= 1;
    }
  }

  // ---- epilogue ----
#pragma unroll
  for (int mt2 = 0; mt2 < 4; mt2++) {
    int row0 = mBase + wr * 64 + mt2 * 16 + q * 4;
#pragma unroll
    for (int nt2 = 0; nt2 < 4; nt2++) {
      int col = nBase + wc * 64 + nt2 * 16 + c;
      float bv = (MODE == 0 || MODE == 1 || MODE == 3) ? bias[col] : 0.f;
      f32x4 v = acc[mt2][nt2];
#pragma unroll
      for (int e = 0; e < 4; e++) {
        int row = row0 + e;
        float x = v[e] + bv;
        if (MODE == 0) x = fminf(fmaxf(x, 0.f), 6.f);
        if (MODE == 3) x += res[(size_t)row * N + col];
        if (MODE == 0 || MODE == 2) outU[(size_t)row * N + col] = f2bf(x);
        else                        outF[(size_t)row * N + col] = x;
      }
    }
  }
}

// ---------------------------------------------------------------------------
// x (B, CIN, HW, HW) f32  ->  A_t (B*NPOS, CIN) bf16
// ---------------------------------------------------------------------------
__global__ __launch_bounds__(256) void transpose_cast_k(
    const float* __restrict__ x, u16* __restrict__ At)
{
  __shared__ float t[32][33];
  int c0 = blockIdx.x * 32, n0 = blockIdx.y * 32, b = blockIdx.z;
  int tx = threadIdx.x, ty = threadIdx.y;
  const float* xb = x + (size_t)b * CIN * NPOS;
#pragma unroll
  for (int i = 0; i < 4; i++) {
    int cc = c0 + ty + i * 8, nn = n0 + tx;
    t[ty + i * 8][tx] = (nn < NPOS) ? xb[(size_t)cc * NPOS + nn] : 0.f;
  }
  __syncthreads();
  u16* Ab = At + (size_t)b * NPOS * CIN;
#pragma unroll
  for (int i = 0; i < 4; i++) {
    int nn = n0 + ty + i * 8, cc = c0 + tx;
    if (nn < NPOS) Ab[(size_t)nn * CIN + cc] = f2bf(t[tx][ty + i * 8]);
  }
}

// ---------------------------------------------------------------------------
// depthwise 3x3 SAME conv + bias + identity residual (fp32)
// ---------------------------------------------------------------------------
__global__ __launch_bounds__(256) void conv_res_k(
    const float* __restrict__ T0, const float* __restrict__ pcw,
    const float* __restrict__ pcb, float* __restrict__ T1)
{
  int idx = blockIdx.x * 256 + threadIdx.x;
  if (idx >= B_ * NPOS * 96) return;
  int d4 = idx % 96; int rem = idx / 96;
  int n = rem % NPOS; int b = rem / NPOS;
  int hh = n / 14, ww = n % 14;
  int d0 = d4 * 4;
  float w9[4][9];
#pragma unroll
  for (int j = 0; j < 4; j++)
#pragma unroll
    for (int t = 0; t < 9; t++) w9[j][t] = pcw[(d0 + j) * 9 + t];
  const float* base = T0 + (size_t)b * NPOS * DM;
  float4 ctr = *(const float4*)(base + (size_t)n * DM + d0);
  float ax = ctr.x + pcb[d0], ay = ctr.y + pcb[d0 + 1];
  float az = ctr.z + pcb[d0 + 2], aw = ctr.w + pcb[d0 + 3];
#pragma unroll
  for (int kh = 0; kh < 3; kh++) {
    int h2 = hh + kh - 1;
    if (h2 < 0 || h2 >= 14) continue;
#pragma unroll
    for (int kw = 0; kw < 3; kw++) {
      int w2 = ww + kw - 1;
      if (w2 < 0 || w2 >= 14) continue;
      float4 v = *(const float4*)(base + (size_t)(h2 * 14 + w2) * DM + d0);
      int t = kh * 3 + kw;
      ax += v.x * w9[0][t]; ay += v.y * w9[1][t];
      az += v.z * w9[2][t]; aw += v.w * w9[3][t];
    }
  }
  float4 o = {ax, ay, az, aw};
  *(float4*)(T1 + (size_t)b * NPOS * DM + (size_t)n * DM + d0) = o;
}

// ---------------------------------------------------------------------------
// LayerNorm(384) f32 -> bf16, one wave per row (float2-vectorized)
// ---------------------------------------------------------------------------
__global__ __launch_bounds__(256) void ln_k(
    const float* __restrict__ in, const float* __restrict__ w,
    const float* __restrict__ bb, u16* __restrict__ out)
{
  int row = blockIdx.x * 4 + (threadIdx.x >> 6);
  int ln = threadIdx.x & 63;
  const float2* r = (const float2*)(in + (size_t)row * DM);
  float2 v[3]; float s = 0.f, sq = 0.f;
#pragma unroll
  for (int j = 0; j < 3; j++) {
    v[j] = r[ln + 64 * j];
    s += v[j].x + v[j].y; sq += v[j].x * v[j].x + v[j].y * v[j].y;
  }
#pragma unroll
  for (int o = 1; o < 64; o <<= 1) { s += __shfl_xor(s, o, 64); sq += __shfl_xor(sq, o, 64); }
  float mu = s * (1.f / 384.f);
  float var = sq * (1.f / 384.f) - mu * mu;
  float rs = rsqrtf(var + 1e-5f);
  uint32_t* orow = (uint32_t*)(out + (size_t)row * DM);
#pragma unroll
  for (int j = 0; j < 3; j++) {
    int d = (ln + 64 * j) * 2;
    float a = (v[j].x - mu) * rs * w[d] + bb[d];
    float bq = (v[j].y - mu) * rs * w[d + 1] + bb[d + 1];
    orow[ln + 64 * j] = (uint32_t)f2bf(a) | ((uint32_t)f2bf(bq) << 16);
  }
}

// ---------------------------------------------------------------------------
// Fused attention per (b,h), flash-style online softmax over 7 j-chunks of 32.
//   (unchanged from r8 — fell out of top-5)
// ---------------------------------------------------------------------------
__global__ __launch_bounds__(256) void attn_k(
    const u16* __restrict__ QKV, const float* __restrict__ tabG,
    u16* __restrict__ AO)
{
  __shared__ __align__(16) u16 Ks[4 * 196 * 8];     // [s][j][e] K fragments
  __shared__ __align__(16) u16 Vt[32 * 232];        // [d][j], pad j>=196 zero
  __shared__ __align__(16) u16 Pc4[4][4 * 16 * 8];  // per-wave P chunk (16x32)
  __shared__ __align__(16) u16 Ts[49 * 32];         // rpe table, [t][k] bf16
  __shared__ __align__(16) u16 Rw4[4][16 * 49];     // per-wave rpe scores bf16
  int bh = blockIdx.x; int b = bh / NH_, h = bh % NH_;
  int tid = threadIdx.x;
  int wv = tid >> 6, ln = tid & 63;
  int q = ln >> 4, c = ln & 15;
  size_t rowbase = (size_t)b * NPOS * 1152 + h * 32;

  // ---- stage K fragments via global_load_lds (wave-uniform dest) ----
  for (int cb = wv * 64; cb < 784; cb += 256) {
    int ch = cb + ln;
    if (ch < 784) {
      int s = ch / 196, j = ch - s * 196;
      GLDS16(QKV + rowbase + 384 + (size_t)j * 1152 + s * 8, &Ks[cb * 8]);
    }
  }
  // ---- stage rpe table transposed to [t][k] bf16 (once per block) ----
  for (int t = tid; t < 49 * 32; t += 256) {
    int tt = t >> 5, k = t & 31;
    Ts[t] = f2bf(tabG[k * 49 + tt]);
  }
  // ---- stage V transposed (vectorized): 784 chunks of 8 d-values ----
  for (int t = tid; t < 784; t += 256) {
    int nn = t >> 2, d0 = (t & 3) * 8;
    short8 v = *(const short8*)(QKV + rowbase + 768 + (size_t)nn * 1152 + d0);
#pragma unroll
    for (int j = 0; j < 8; j++) Vt[(d0 + j) * 232 + nn] = (u16)v[j];
  }
  for (int t = tid; t < 32 * 36; t += 256) {
    int d = t / 36, jj = t - d * 36;
    Vt[d * 232 + 196 + jj] = 0;
  }
  __syncthreads();

  u16* Pw = Pc4[wv];
  u16* Rw = Rw4[wv];

  for (int mt = wv; mt < 13; mt += 4) {
    int mb = mt * 16;
    int irow = mb + c; if (irow > 195) irow = 195;
    short8 afrag = *(const short8*)(QKV + rowbase + (size_t)irow * 1152 + q * 8);
    int i0 = mb + q * 4;

    // ---- rpe scores via MFMA -> Rw (table frags transient from LDS) ----
#pragma unroll
    for (int nt = 0; nt < 4; nt++) {
      int t = nt * 16 + c;
      int tt = t < 49 ? t : 48;
      short8 tb = *(const short8*)&Ts[tt * 32 + q * 8];
      f32x4 z = {0.f, 0.f, 0.f, 0.f};
      f32x4 rr = __builtin_amdgcn_mfma_f32_16x16x32_bf16(afrag, tb, z, 0, 0, 0);
      if (t < 49) {
#pragma unroll
        for (int e = 0; e < 4; e++)
          Rw[(q * 4 + e) * 49 + t] = f2bf(rr[e] * SCALE_Q);
      }
    }

    // row geometry (hoisted)
    int ri4[4], ci4[4];
#pragma unroll
    for (int e = 0; e < 4; e++) {
      int i = i0 + e; int ri = i / 14;
      ri4[e] = ri; ci4[e] = i - ri * 14;
    }

    float m[4], l[4];
    f32x4 oacc[2];
#pragma unroll
    for (int e = 0; e < 4; e++) { m[e] = -INFINITY; l[e] = 0.f; }
    oacc[0] = (f32x4){0.f, 0.f, 0.f, 0.f};
    oacc[1] = (f32x4){0.f, 0.f, 0.f, 0.f};

    // ---- online softmax over 7 chunks of 32 j ----
    for (int ck = 0; ck < 7; ck++) {
      // 2 QK MFMAs from Ks LDS
      f32x4 s01[2];
#pragma unroll
      for (int t = 0; t < 2; t++) {
        int j = (ck * 2 + t) * 16 + c;
        int jc = j > 195 ? 195 : j;
        short8 bfrag = *(const short8*)&Ks[(q * 196 + jc) * 8];
        f32x4 z = {0.f, 0.f, 0.f, 0.f};
        s01[t] = __builtin_amdgcn_mfma_f32_16x16x32_bf16(afrag, bfrag, z, 0, 0, 0);
      }
      // bias + mask
#pragma unroll
      for (int t = 0; t < 2; t++) {
        int j = (ck * 2 + t) * 16 + c;
        bool jok = (j < 196);
        int rj = j / 14, cj = j - rj * 14;
#pragma unroll
        for (int e = 0; e < 4; e++) {
          float sv = -1e30f;
          if (jok && (i0 + e) < 196) {
            int dr = ri4[e] - rj, dc = ci4[e] - cj;
            int adr = dr < 0 ? -dr : dr, adc = dc < 0 ? -dc : dc;
            int tr = adr <= 1 ? adr : (adr <= 3 ? 2 : 3);
            int tc = adc <= 1 ? adc : (adc <= 3 ? 2 : 3);
            int fr = dr < 0 ? -tr : tr, fc = dc < 0 ? -tc : tc;
            int bucket = fr * 7 + fc + 24;
            sv = s01[t][e] * SCALE_Q + bf2f(Rw[(q * 4 + e) * 49 + bucket]);
          }
          s01[t][e] = sv;
        }
      }
      // chunk max (16-lane group reduce) + online update
#pragma unroll
      for (int e = 0; e < 4; e++) {
        float mc = fmaxf(s01[0][e], s01[1][e]);
#pragma unroll
        for (int o = 1; o < 16; o <<= 1) mc = fmaxf(mc, __shfl_xor(mc, o, 64));
        float mn = fmaxf(m[e], mc);
        float sc = __expf(m[e] - mn);
        m[e] = mn;
        float p0 = __expf(s01[0][e] - mn);
        float p1 = __expf(s01[1][e] - mn);
        l[e] = l[e] * sc + p0 + p1;
        oacc[0][e] *= sc; oacc[1][e] *= sc;
        s01[0][e] = p0; s01[1][e] = p1;
      }
      // write P chunk in A-frag layout: slot = t*2 + (c>>3), row q*4+e, col c&7
#pragma unroll
      for (int t = 0; t < 2; t++) {
        int sl = t * 2 + (c >> 3);
#pragma unroll
        for (int e = 0; e < 4; e++)
          Pw[(sl * 16 + q * 4 + e) * 8 + (c & 7)] = f2bf(s01[t][e]);
      }
      // PV: 2 MFMAs (d halves), k = this chunk's 32 j
#pragma unroll
      for (int n2 = 0; n2 < 2; n2++) {
        short8 pa = *(const short8*)&Pw[(q * 16 + c) * 8];
        short8 vb = *(const short8*)&Vt[(n2 * 16 + c) * 232 + ck * 32 + q * 8];
        oacc[n2] = __builtin_amdgcn_mfma_f32_16x16x32_bf16(pa, vb, oacc[n2], 0, 0, 0);
      }
    }

    // final 1/l and store
    float inv[4];
#pragma unroll
    for (int e = 0; e < 4; e++) {
      float s2 = l[e];
#pragma unroll
      for (int o = 1; o < 16; o <<= 1) s2 += __shfl_xor(s2, o, 64);
      inv[e] = 1.f / s2;
    }
#pragma unroll
    for (int n2 = 0; n2 < 2; n2++) {
#pragma unroll
      for (int e = 0; e < 4; e++) {
        int i = i0 + e;
        if (i < 196) {
          int d = n2 * 16 + c;
          AO[((size_t)b * NPOS + i) * DM + h * 32 + d] = f2bf(oacc[n2][e] * inv[e]);
        }
      }
    }
  }
}

// ---------------------------------------------------------------------------
// BN1 over (batch, dmodel) per position n: two-stage stats
// ---------------------------------------------------------------------------
__global__ __launch_bounds__(256) void bn1_partial_k(
    const float* __restrict__ T3, float* __restrict__ part)
{
  int n = blockIdx.x >> 3, g = blockIdx.x & 7;
  int tid = threadIdx.x;
  float s = 0.f, sq = 0.f;
  for (int b2 = g * 16; b2 < g * 16 + 16; b2++) {
    const float* p = T3 + ((size_t)b2 * NPOS + n) * DM;
    for (int d = tid; d < DM; d += 256) { float v = p[d]; s += v; sq += v * v; }
  }
#pragma unroll
  for (int o = 1; o < 64; o <<= 1) { s += __shfl_xor(s, o, 64); sq += __shfl_xor(sq, o, 64); }
  __shared__ float ls[4], lq[4];
  int wv = tid >> 6, ln = tid & 63;
  if (ln == 0) { ls[wv] = s; lq[wv] = sq; }
  __syncthreads();
  if (tid == 0) {
    part[blockIdx.x * 2]     = ls[0] + ls[1] + ls[2] + ls[3];
    part[blockIdx.x * 2 + 1] = lq[0] + lq[1] + lq[2] + lq[3];
  }
}

__global__ __launch_bounds__(256) void bn1_finish_k(
    const float* __restrict__ part, const float* __restrict__ bw,
    const float* __restrict__ bbb, float* __restrict__ scaleArr,
    float* __restrict__ shiftArr)
{
  int n = threadIdx.x;
  if (n >= NPOS) return;
  float S = 0.f, Q = 0.f;
#pragma unroll
  for (int g = 0; g < 8; g++) { S += part[(n * 8 + g) * 2]; Q += part[(n * 8 + g) * 2 + 1]; }
  float mu = S / 49152.f;
  float var = Q / 49152.f - mu * mu;
  float rs = rsqrtf(var + 2e-5f);
  float sc = rs * bw[n];
  scaleArr[n] = sc;
  shiftArr[n] = bbb[n] - mu * sc;
}

__global__ __launch_bounds__(256) void bn1_apply_k(
    const float* __restrict__ T3, const float* __restrict__ scaleArr,
    const float* __restrict__ shiftArr, u16* __restrict__ outb)
{
  int idx = blockIdx.x * 256 + threadIdx.x;           // float4 index
  if (idx >= MT * DM / 4) return;
  int n = (idx / 96) % NPOS;
  float4 v = *(const float4*)(T3 + (size_t)idx * 4);
  float sc = scaleArr[n], sh = shiftArr[n];
  uint32_t p0 = (uint32_t)f2bf(v.x * sc + sh) | ((uint32_t)f2bf(v.y * sc + sh) << 16);
  uint32_t p1 = (uint32_t)f2bf(v.z * sc + sh) | ((uint32_t)f2bf(v.w * sc + sh) << 16);
  ((uint2*)outb)[idx] = make_uint2(p0, p1);
}

// ---------------------------------------------------------------------------
// split-K reduce for lin head + bias
// ---------------------------------------------------------------------------
__global__ __launch_bounds__(256) void lin_reduce_k(
    const float* __restrict__ part, const float* __restrict__ lb,
    float* __restrict__ y)
{
  int idx = blockIdx.x * 256 + threadIdx.x;
  if (idx >= 128 * DM) return;
  int col = idx % DM;
  float s = lb[col];
#pragma unroll
  for (int sp = 0; sp < 49; sp++) s += part[(size_t)sp * (128 * DM) + idx];
  y[idx] = s;
}

// ---------------------------------------------------------------------------
// BN2 over batch (128) per feature col, in-place on y
// ---------------------------------------------------------------------------
__global__ __launch_bounds__(64) void bn2_k(
    float* __restrict__ y, const float* __restrict__ w,
    const float* __restrict__ bb)
{
  int col = blockIdx.x; int ln = threadIdx.x;
  float v0 = y[(size_t)ln * DM + col];
  float v1 = y[(size_t)(ln + 64) * DM + col];
  float s = v0 + v1, sq = v0 * v0 + v1 * v1;
#pragma unroll
  for (int o = 1; o < 64; o <<= 1) { s += __shfl_xor(s, o, 64); sq += __shfl_xor(sq, o, 64); }
  float mu = s / 128.f;
  float var = sq / 128.f - mu * mu;
  float rs = rsqrtf(var + 2e-5f);
  float sc = rs * w[col], sh = bb[col] - mu * sc;
  y[(size_t)ln * DM + col] = v0 * sc + sh;
  y[(size_t)(ln + 64) * DM + col] = v1 * sc + sh;
}

// ---------------------------------------------------------------------------
// merged f32 -> bf16 cast for the six small weight matrices
// segment boundaries in float4 units
// ---------------------------------------------------------------------------
__global__ __launch_bounds__(256) void castall_k(
    const float* __restrict__ s0, u16* __restrict__ d0,
    const float* __restrict__ s1, u16* __restrict__ d1,
    const float* __restrict__ s2, u16* __restrict__ d2,
    const float* __restrict__ s3, u16* __restrict__ d3,
    const float* __restrict__ s4, u16* __restrict__ d4,
    const float* __restrict__ s5, u16* __restrict__ d5)
{
  const int b0 = 262144, b1 = b0 + 98304, b2 = b1 + 110592,
            b3 = b2 + 36864, b4 = b3 + 147456, b5 = b4 + 147456; // 802816
  int idx = blockIdx.x * 256 + threadIdx.x;
  int stride = gridDim.x * 256;
  for (; idx < b5; idx += stride) {
    const float* s; u16* d; int l;
    if      (idx < b0) { s = s0; d = d0; l = idx; }
    else if (idx < b1) { s = s1; d = d1; l = idx - b0; }
    else if (idx < b2) { s = s2; d = d2; l = idx - b1; }
    else if (idx < b3) { s = s3; d = d3; l = idx - b2; }
    else if (idx < b4) { s = s4; d = d4; l = idx - b3; }
    else               { s = s5; d = d5; l = idx - b4; }
    float4 v = *(const float4*)(s + (size_t)l * 4);
    uint32_t p0 = (uint32_t)f2bf(v.x) | ((uint32_t)f2bf(v.y) << 16);
    uint32_t p1 = (uint32_t)f2bf(v.z) | ((uint32_t)f2bf(v.w) << 16);
    ((uint2*)d)[l] = make_uint2(p0, p1);
  }
}

// ---------------------------------------------------------------------------
// Orchestration
// ---------------------------------------------------------------------------
extern "C" void kernel_launch(void* const* d_in, const int* in_sizes, int n_in,
                              void* d_out, int out_size, void* d_ws, size_t ws_size,
                              hipStream_t stream)
{
  (void)in_sizes; (void)n_in; (void)out_size;
  const float* x    = (const float*)d_in[0];
  const float* fc1w = (const float*)d_in[1];
  const float* fc1b = (const float*)d_in[2];
  const float* fc2w = (const float*)d_in[3];
  const float* fc2b = (const float*)d_in[4];
  const float* pcw  = (const float*)d_in[5];
  const float* pcb  = (const float*)d_in[6];
  const float* ln1w = (const float*)d_in[7];
  const float* ln1b = (const float*)d_in[8];
  const float* qkvw = (const float*)d_in[9];
  const float* rpet = (const float*)d_in[10];
  const float* projw= (const float*)d_in[11];
  const float* projb= (const float*)d_in[12];
  const float* ln2w = (const float*)d_in[13];
  const float* ln2b = (const float*)d_in[14];
  const float* m1w  = (const float*)d_in[15];
  const float* m1b  = (const float*)d_in[16];
  const float* m2w  = (const float*)d_in[17];
  const float* m2b  = (const float*)d_in[18];
  const float* bn1w = (const float*)d_in[19];
  const float* bn1b = (const float*)d_in[20];
  const float* linw = (const float*)d_in[21];
  const float* linb = (const float*)d_in[22];
  const float* bn2w = (const float*)d_in[23];
  const float* bn2b = (const float*)d_in[24];
  float* y = (float*)d_out;

  // -------- aliased workspace layout (regions share by liveness) ----------
  const size_t RA = 0;                      // At / MLP1
  const size_t RB = 77070336;               // U / QKV / T3nb
  const size_t RC = RB + 57802752;          // H / AO / H2
  const size_t RD = RC + 19267584;          // T0 / T2
  const size_t RE = RD + 38535168;          // T1 / T3
  const size_t RF = RE + 38535168;          // PART (lin split-K)
  const size_t RG = RF + 9633792;           // small bf16 weights
  const size_t RS = RG + 6422528;           // bn1 scale/shift + partials
  const size_t NEED = RS + 2048 + 16384;
  if (ws_size < NEED) return;

  char* ws = (char*)d_ws;
  u16*   At    = (u16*)(ws + RA);
  u16*   MLP1  = (u16*)(ws + RA);
  u16*   U     = (u16*)(ws + RB);
  u16*   QKV   = (u16*)(ws + RB);
  u16*   T3nb  = (u16*)(ws + RB);
  u16*   H     = (u16*)(ws + RC);
  u16*   AO    = (u16*)(ws + RC);
  u16*   H2    = (u16*)(ws + RC);
  float* T0    = (float*)(ws + RD);
  float* T2    = (float*)(ws + RD);
  float* T1    = (float*)(ws + RE);
  float* T3    = (float*)(ws + RE);
  float* PART  = (float*)(ws + RF);
  u16*   wb_fc1 = (u16*)(ws + RG);
  u16*   wb_fc2 = wb_fc1 + 1048576;
  u16*   wb_qkv = wb_fc2 + 393216;
  u16*   wb_proj= wb_qkv + 442368;
  u16*   wb_m1  = wb_proj + 147456;
  u16*   wb_m2  = wb_m1 + 589824;
  float* bnS   = (float*)(ws + RS);
  float* bnSh  = bnS + 196;
  float* bnP   = (float*)(ws + RS + 2048);

  // weight casts (f32 -> bf16), one merged kernel
  castall_k<<<1024, 256, 0, stream>>>(fc1w, wb_fc1, fc2w, wb_fc2, qkvw, wb_qkv,
                                      projw, wb_proj, m1w, wb_m1, m2w, wb_m2);

  // x (B,CIN,N) -> At (B*N, CIN) bf16
  transpose_cast_k<<<dim3(32, 7, 128), dim3(32, 8), 0, stream>>>(x, At);

  // embed fc1: U = relu6(At @ fc1w^T + b)   [25088 x 1024]
  gemm_k<0><<<196 * 8, 256, 0, stream>>>(At, wb_fc1, fc1b, nullptr, U,
                                          MT, 1024, 1024, 1024, 1024, 8, 0);
  // embed fc2: T0 = U @ fc2w^T + b          [25088 x 384] f32
  gemm_k<1><<<196 * 3, 256, 0, stream>>>(U, wb_fc2, fc2b, nullptr, T0,
                                          MT, 384, 1024, 1024, 1024, 3, 0);
  // depthwise conv + bias + residual -> T1
  conv_res_k<<<(B_ * NPOS * 96 + 255) / 256, 256, 0, stream>>>(T0, pcw, pcb, T1);
  // LN1 -> H (bf16)
  ln_k<<<MT / 4, 256, 0, stream>>>(T1, ln1w, ln1b, H);
  // qkv: QKV = H @ qkvw^T (no bias)          [25088 x 1152] bf16
  gemm_k<2><<<196 * 9, 256, 0, stream>>>(H, wb_qkv, nullptr, nullptr, QKV,
                                          MT, 1152, 384, 384, 384, 9, 0);
  // fused attention (rpe in-kernel, flash-style) -> AO (bf16)
  attn_k<<<1536, 256, 0, stream>>>(QKV, rpet, AO);
  // proj + residual(T1) -> T2 (f32)
  gemm_k<3><<<196 * 3, 256, 0, stream>>>(AO, wb_proj, projb, T1, T2,
                                          MT, 384, 384, 384, 384, 3, 0);
  // LN2 -> H2 (bf16)
  ln_k<<<MT / 4, 256, 0, stream>>>(T2, ln2w, ln2b, H2);
  // mlp fc1: MLP1 = relu6(H2 @ m1w^T + b)    [25088 x 1536] bf16
  gemm_k<0><<<196 * 12, 256, 0, stream>>>(H2, wb_m1, m1b, nullptr, MLP1,
                                           MT, 1536, 384, 384, 384, 12, 0);
  // mlp fc2 + residual(T2) -> T3 (f32)
  gemm_k<3><<<196 * 3, 256, 0, stream>>>(MLP1, wb_m2, m2b, T2, T3,
                                          MT, 384, 1536, 1536, 1536, 3, 0);
  // BN1 (per position) -> T3nb (bf16)
  bn1_partial_k<<<196 * 8, 256, 0, stream>>>(T3, bnP);
  bn1_finish_k<<<1, 256, 0, stream>>>(bnP, bn1w, bn1b, bnS, bnSh);
  bn1_apply_k<<<(MT * DM / 4 + 255) / 256, 256, 0, stream>>>(T3, bnS, bnSh, T3nb);
  // lin head: y = T3nb(128 x 75264) @ linw^T, split-K 49 x 1536 (W f32 direct)
  gemm_k<4><<<3 * 49, 256, 0, stream>>>(T3nb, linw, nullptr, nullptr, PART,
                                         128, 384, 1536, 75264, 75264, 3, 1536);
  lin_reduce_k<<<192, 256, 0, stream>>>(PART, linb, y);
  // BN2 (per feature over batch), in place on d_out
  bn2_k<<<384, 64, 0, stream>>>(y, bn2w, bn2b);
}

// Round 10
// 752.896 us; speedup vs baseline: 1.2824x; 1.0418x over previous
//
#include <hip/hip_runtime.h>
#include <cstdint>

// ---------------------------------------------------------------------------
// Problem constants
// ---------------------------------------------------------------------------
#define B_    128
#define CIN   1024
#define NPOS  196          // 14*14
#define DM    384
#define NH_   12
#define HD_   32
#define DFF_  1536
#define MT    25088        // B_*NPOS
#define SCALE_Q 0.17677669529663687f   // 1/sqrt(32)

typedef unsigned short u16;
typedef __attribute__((ext_vector_type(8))) short  short8;   // 8 bf16 (4 VGPR)
typedef __attribute__((ext_vector_type(4))) float  f32x4;    // MFMA C/D

__device__ __forceinline__ u16 f2bf(float f) {
  union { float f; uint32_t u; } v; v.f = f;
  uint32_t u = v.u;
  return (u16)((u + 0x7fffu + ((u >> 16) & 1u)) >> 16);
}
__device__ __forceinline__ float bf2f(u16 h) {
  union { uint32_t u; float f; } v; v.u = ((uint32_t)h) << 16;
  return v.f;
}

#define GLDS16(g, l)                                                           \
  __builtin_amdgcn_global_load_lds(                                            \
      (const __attribute__((address_space(1))) void*)(g),                      \
      (__attribute__((address_space(3))) void*)(l), 16, 0, 0)

// ---------------------------------------------------------------------------
// Generic bf16 MFMA GEMM:  out = epi( A[M x K] * W[N x K]^T )
// 128x128 tile, 4 waves (2x2 of 64x64), BK=64, 32 MFMA / K-step.
// r10 schedule (MODE != 4), counted-vmcnt pipeline (T4):
//   frags(cur)->regs; lgkmcnt(0); barrier; STAGE(t+2, cur); MFMA;
//   vmcnt(8); barrier.   Loads issued at t are consumed at t+2 (two full
//   iterations in flight); vmcnt never drains to 0 in the main loop.
//   Correctness: every wave issues the same 8 loads/tile and waits its own
//   vmcnt(8) BEFORE the barrier -> at barrier exit tile t+1 fully in LDS.
// MODE 4 (mixed vmem+ds_write staging) keeps a simple drain schedule.
// XCD-chunked bijective blockIdx swizzle (r9): A-band reuse within one L2.
// ---------------------------------------------------------------------------
template <int MODE>
__global__ __launch_bounds__(256) void gemm_k(
    const u16* __restrict__ A, const void* __restrict__ Wv,
    const float* __restrict__ bias, const float* __restrict__ res,
    void* __restrict__ outp,
    int M, int N, int K, int lda, int ldw, int nTN, int splitK)
{
  __shared__ __align__(16) u16 As[2][8 * 128 * 8];   // dbuf [s][r][8]
  __shared__ __align__(16) u16 Bs[2][8 * 128 * 8];

  // ---- bijective XCD-chunked swizzle ----
  int nwg = gridDim.x;
  int bid0 = blockIdx.x;
  int qq = nwg >> 3, rr = nwg & 7;
  int xcd = bid0 & 7, idx = bid0 >> 3;
  int bid = (xcd < rr ? xcd * (qq + 1) : rr * (qq + 1) + (xcd - rr) * qq) + idx;

  int split = 0, mT, nT;
  if (MODE == 4) { split = bid / nTN; nT = bid % nTN; mT = 0; }
  else           { mT = bid / nTN;    nT = bid % nTN; }

  const u16* Ab = A + (size_t)split * splitK;
  float* outF = (float*)outp + ((MODE == 4) ? (size_t)split * (size_t)M * N : (size_t)0);
  u16*   outU = (u16*)outp;

  int tid = threadIdx.x;
  int wv = tid >> 6, ln = tid & 63;
  int q = ln >> 4, c = ln & 15;
  int wr = wv >> 1, wc = wv & 1;
  int mBase = mT * 128, nBase = nT * 128;

  f32x4 acc[4][4];
#pragma unroll
  for (int i = 0; i < 4; i++)
#pragma unroll
    for (int j = 0; j < 4; j++) acc[i][j] = (f32x4){0.f, 0.f, 0.f, 0.f};

  const u16* Ag = Ab + (size_t)mBase * lda;
  const u16*  Wg16 = (const u16*)Wv + (size_t)split * splitK + (size_t)nBase * ldw;
  const float* Wg32 = (const float*)Wv + (size_t)split * splitK + (size_t)nBase * ldw;

  auto STAGE = [&](int t, int buf) {
    int k0 = t * 64;
#pragma unroll
    for (int i = 0; i < 4; i++) {
      int ch = wv * 4 + i;             // chunk 0..15 (1024B each)
      int s = ch >> 1;                 // k-slot (8 bf16), 0..7
      int r = (ch & 1) * 64 + ln;      // tile row
      GLDS16(Ag + (size_t)r * lda + (k0 + s * 8), &As[buf][ch * 512]);
      if constexpr (MODE == 4) {
        const float* wp = Wg32 + (size_t)r * ldw + (k0 + s * 8);
        float4 f0 = *(const float4*)wp, f1 = *(const float4*)(wp + 4);
        short8 pk;
        pk[0] = (short)f2bf(f0.x); pk[1] = (short)f2bf(f0.y);
        pk[2] = (short)f2bf(f0.z); pk[3] = (short)f2bf(f0.w);
        pk[4] = (short)f2bf(f1.x); pk[5] = (short)f2bf(f1.y);
        pk[6] = (short)f2bf(f1.z); pk[7] = (short)f2bf(f1.w);
        *(short8*)&Bs[buf][ch * 512 + ln * 8] = pk;
      } else {
        GLDS16(Wg16 + (size_t)r * ldw + (k0 + s * 8), &Bs[buf][ch * 512]);
      }
    }
  };

  int NT = K >> 6;   // K-steps of 64 (all K are multiples of 64)

  // ---- prologue ----
  if constexpr (MODE == 4) {
    STAGE(0, 0);
    asm volatile("s_waitcnt vmcnt(0) lgkmcnt(0)" ::: "memory");
  } else {
    STAGE(0, 0);
    if (NT > 1) {
      STAGE(1, 1);
      asm volatile("s_waitcnt vmcnt(8)" ::: "memory");   // tile 0 complete
    } else {
      asm volatile("s_waitcnt vmcnt(0)" ::: "memory");
    }
  }
  __builtin_amdgcn_s_barrier();

  int cur = 0;
  for (int t = 0; t < NT; ++t) {
    // ---- all fragments of tile t -> registers (frees LDS buffer early) ----
    short8 afr[2][4], bfr[2][4];
#pragma unroll
    for (int kk = 0; kk < 2; kk++) {
#pragma unroll
      for (int mt2 = 0; mt2 < 4; mt2++)
        afr[kk][mt2] = *(const short8*)&As[cur][(((kk * 4 + q) * 128) + wr * 64 + mt2 * 16 + c) * 8];
#pragma unroll
      for (int nt2 = 0; nt2 < 4; nt2++)
        bfr[kk][nt2] = *(const short8*)&Bs[cur][(((kk * 4 + q) * 128) + wc * 64 + nt2 * 16 + c) * 8];
    }
    asm volatile("s_waitcnt lgkmcnt(0)" ::: "memory");
    __builtin_amdgcn_sched_barrier(0);
    __builtin_amdgcn_s_barrier();          // all waves done reading buffer cur

    if constexpr (MODE == 4) {
      if (t + 1 < NT) STAGE(t + 1, cur ^ 1);
      __builtin_amdgcn_sched_barrier(0);
#pragma unroll
      for (int kk = 0; kk < 2; kk++)
#pragma unroll
        for (int mt2 = 0; mt2 < 4; mt2++)
#pragma unroll
          for (int nt2 = 0; nt2 < 4; nt2++)
            acc[mt2][nt2] = __builtin_amdgcn_mfma_f32_16x16x32_bf16(
                afr[kk][mt2], bfr[kk][nt2], acc[mt2][nt2], 0, 0, 0);
      if (t + 1 < NT) {
        asm volatile("s_waitcnt vmcnt(0) lgkmcnt(0)" ::: "memory");
        __builtin_amdgcn_s_barrier();
        cur ^= 1;
      }
    } else {
      if (t + 2 < NT) STAGE(t + 2, cur);   // refill the buffer just freed
      __builtin_amdgcn_sched_barrier(0);
#pragma unroll
      for (int kk = 0; kk < 2; kk++)
#pragma unroll
        for (int mt2 = 0; mt2 < 4; mt2++)
#pragma unroll
          for (int nt2 = 0; nt2 < 4; nt2++)
            acc[mt2][nt2] = __builtin_amdgcn_mfma_f32_16x16x32_bf16(
                afr[kk][mt2], bfr[kk][nt2], acc[mt2][nt2], 0, 0, 0);
      if (t + 1 < NT) {
        if (t + 2 < NT)
          asm volatile("s_waitcnt vmcnt(8)" ::: "memory");  // t+1 done; t+2 in flight
        else
          asm volatile("s_waitcnt vmcnt(0)" ::: "memory");
        __builtin_amdgcn_s_barrier();
        cur ^= 1;
      }
    }
  }

  // ---- epilogue ----
#pragma unroll
  for (int mt2 = 0; mt2 < 4; mt2++) {
    int row0 = mBase + wr * 64 + mt2 * 16 + q * 4;
#pragma unroll
    for (int nt2 = 0; nt2 < 4; nt2++) {
      int col = nBase + wc * 64 + nt2 * 16 + c;
      float bv = (MODE == 0 || MODE == 1 || MODE == 3) ? bias[col] : 0.f;
      f32x4 v = acc[mt2][nt2];
#pragma unroll
      for (int e = 0; e < 4; e++) {
        int row = row0 + e;
        float x = v[e] + bv;
        if (MODE == 0) x = fminf(fmaxf(x, 0.f), 6.f);
        if (MODE == 3) x += res[(size_t)row * N + col];
        if (MODE == 0 || MODE == 2) outU[(size_t)row * N + col] = f2bf(x);
        else                        outF[(size_t)row * N + col] = x;
      }
    }
  }
}

// ---------------------------------------------------------------------------
// x (B, CIN, HW, HW) f32  ->  A_t (B*NPOS, CIN) bf16
// ---------------------------------------------------------------------------
__global__ __launch_bounds__(256) void transpose_cast_k(
    const float* __restrict__ x, u16* __restrict__ At)
{
  __shared__ float t[32][33];
  int c0 = blockIdx.x * 32, n0 = blockIdx.y * 32, b = blockIdx.z;
  int tx = threadIdx.x, ty = threadIdx.y;
  const float* xb = x + (size_t)b * CIN * NPOS;
#pragma unroll
  for (int i = 0; i < 4; i++) {
    int cc = c0 + ty + i * 8, nn = n0 + tx;
    t[ty + i * 8][tx] = (nn < NPOS) ? xb[(size_t)cc * NPOS + nn] : 0.f;
  }
  __syncthreads();
  u16* Ab = At + (size_t)b * NPOS * CIN;
#pragma unroll
  for (int i = 0; i < 4; i++) {
    int nn = n0 + ty + i * 8, cc = c0 + tx;
    if (nn < NPOS) Ab[(size_t)nn * CIN + cc] = f2bf(t[tx][ty + i * 8]);
  }
}

// ---------------------------------------------------------------------------
// depthwise 3x3 SAME conv + bias + identity residual (fp32)
// ---------------------------------------------------------------------------
__global__ __launch_bounds__(256) void conv_res_k(
    const float* __restrict__ T0, const float* __restrict__ pcw,
    const float* __restrict__ pcb, float* __restrict__ T1)
{
  int idx = blockIdx.x * 256 + threadIdx.x;
  if (idx >= B_ * NPOS * 96) return;
  int d4 = idx % 96; int rem = idx / 96;
  int n = rem % NPOS; int b = rem / NPOS;
  int hh = n / 14, ww = n % 14;
  int d0 = d4 * 4;
  float w9[4][9];
#pragma unroll
  for (int j = 0; j < 4; j++)
#pragma unroll
    for (int t = 0; t < 9; t++) w9[j][t] = pcw[(d0 + j) * 9 + t];
  const float* base = T0 + (size_t)b * NPOS * DM;
  float4 ctr = *(const float4*)(base + (size_t)n * DM + d0);
  float ax = ctr.x + pcb[d0], ay = ctr.y + pcb[d0 + 1];
  float az = ctr.z + pcb[d0 + 2], aw = ctr.w + pcb[d0 + 3];
#pragma unroll
  for (int kh = 0; kh < 3; kh++) {
    int h2 = hh + kh - 1;
    if (h2 < 0 || h2 >= 14) continue;
#pragma unroll
    for (int kw = 0; kw < 3; kw++) {
      int w2 = ww + kw - 1;
      if (w2 < 0 || w2 >= 14) continue;
      float4 v = *(const float4*)(base + (size_t)(h2 * 14 + w2) * DM + d0);
      int t = kh * 3 + kw;
      ax += v.x * w9[0][t]; ay += v.y * w9[1][t];
      az += v.z * w9[2][t]; aw += v.w * w9[3][t];
    }
  }
  float4 o = {ax, ay, az, aw};
  *(float4*)(T1 + (size_t)b * NPOS * DM + (size_t)n * DM + d0) = o;
}

// ---------------------------------------------------------------------------
// LayerNorm(384) f32 -> bf16, one wave per row (float2-vectorized)
// ---------------------------------------------------------------------------
__global__ __launch_bounds__(256) void ln_k(
    const float* __restrict__ in, const float* __restrict__ w,
    const float* __restrict__ bb, u16* __restrict__ out)
{
  int row = blockIdx.x * 4 + (threadIdx.x >> 6);
  int ln = threadIdx.x & 63;
  const float2* r = (const float2*)(in + (size_t)row * DM);
  float2 v[3]; float s = 0.f, sq = 0.f;
#pragma unroll
  for (int j = 0; j < 3; j++) {
    v[j] = r[ln + 64 * j];
    s += v[j].x + v[j].y; sq += v[j].x * v[j].x + v[j].y * v[j].y;
  }
#pragma unroll
  for (int o = 1; o < 64; o <<= 1) { s += __shfl_xor(s, o, 64); sq += __shfl_xor(sq, o, 64); }
  float mu = s * (1.f / 384.f);
  float var = sq * (1.f / 384.f) - mu * mu;
  float rs = rsqrtf(var + 1e-5f);
  uint32_t* orow = (uint32_t*)(out + (size_t)row * DM);
#pragma unroll
  for (int j = 0; j < 3; j++) {
    int d = (ln + 64 * j) * 2;
    float a = (v[j].x - mu) * rs * w[d] + bb[d];
    float bq = (v[j].y - mu) * rs * w[d + 1] + bb[d + 1];
    orow[ln + 64 * j] = (uint32_t)f2bf(a) | ((uint32_t)f2bf(bq) << 16);
  }
}

// ---------------------------------------------------------------------------
// Fused attention per (b,h), flash-style online softmax over 7 j-chunks of 32.
//   (unchanged from r8 — out of top-5)
// ---------------------------------------------------------------------------
__global__ __launch_bounds__(256) void attn_k(
    const u16* __restrict__ QKV, const float* __restrict__ tabG,
    u16* __restrict__ AO)
{
  __shared__ __align__(16) u16 Ks[4 * 196 * 8];     // [s][j][e] K fragments
  __shared__ __align__(16) u16 Vt[32 * 232];        // [d][j], pad j>=196 zero
  __shared__ __align__(16) u16 Pc4[4][4 * 16 * 8];  // per-wave P chunk (16x32)
  __shared__ __align__(16) u16 Ts[49 * 32];         // rpe table, [t][k] bf16
  __shared__ __align__(16) u16 Rw4[4][16 * 49];     // per-wave rpe scores bf16
  int bh = blockIdx.x; int b = bh / NH_, h = bh % NH_;
  int tid = threadIdx.x;
  int wv = tid >> 6, ln = tid & 63;
  int q = ln >> 4, c = ln & 15;
  size_t rowbase = (size_t)b * NPOS * 1152 + h * 32;

  // ---- stage K fragments via global_load_lds (wave-uniform dest) ----
  for (int cb = wv * 64; cb < 784; cb += 256) {
    int ch = cb + ln;
    if (ch < 784) {
      int s = ch / 196, j = ch - s * 196;
      GLDS16(QKV + rowbase + 384 + (size_t)j * 1152 + s * 8, &Ks[cb * 8]);
    }
  }
  // ---- stage rpe table transposed to [t][k] bf16 (once per block) ----
  for (int t = tid; t < 49 * 32; t += 256) {
    int tt = t >> 5, k = t & 31;
    Ts[t] = f2bf(tabG[k * 49 + tt]);
  }
  // ---- stage V transposed (vectorized): 784 chunks of 8 d-values ----
  for (int t = tid; t < 784; t += 256) {
    int nn = t >> 2, d0 = (t & 3) * 8;
    short8 v = *(const short8*)(QKV + rowbase + 768 + (size_t)nn * 1152 + d0);
#pragma unroll
    for (int j = 0; j < 8; j++) Vt[(d0 + j) * 232 + nn] = (u16)v[j];
  }
  for (int t = tid; t < 32 * 36; t += 256) {
    int d = t / 36, jj = t - d * 36;
    Vt[d * 232 + 196 + jj] = 0;
  }
  __syncthreads();

  u16* Pw = Pc4[wv];
  u16* Rw = Rw4[wv];

  for (int mt = wv; mt < 13; mt += 4) {
    int mb = mt * 16;
    int irow = mb + c; if (irow > 195) irow = 195;
    short8 afrag = *(const short8*)(QKV + rowbase + (size_t)irow * 1152 + q * 8);
    int i0 = mb + q * 4;

    // ---- rpe scores via MFMA -> Rw (table frags transient from LDS) ----
#pragma unroll
    for (int nt = 0; nt < 4; nt++) {
      int t = nt * 16 + c;
      int tt = t < 49 ? t : 48;
      short8 tb = *(const short8*)&Ts[tt * 32 + q * 8];
      f32x4 z = {0.f, 0.f, 0.f, 0.f};
      f32x4 rr = __builtin_amdgcn_mfma_f32_16x16x32_bf16(afrag, tb, z, 0, 0, 0);
      if (t < 49) {
#pragma unroll
        for (int e = 0; e < 4; e++)
          Rw[(q * 4 + e) * 49 + t] = f2bf(rr[e] * SCALE_Q);
      }
    }

    // row geometry (hoisted)
    int ri4[4], ci4[4];
#pragma unroll
    for (int e = 0; e < 4; e++) {
      int i = i0 + e; int ri = i / 14;
      ri4[e] = ri; ci4[e] = i - ri * 14;
    }

    float m[4], l[4];
    f32x4 oacc[2];
#pragma unroll
    for (int e = 0; e < 4; e++) { m[e] = -INFINITY; l[e] = 0.f; }
    oacc[0] = (f32x4){0.f, 0.f, 0.f, 0.f};
    oacc[1] = (f32x4){0.f, 0.f, 0.f, 0.f};

    // ---- online softmax over 7 chunks of 32 j ----
    for (int ck = 0; ck < 7; ck++) {
      // 2 QK MFMAs from Ks LDS
      f32x4 s01[2];
#pragma unroll
      for (int t = 0; t < 2; t++) {
        int j = (ck * 2 + t) * 16 + c;
        int jc = j > 195 ? 195 : j;
        short8 bfrag = *(const short8*)&Ks[(q * 196 + jc) * 8];
        f32x4 z = {0.f, 0.f, 0.f, 0.f};
        s01[t] = __builtin_amdgcn_mfma_f32_16x16x32_bf16(afrag, bfrag, z, 0, 0, 0);
      }
      // bias + mask
#pragma unroll
      for (int t = 0; t < 2; t++) {
        int j = (ck * 2 + t) * 16 + c;
        bool jok = (j < 196);
        int rj = j / 14, cj = j - rj * 14;
#pragma unroll
        for (int e = 0; e < 4; e++) {
          float sv = -1e30f;
          if (jok && (i0 + e) < 196) {
            int dr = ri4[e] - rj, dc = ci4[e] - cj;
            int adr = dr < 0 ? -dr : dr, adc = dc < 0 ? -dc : dc;
            int tr = adr <= 1 ? adr : (adr <= 3 ? 2 : 3);
            int tc = adc <= 1 ? adc : (adc <= 3 ? 2 : 3);
            int fr = dr < 0 ? -tr : tr, fc = dc < 0 ? -tc : tc;
            int bucket = fr * 7 + fc + 24;
            sv = s01[t][e] * SCALE_Q + bf2f(Rw[(q * 4 + e) * 49 + bucket]);
          }
          s01[t][e] = sv;
        }
      }
      // chunk max (16-lane group reduce) + online update
#pragma unroll
      for (int e = 0; e < 4; e++) {
        float mc = fmaxf(s01[0][e], s01[1][e]);
#pragma unroll
        for (int o = 1; o < 16; o <<= 1) mc = fmaxf(mc, __shfl_xor(mc, o, 64));
        float mn = fmaxf(m[e], mc);
        float sc = __expf(m[e] - mn);
        m[e] = mn;
        float p0 = __expf(s01[0][e] - mn);
        float p1 = __expf(s01[1][e] - mn);
        l[e] = l[e] * sc + p0 + p1;
        oacc[0][e] *= sc; oacc[1][e] *= sc;
        s01[0][e] = p0; s01[1][e] = p1;
      }
      // write P chunk in A-frag layout: slot = t*2 + (c>>3), row q*4+e, col c&7
#pragma unroll
      for (int t = 0; t < 2; t++) {
        int sl = t * 2 + (c >> 3);
#pragma unroll
        for (int e = 0; e < 4; e++)
          Pw[(sl * 16 + q * 4 + e) * 8 + (c & 7)] = f2bf(s01[t][e]);
      }
      // PV: 2 MFMAs (d halves), k = this chunk's 32 j
#pragma unroll
      for (int n2 = 0; n2 < 2; n2++) {
        short8 pa = *(const short8*)&Pw[(q * 16 + c) * 8];
        short8 vb = *(const short8*)&Vt[(n2 * 16 + c) * 232 + ck * 32 + q * 8];
        oacc[n2] = __builtin_amdgcn_mfma_f32_16x16x32_bf16(pa, vb, oacc[n2], 0, 0, 0);
      }
    }

    // final 1/l and store
    float inv[4];
#pragma unroll
    for (int e = 0; e < 4; e++) {
      float s2 = l[e];
#pragma unroll
      for (int o = 1; o < 16; o <<= 1) s2 += __shfl_xor(s2, o, 64);
      inv[e] = 1.f / s2;
    }
#pragma unroll
    for (int n2 = 0; n2 < 2; n2++) {
#pragma unroll
      for (int e = 0; e < 4; e++) {
        int i = i0 + e;
        if (i < 196) {
          int d = n2 * 16 + c;
          AO[((size_t)b * NPOS + i) * DM + h * 32 + d] = f2bf(oacc[n2][e] * inv[e]);
        }
      }
    }
  }
}

// ---------------------------------------------------------------------------
// BN1 over (batch, dmodel) per position n: two-stage stats
// ---------------------------------------------------------------------------
__global__ __launch_bounds__(256) void bn1_partial_k(
    const float* __restrict__ T3, float* __restrict__ part)
{
  int n = blockIdx.x >> 3, g = blockIdx.x & 7;
  int tid = threadIdx.x;
  float s = 0.f, sq = 0.f;
  for (int b2 = g * 16; b2 < g * 16 + 16; b2++) {
    const float* p = T3 + ((size_t)b2 * NPOS + n) * DM;
    for (int d = tid; d < DM; d += 256) { float v = p[d]; s += v; sq += v * v; }
  }
#pragma unroll
  for (int o = 1; o < 64; o <<= 1) { s += __shfl_xor(s, o, 64); sq += __shfl_xor(sq, o, 64); }
  __shared__ float ls[4], lq[4];
  int wv = tid >> 6, ln = tid & 63;
  if (ln == 0) { ls[wv] = s; lq[wv] = sq; }
  __syncthreads();
  if (tid == 0) {
    part[blockIdx.x * 2]     = ls[0] + ls[1] + ls[2] + ls[3];
    part[blockIdx.x * 2 + 1] = lq[0] + lq[1] + lq[2] + lq[3];
  }
}

__global__ __launch_bounds__(256) void bn1_finish_k(
    const float* __restrict__ part, const float* __restrict__ bw,
    const float* __restrict__ bbb, float* __restrict__ scaleArr,
    float* __restrict__ shiftArr)
{
  int n = threadIdx.x;
  if (n >= NPOS) return;
  float S = 0.f, Q = 0.f;
#pragma unroll
  for (int g = 0; g < 8; g++) { S += part[(n * 8 + g) * 2]; Q += part[(n * 8 + g) * 2 + 1]; }
  float mu = S / 49152.f;
  float var = Q / 49152.f - mu * mu;
  float rs = rsqrtf(var + 2e-5f);
  float sc = rs * bw[n];
  scaleArr[n] = sc;
  shiftArr[n] = bbb[n] - mu * sc;
}

__global__ __launch_bounds__(256) void bn1_apply_k(
    const float* __restrict__ T3, const float* __restrict__ scaleArr,
    const float* __restrict__ shiftArr, u16* __restrict__ outb)
{
  int idx = blockIdx.x * 256 + threadIdx.x;           // float4 index
  if (idx >= MT * DM / 4) return;
  int n = (idx / 96) % NPOS;
  float4 v = *(const float4*)(T3 + (size_t)idx * 4);
  float sc = scaleArr[n], sh = shiftArr[n];
  uint32_t p0 = (uint32_t)f2bf(v.x * sc + sh) | ((uint32_t)f2bf(v.y * sc + sh) << 16);
  uint32_t p1 = (uint32_t)f2bf(v.z * sc + sh) | ((uint32_t)f2bf(v.w * sc + sh) << 16);
  ((uint2*)outb)[idx] = make_uint2(p0, p1);
}

// ---------------------------------------------------------------------------
// split-K reduce for lin head + bias
// ---------------------------------------------------------------------------
__global__ __launch_bounds__(256) void lin_reduce_k(
    const float* __restrict__ part, const float* __restrict__ lb,
    float* __restrict__ y)
{
  int idx = blockIdx.x * 256 + threadIdx.x;
  if (idx >= 128 * DM) return;
  int col = idx % DM;
  float s = lb[col];
#pragma unroll
  for (int sp = 0; sp < 49; sp++) s += part[(size_t)sp * (128 * DM) + idx];
  y[idx] = s;
}

// ---------------------------------------------------------------------------
// BN2 over batch (128) per feature col, in-place on y
// ---------------------------------------------------------------------------
__global__ __launch_bounds__(64) void bn2_k(
    float* __restrict__ y, const float* __restrict__ w,
    const float* __restrict__ bb)
{
  int col = blockIdx.x; int ln = threadIdx.x;
  float v0 = y[(size_t)ln * DM + col];
  float v1 = y[(size_t)(ln + 64) * DM + col];
  float s = v0 + v1, sq = v0 * v0 + v1 * v1;
#pragma unroll
  for (int o = 1; o < 64; o <<= 1) { s += __shfl_xor(s, o, 64); sq += __shfl_xor(sq, o, 64); }
  float mu = s / 128.f;
  float var = sq / 128.f - mu * mu;
  float rs = rsqrtf(var + 2e-5f);
  float sc = rs * w[col], sh = bb[col] - mu * sc;
  y[(size_t)ln * DM + col] = v0 * sc + sh;
  y[(size_t)(ln + 64) * DM + col] = v1 * sc + sh;
}

// ---------------------------------------------------------------------------
// merged f32 -> bf16 cast for the six small weight matrices
// ---------------------------------------------------------------------------
__global__ __launch_bounds__(256) void castall_k(
    const float* __restrict__ s0, u16* __restrict__ d0,
    const float* __restrict__ s1, u16* __restrict__ d1,
    const float* __restrict__ s2, u16* __restrict__ d2,
    const float* __restrict__ s3, u16* __restrict__ d3,
    const float* __restrict__ s4, u16* __restrict__ d4,
    const float* __restrict__ s5, u16* __restrict__ d5)
{
  const int b0 = 262144, b1 = b0 + 98304, b2 = b1 + 110592,
            b3 = b2 + 36864, b4 = b3 + 147456, b5 = b4 + 147456; // 802816
  int idx = blockIdx.x * 256 + threadIdx.x;
  int stride = gridDim.x * 256;
  for (; idx < b5; idx += stride) {
    const float* s; u16* d; int l;
    if      (idx < b0) { s = s0; d = d0; l = idx; }
    else if (idx < b1) { s = s1; d = d1; l = idx - b0; }
    else if (idx < b2) { s = s2; d = d2; l = idx - b1; }
    else if (idx < b3) { s = s3; d = d3; l = idx - b2; }
    else if (idx < b4) { s = s4; d = d4; l = idx - b3; }
    else               { s = s5; d = d5; l = idx - b4; }
    float4 v = *(const float4*)(s + (size_t)l * 4);
    uint32_t p0 = (uint32_t)f2bf(v.x) | ((uint32_t)f2bf(v.y) << 16);
    uint32_t p1 = (uint32_t)f2bf(v.z) | ((uint32_t)f2bf(v.w) << 16);
    ((uint2*)d)[l] = make_uint2(p0, p1);
  }
}

// ---------------------------------------------------------------------------
// Orchestration
// ---------------------------------------------------------------------------
extern "C" void kernel_launch(void* const* d_in, const int* in_sizes, int n_in,
                              void* d_out, int out_size, void* d_ws, size_t ws_size,
                              hipStream_t stream)
{
  (void)in_sizes; (void)n_in; (void)out_size;
  const float* x    = (const float*)d_in[0];
  const float* fc1w = (const float*)d_in[1];
  const float* fc1b = (const float*)d_in[2];
  const float* fc2w = (const float*)d_in[3];
  const float* fc2b = (const float*)d_in[4];
  const float* pcw  = (const float*)d_in[5];
  const float* pcb  = (const float*)d_in[6];
  const float* ln1w = (const float*)d_in[7];
  const float* ln1b = (const float*)d_in[8];
  const float* qkvw = (const float*)d_in[9];
  const float* rpet = (const float*)d_in[10];
  const float* projw= (const float*)d_in[11];
  const float* projb= (const float*)d_in[12];
  const float* ln2w = (const float*)d_in[13];
  const float* ln2b = (const float*)d_in[14];
  const float* m1w  = (const float*)d_in[15];
  const float* m1b  = (const float*)d_in[16];
  const float* m2w  = (const float*)d_in[17];
  const float* m2b  = (const float*)d_in[18];
  const float* bn1w = (const float*)d_in[19];
  const float* bn1b = (const float*)d_in[20];
  const float* linw = (const float*)d_in[21];
  const float* linb = (const float*)d_in[22];
  const float* bn2w = (const float*)d_in[23];
  const float* bn2b = (const float*)d_in[24];
  float* y = (float*)d_out;

  // -------- aliased workspace layout (regions share by liveness) ----------
  const size_t RA = 0;                      // At / MLP1
  const size_t RB = 77070336;               // U / QKV / T3nb
  const size_t RC = RB + 57802752;          // H / AO / H2
  const size_t RD = RC + 19267584;          // T0 / T2
  const size_t RE = RD + 38535168;          // T1 / T3
  const size_t RF = RE + 38535168;          // PART (lin split-K)
  const size_t RG = RF + 9633792;           // small bf16 weights
  const size_t RS = RG + 6422528;           // bn1 scale/shift + partials
  const size_t NEED = RS + 2048 + 16384;
  if (ws_size < NEED) return;

  char* ws = (char*)d_ws;
  u16*   At    = (u16*)(ws + RA);
  u16*   MLP1  = (u16*)(ws + RA);
  u16*   U     = (u16*)(ws + RB);
  u16*   QKV   = (u16*)(ws + RB);
  u16*   T3nb  = (u16*)(ws + RB);
  u16*   H     = (u16*)(ws + RC);
  u16*   AO    = (u16*)(ws + RC);
  u16*   H2    = (u16*)(ws + RC);
  float* T0    = (float*)(ws + RD);
  float* T2    = (float*)(ws + RD);
  float* T1    = (float*)(ws + RE);
  float* T3    = (float*)(ws + RE);
  float* PART  = (float*)(ws + RF);
  u16*   wb_fc1 = (u16*)(ws + RG);
  u16*   wb_fc2 = wb_fc1 + 1048576;
  u16*   wb_qkv = wb_fc2 + 393216;
  u16*   wb_proj= wb_qkv + 442368;
  u16*   wb_m1  = wb_proj + 147456;
  u16*   wb_m2  = wb_m1 + 589824;
  float* bnS   = (float*)(ws + RS);
  float* bnSh  = bnS + 196;
  float* bnP   = (float*)(ws + RS + 2048);

  // weight casts (f32 -> bf16), one merged kernel
  castall_k<<<1024, 256, 0, stream>>>(fc1w, wb_fc1, fc2w, wb_fc2, qkvw, wb_qkv,
                                      projw, wb_proj, m1w, wb_m1, m2w, wb_m2);

  // x (B,CIN,N) -> At (B*N, CIN) bf16
  transpose_cast_k<<<dim3(32, 7, 128), dim3(32, 8), 0, stream>>>(x, At);

  // embed fc1: U = relu6(At @ fc1w^T + b)   [25088 x 1024]
  gemm_k<0><<<196 * 8, 256, 0, stream>>>(At, wb_fc1, fc1b, nullptr, U,
                                          MT, 1024, 1024, 1024, 1024, 8, 0);
  // embed fc2: T0 = U @ fc2w^T + b          [25088 x 384] f32
  gemm_k<1><<<196 * 3, 256, 0, stream>>>(U, wb_fc2, fc2b, nullptr, T0,
                                          MT, 384, 1024, 1024, 1024, 3, 0);
  // depthwise conv + bias + residual -> T1
  conv_res_k<<<(B_ * NPOS * 96 + 255) / 256, 256, 0, stream>>>(T0, pcw, pcb, T1);
  // LN1 -> H (bf16)
  ln_k<<<MT / 4, 256, 0, stream>>>(T1, ln1w, ln1b, H);
  // qkv: QKV = H @ qkvw^T (no bias)          [25088 x 1152] bf16
  gemm_k<2><<<196 * 9, 256, 0, stream>>>(H, wb_qkv, nullptr, nullptr, QKV,
                                          MT, 1152, 384, 384, 384, 9, 0);
  // fused attention (rpe in-kernel, flash-style) -> AO (bf16)
  attn_k<<<1536, 256, 0, stream>>>(QKV, rpet, AO);
  // proj + residual(T1) -> T2 (f32)
  gemm_k<3><<<196 * 3, 256, 0, stream>>>(AO, wb_proj, projb, T1, T2,
                                          MT, 384, 384, 384, 384, 3, 0);
  // LN2 -> H2 (bf16)
  ln_k<<<MT / 4, 256, 0, stream>>>(T2, ln2w, ln2b, H2);
  // mlp fc1: MLP1 = relu6(H2 @ m1w^T + b)    [25088 x 1536] bf16
  gemm_k<0><<<196 * 12, 256, 0, stream>>>(H2, wb_m1, m1b, nullptr, MLP1,
                                           MT, 1536, 384, 384, 384, 12, 0);
  // mlp fc2 + residual(T2) -> T3 (f32)
  gemm_k<3><<<196 * 3, 256, 0, stream>>>(MLP1, wb_m2, m2b, T2, T3,
                                          MT, 384, 1536, 1536, 1536, 3, 0);
  // BN1 (per position) -> T3nb (bf16)
  bn1_partial_k<<<196 * 8, 256, 0, stream>>>(T3, bnP);
  bn1_finish_k<<<1, 256, 0, stream>>>(bnP, bn1w, bn1b, bnS, bnSh);
  bn1_apply_k<<<(MT * DM / 4 + 255) / 256, 256, 0, stream>>>(T3, bnS, bnSh, T3nb);
  // lin head: y = T3nb(128 x 75264) @ linw^T, split-K 49 x 1536 (W f32 direct)
  gemm_k<4><<<3 * 49, 256, 0, stream>>>(T3nb, linw, nullptr, nullptr, PART,
                                         128, 384, 1536, 75264, 75264, 3, 1536);
  lin_reduce_k<<<192, 256, 0, stream>>>(PART, linb, y);
  // BN2 (per feature over batch), in place on d_out
  bn2_k<<<384, 64, 0, stream>>>(y, bn2w, bn2b);
}

// Round 11
// 714.686 us; speedup vs baseline: 1.3510x; 1.0535x over previous
//
#include <hip/hip_runtime.h>
#include <cstdint>

// ---------------------------------------------------------------------------
// Problem constants
// ---------------------------------------------------------------------------
#define B_    128
#define CIN   1024
#define NPOS  196          // 14*14
#define DM    384
#define NH_   12
#define HD_   32
#define DFF_  1536
#define MT    25088        // B_*NPOS
#define SCALE_Q 0.17677669529663687f   // 1/sqrt(32)

typedef unsigned short u16;
typedef __attribute__((ext_vector_type(8))) short  short8;   // 8 bf16 (4 VGPR)
typedef __attribute__((ext_vector_type(4))) float  f32x4;    // MFMA C/D

__device__ __forceinline__ u16 f2bf(float f) {
  union { float f; uint32_t u; } v; v.f = f;
  uint32_t u = v.u;
  return (u16)((u + 0x7fffu + ((u >> 16) & 1u)) >> 16);
}
__device__ __forceinline__ float bf2f(u16 h) {
  union { uint32_t u; float f; } v; v.u = ((uint32_t)h) << 16;
  return v.f;
}

#define GLDS16(g, l)                                                           \
  __builtin_amdgcn_global_load_lds(                                            \
      (const __attribute__((address_space(1))) void*)(g),                      \
      (__attribute__((address_space(3))) void*)(l), 16, 0, 0)

// ---------------------------------------------------------------------------
// Generic bf16 MFMA GEMM (unchanged from r10 — counted-vmcnt pipeline + XCD
// swizzle; all GEMMs now below attn in the profile).
// MODE: 0 = bias+relu6 -> bf16 | 1 = bias -> f32 | 2 = plain -> bf16
//       3 = bias+res -> f32    | 4 = split-K partial -> f32 (W f32 in staging)
// ---------------------------------------------------------------------------
template <int MODE>
__global__ __launch_bounds__(256) void gemm_k(
    const u16* __restrict__ A, const void* __restrict__ Wv,
    const float* __restrict__ bias, const float* __restrict__ res,
    void* __restrict__ outp,
    int M, int N, int K, int lda, int ldw, int nTN, int splitK)
{
  __shared__ __align__(16) u16 As[2][8 * 128 * 8];   // dbuf [s][r][8]
  __shared__ __align__(16) u16 Bs[2][8 * 128 * 8];

  // ---- bijective XCD-chunked swizzle ----
  int nwg = gridDim.x;
  int bid0 = blockIdx.x;
  int qq = nwg >> 3, rr = nwg & 7;
  int xcd = bid0 & 7, idx = bid0 >> 3;
  int bid = (xcd < rr ? xcd * (qq + 1) : rr * (qq + 1) + (xcd - rr) * qq) + idx;

  int split = 0, mT, nT;
  if (MODE == 4) { split = bid / nTN; nT = bid % nTN; mT = 0; }
  else           { mT = bid / nTN;    nT = bid % nTN; }

  const u16* Ab = A + (size_t)split * splitK;
  float* outF = (float*)outp + ((MODE == 4) ? (size_t)split * (size_t)M * N : (size_t)0);
  u16*   outU = (u16*)outp;

  int tid = threadIdx.x;
  int wv = tid >> 6, ln = tid & 63;
  int q = ln >> 4, c = ln & 15;
  int wr = wv >> 1, wc = wv & 1;
  int mBase = mT * 128, nBase = nT * 128;

  f32x4 acc[4][4];
#pragma unroll
  for (int i = 0; i < 4; i++)
#pragma unroll
    for (int j = 0; j < 4; j++) acc[i][j] = (f32x4){0.f, 0.f, 0.f, 0.f};

  const u16* Ag = Ab + (size_t)mBase * lda;
  const u16*  Wg16 = (const u16*)Wv + (size_t)split * splitK + (size_t)nBase * ldw;
  const float* Wg32 = (const float*)Wv + (size_t)split * splitK + (size_t)nBase * ldw;

  auto STAGE = [&](int t, int buf) {
    int k0 = t * 64;
#pragma unroll
    for (int i = 0; i < 4; i++) {
      int ch = wv * 4 + i;             // chunk 0..15 (1024B each)
      int s = ch >> 1;                 // k-slot (8 bf16), 0..7
      int r = (ch & 1) * 64 + ln;      // tile row
      GLDS16(Ag + (size_t)r * lda + (k0 + s * 8), &As[buf][ch * 512]);
      if constexpr (MODE == 4) {
        const float* wp = Wg32 + (size_t)r * ldw + (k0 + s * 8);
        float4 f0 = *(const float4*)wp, f1 = *(const float4*)(wp + 4);
        short8 pk;
        pk[0] = (short)f2bf(f0.x); pk[1] = (short)f2bf(f0.y);
        pk[2] = (short)f2bf(f0.z); pk[3] = (short)f2bf(f0.w);
        pk[4] = (short)f2bf(f1.x); pk[5] = (short)f2bf(f1.y);
        pk[6] = (short)f2bf(f1.z); pk[7] = (short)f2bf(f1.w);
        *(short8*)&Bs[buf][ch * 512 + ln * 8] = pk;
      } else {
        GLDS16(Wg16 + (size_t)r * ldw + (k0 + s * 8), &Bs[buf][ch * 512]);
      }
    }
  };

  int NT = K >> 6;   // K-steps of 64 (all K are multiples of 64)

  // ---- prologue ----
  if constexpr (MODE == 4) {
    STAGE(0, 0);
    asm volatile("s_waitcnt vmcnt(0) lgkmcnt(0)" ::: "memory");
  } else {
    STAGE(0, 0);
    if (NT > 1) {
      STAGE(1, 1);
      asm volatile("s_waitcnt vmcnt(8)" ::: "memory");   // tile 0 complete
    } else {
      asm volatile("s_waitcnt vmcnt(0)" ::: "memory");
    }
  }
  __builtin_amdgcn_s_barrier();

  int cur = 0;
  for (int t = 0; t < NT; ++t) {
    // ---- all fragments of tile t -> registers (frees LDS buffer early) ----
    short8 afr[2][4], bfr[2][4];
#pragma unroll
    for (int kk = 0; kk < 2; kk++) {
#pragma unroll
      for (int mt2 = 0; mt2 < 4; mt2++)
        afr[kk][mt2] = *(const short8*)&As[cur][(((kk * 4 + q) * 128) + wr * 64 + mt2 * 16 + c) * 8];
#pragma unroll
      for (int nt2 = 0; nt2 < 4; nt2++)
        bfr[kk][nt2] = *(const short8*)&Bs[cur][(((kk * 4 + q) * 128) + wc * 64 + nt2 * 16 + c) * 8];
    }
    asm volatile("s_waitcnt lgkmcnt(0)" ::: "memory");
    __builtin_amdgcn_sched_barrier(0);
    __builtin_amdgcn_s_barrier();          // all waves done reading buffer cur

    if constexpr (MODE == 4) {
      if (t + 1 < NT) STAGE(t + 1, cur ^ 1);
      __builtin_amdgcn_sched_barrier(0);
#pragma unroll
      for (int kk = 0; kk < 2; kk++)
#pragma unroll
        for (int mt2 = 0; mt2 < 4; mt2++)
#pragma unroll
          for (int nt2 = 0; nt2 < 4; nt2++)
            acc[mt2][nt2] = __builtin_amdgcn_mfma_f32_16x16x32_bf16(
                afr[kk][mt2], bfr[kk][nt2], acc[mt2][nt2], 0, 0, 0);
      if (t + 1 < NT) {
        asm volatile("s_waitcnt vmcnt(0) lgkmcnt(0)" ::: "memory");
        __builtin_amdgcn_s_barrier();
        cur ^= 1;
      }
    } else {
      if (t + 2 < NT) STAGE(t + 2, cur);   // refill the buffer just freed
      __builtin_amdgcn_sched_barrier(0);
#pragma unroll
      for (int kk = 0; kk < 2; kk++)
#pragma unroll
        for (int mt2 = 0; mt2 < 4; mt2++)
#pragma unroll
          for (int nt2 = 0; nt2 < 4; nt2++)
            acc[mt2][nt2] = __builtin_amdgcn_mfma_f32_16x16x32_bf16(
                afr[kk][mt2], bfr[kk][nt2], acc[mt2][nt2], 0, 0, 0);
      if (t + 1 < NT) {
        if (t + 2 < NT)
          asm volatile("s_waitcnt vmcnt(8)" ::: "memory");  // t+1 done; t+2 in flight
        else
          asm volatile("s_waitcnt vmcnt(0)" ::: "memory");
        __builtin_amdgcn_s_barrier();
        cur ^= 1;
      }
    }
  }

  // ---- epilogue ----
#pragma unroll
  for (int mt2 = 0; mt2 < 4; mt2++) {
    int row0 = mBase + wr * 64 + mt2 * 16 + q * 4;
#pragma unroll
    for (int nt2 = 0; nt2 < 4; nt2++) {
      int col = nBase + wc * 64 + nt2 * 16 + c;
      float bv = (MODE == 0 || MODE == 1 || MODE == 3) ? bias[col] : 0.f;
      f32x4 v = acc[mt2][nt2];
#pragma unroll
      for (int e = 0; e < 4; e++) {
        int row = row0 + e;
        float x = v[e] + bv;
        if (MODE == 0) x = fminf(fmaxf(x, 0.f), 6.f);
        if (MODE == 3) x += res[(size_t)row * N + col];
        if (MODE == 0 || MODE == 2) outU[(size_t)row * N + col] = f2bf(x);
        else                        outF[(size_t)row * N + col] = x;
      }
    }
  }
}

// ---------------------------------------------------------------------------
// Bucket LUT: lut[i][j] (u8, stride 224) = rp bucket 0..48 for j<196, 49
// (sentinel -> Rw[..][49] = -inf) for j in [196,224). Same for all (b,h).
// ---------------------------------------------------------------------------
__global__ __launch_bounds__(224) void blut_k(uint8_t* __restrict__ lut)
{
  int i = blockIdx.x;          // 0..195
  int j = threadIdx.x;         // 0..223
  uint8_t v = 49;
  if (j < 196) {
    int ri = i / 14, ci = i - ri * 14;
    int rj = j / 14, cj = j - rj * 14;
    int dr = ri - rj, dc = ci - cj;
    int adr = dr < 0 ? -dr : dr, adc = dc < 0 ? -dc : dc;
    int tr = adr <= 1 ? adr : (adr <= 3 ? 2 : 3);
    int tc = adc <= 1 ? adc : (adc <= 3 ? 2 : 3);
    int fr = dr < 0 ? -tr : tr, fc = dc < 0 ? -tc : tc;
    v = (uint8_t)(fr * 7 + fc + 24);
  }
  lut[i * 224 + j] = v;
}

// ---------------------------------------------------------------------------
// Fused attention per (b,h), flash-style over 7 j-chunks of 32.
// r11: VALU diet (was VALUBusy 68%):
//   - bucket piecewise math (12+ ops/elem) -> 1 coalesced u8 LUT load
//     (global, L1/L2-resident 44KB) + LDS gather; j-mask folded into the
//     LUT sentinel 49 -> Rw[row][49] = bf16 -inf.
//   - shared chunk max per 16-lane q-group (common softmax shift cancels
//     per-row): 4 shfl + 1 rescale-exp per chunk vs 16 shfl + 4.
//   - truncating bf16 convert for P (normalized; <=0.4% rel).
// LDS = 12544(Ks) + 14592(Vt s228) + 4096(Pc) + 3136(Ts) + 6400(Rw 16x50)
//     = 40768 -> 4 blocks/CU.
// ---------------------------------------------------------------------------
__global__ __launch_bounds__(256) void attn_k(
    const u16* __restrict__ QKV, const float* __restrict__ tabG,
    const uint8_t* __restrict__ lutG, u16* __restrict__ AO)
{
  __shared__ __align__(16) u16 Ks[4 * 196 * 8];     // [s][j][e] K fragments
  __shared__ __align__(16) u16 Vt[32 * 228];        // [d][j], pad j>=196 zero
  __shared__ __align__(16) u16 Pc4[4][4 * 16 * 8];  // per-wave P chunk (16x32)
  __shared__ __align__(16) u16 Ts[49 * 32];         // rpe table, [t][k] bf16
  __shared__ __align__(16) u16 Rw4[4][16 * 50];     // per-wave rpe scores bf16
  int bh = blockIdx.x; int b = bh / NH_, h = bh % NH_;
  int tid = threadIdx.x;
  int wv = tid >> 6, ln = tid & 63;
  int q = ln >> 4, c = ln & 15;
  size_t rowbase = (size_t)b * NPOS * 1152 + h * 32;

  // ---- stage K fragments via global_load_lds (wave-uniform dest) ----
  for (int cb = wv * 64; cb < 784; cb += 256) {
    int ch = cb + ln;
    if (ch < 784) {
      int s = ch / 196, j = ch - s * 196;
      GLDS16(QKV + rowbase + 384 + (size_t)j * 1152 + s * 8, &Ks[cb * 8]);
    }
  }
  // ---- stage rpe table transposed to [t][k] bf16 (once per block) ----
  for (int t = tid; t < 49 * 32; t += 256) {
    int tt = t >> 5, k = t & 31;
    Ts[t] = f2bf(tabG[k * 49 + tt]);
  }
  // ---- stage V transposed (vectorized) ----
  for (int t = tid; t < 784; t += 256) {
    int nn = t >> 2, d0 = (t & 3) * 8;
    short8 v = *(const short8*)(QKV + rowbase + 768 + (size_t)nn * 1152 + d0);
#pragma unroll
    for (int j = 0; j < 8; j++) Vt[(d0 + j) * 228 + nn] = (u16)v[j];
  }
  for (int t = tid; t < 32 * 32; t += 256) {
    int d = t >> 5, jj = 196 + (t & 31);
    Vt[d * 228 + jj] = 0;
  }
  __syncthreads();

  u16* Pw = Pc4[wv];
  u16* Rw = Rw4[wv];

  for (int mt = wv; mt < 13; mt += 4) {
    int mb = mt * 16;
    int irow = mb + c; if (irow > 195) irow = 195;
    short8 afrag = *(const short8*)(QKV + rowbase + (size_t)irow * 1152 + q * 8);
    int i0 = mb + q * 4;

    // ---- rpe scores via MFMA -> Rw; sentinel col 49 = -inf ----
#pragma unroll
    for (int nt = 0; nt < 4; nt++) {
      int t = nt * 16 + c;
      int tt = t < 49 ? t : 48;
      short8 tb = *(const short8*)&Ts[tt * 32 + q * 8];
      f32x4 z = {0.f, 0.f, 0.f, 0.f};
      f32x4 rr = __builtin_amdgcn_mfma_f32_16x16x32_bf16(afrag, tb, z, 0, 0, 0);
      if (t < 49) {
#pragma unroll
        for (int e = 0; e < 4; e++)
          Rw[(q * 4 + e) * 50 + t] = f2bf(rr[e] * SCALE_Q);
      }
    }
    if (c == 0) {
#pragma unroll
      for (int e = 0; e < 4; e++)
        Rw[(q * 4 + e) * 50 + 49] = 0xFF80;   // bf16 -inf
    }

    // per-row lut/Rw offsets (rows >=196 clamp to 195; results discarded)
    int lutOff[4], rwOff[4];
#pragma unroll
    for (int e = 0; e < 4; e++) {
      int i = i0 + e; if (i > 195) i = 195;
      lutOff[e] = i * 224;
      rwOff[e] = (q * 4 + e) * 50;
    }

    float m = -INFINITY;
    float l4[4] = {0.f, 0.f, 0.f, 0.f};
    f32x4 oacc[2];
    oacc[0] = (f32x4){0.f, 0.f, 0.f, 0.f};
    oacc[1] = (f32x4){0.f, 0.f, 0.f, 0.f};

    // ---- online softmax over 7 chunks of 32 j ----
    for (int ck = 0; ck < 7; ck++) {
      // 2 QK MFMAs from Ks LDS
      f32x4 s01[2];
#pragma unroll
      for (int t = 0; t < 2; t++) {
        int j = (ck * 2 + t) * 16 + c;
        int jc = j > 195 ? 195 : j;
        short8 bfrag = *(const short8*)&Ks[(q * 196 + jc) * 8];
        f32x4 z = {0.f, 0.f, 0.f, 0.f};
        s01[t] = __builtin_amdgcn_mfma_f32_16x16x32_bf16(afrag, bfrag, z, 0, 0, 0);
      }
      // bucket LUT loads (coalesced u8) -> Rw gather (mask folded in)
      uint8_t bk[2][4];
#pragma unroll
      for (int t = 0; t < 2; t++) {
        int jj = ck * 32 + t * 16 + c;
#pragma unroll
        for (int e = 0; e < 4; e++) bk[t][e] = lutG[lutOff[e] + jj];
      }
#pragma unroll
      for (int t = 0; t < 2; t++)
#pragma unroll
        for (int e = 0; e < 4; e++)
          s01[t][e] = s01[t][e] * SCALE_Q + bf2f(Rw[rwOff[e] + bk[t][e]]);

      // shared chunk max per 16-lane q-group (common shift cancels per row)
      float mc = s01[0][0];
#pragma unroll
      for (int t = 0; t < 2; t++)
#pragma unroll
        for (int e = 0; e < 4; e++) mc = fmaxf(mc, s01[t][e]);
#pragma unroll
      for (int o = 1; o < 16; o <<= 1) mc = fmaxf(mc, __shfl_xor(mc, o, 64));
      float mn = fmaxf(m, mc);
      float sc = __expf(m - mn);
      m = mn;
#pragma unroll
      for (int t = 0; t < 2; t++)
#pragma unroll
        for (int e = 0; e < 4; e++) s01[t][e] = __expf(s01[t][e] - mn);
#pragma unroll
      for (int e = 0; e < 4; e++) {
        l4[e] = l4[e] * sc + s01[0][e] + s01[1][e];
        oacc[0][e] *= sc; oacc[1][e] *= sc;
      }
      // P chunk store, truncating bf16, A-frag layout
#pragma unroll
      for (int t = 0; t < 2; t++) {
        int sl = t * 2 + (c >> 3);
#pragma unroll
        for (int e = 0; e < 4; e++) {
          union { float f; uint32_t u; } pv; pv.f = s01[t][e];
          Pw[(sl * 16 + q * 4 + e) * 8 + (c & 7)] = (u16)(pv.u >> 16);
        }
      }
      // PV: 2 MFMAs (d halves)
#pragma unroll
      for (int n2 = 0; n2 < 2; n2++) {
        short8 pa = *(const short8*)&Pw[(q * 16 + c) * 8];
        short8 vb = *(const short8*)&Vt[(n2 * 16 + c) * 228 + ck * 32 + q * 8];
        oacc[n2] = __builtin_amdgcn_mfma_f32_16x16x32_bf16(pa, vb, oacc[n2], 0, 0, 0);
      }
    }

    // final 1/l and store
    float inv[4];
#pragma unroll
    for (int e = 0; e < 4; e++) {
      float s2 = l4[e];
#pragma unroll
      for (int o = 1; o < 16; o <<= 1) s2 += __shfl_xor(s2, o, 64);
      inv[e] = 1.f / s2;
    }
#pragma unroll
    for (int n2 = 0; n2 < 2; n2++) {
#pragma unroll
      for (int e = 0; e < 4; e++) {
        int i = i0 + e;
        if (i < 196) {
          int d = n2 * 16 + c;
          AO[((size_t)b * NPOS + i) * DM + h * 32 + d] = f2bf(oacc[n2][e] * inv[e]);
        }
      }
    }
  }
}

// ---------------------------------------------------------------------------
// x (B, CIN, HW, HW) f32  ->  A_t (B*NPOS, CIN) bf16
// ---------------------------------------------------------------------------
__global__ __launch_bounds__(256) void transpose_cast_k(
    const float* __restrict__ x, u16* __restrict__ At)
{
  __shared__ float t[32][33];
  int c0 = blockIdx.x * 32, n0 = blockIdx.y * 32, b = blockIdx.z;
  int tx = threadIdx.x, ty = threadIdx.y;
  const float* xb = x + (size_t)b * CIN * NPOS;
#pragma unroll
  for (int i = 0; i < 4; i++) {
    int cc = c0 + ty + i * 8, nn = n0 + tx;
    t[ty + i * 8][tx] = (nn < NPOS) ? xb[(size_t)cc * NPOS + nn] : 0.f;
  }
  __syncthreads();
  u16* Ab = At + (size_t)b * NPOS * CIN;
#pragma unroll
  for (int i = 0; i < 4; i++) {
    int nn = n0 + ty + i * 8, cc = c0 + tx;
    if (nn < NPOS) Ab[(size_t)nn * CIN + cc] = f2bf(t[tx][ty + i * 8]);
  }
}

// ---------------------------------------------------------------------------
// depthwise 3x3 SAME conv + bias + identity residual (fp32)
// ---------------------------------------------------------------------------
__global__ __launch_bounds__(256) void conv_res_k(
    const float* __restrict__ T0, const float* __restrict__ pcw,
    const float* __restrict__ pcb, float* __restrict__ T1)
{
  int idx = blockIdx.x * 256 + threadIdx.x;
  if (idx >= B_ * NPOS * 96) return;
  int d4 = idx % 96; int rem = idx / 96;
  int n = rem % NPOS; int b = rem / NPOS;
  int hh = n / 14, ww = n % 14;
  int d0 = d4 * 4;
  float w9[4][9];
#pragma unroll
  for (int j = 0; j < 4; j++)
#pragma unroll
    for (int t = 0; t < 9; t++) w9[j][t] = pcw[(d0 + j) * 9 + t];
  const float* base = T0 + (size_t)b * NPOS * DM;
  float4 ctr = *(const float4*)(base + (size_t)n * DM + d0);
  float ax = ctr.x + pcb[d0], ay = ctr.y + pcb[d0 + 1];
  float az = ctr.z + pcb[d0 + 2], aw = ctr.w + pcb[d0 + 3];
#pragma unroll
  for (int kh = 0; kh < 3; kh++) {
    int h2 = hh + kh - 1;
    if (h2 < 0 || h2 >= 14) continue;
#pragma unroll
    for (int kw = 0; kw < 3; kw++) {
      int w2 = ww + kw - 1;
      if (w2 < 0 || w2 >= 14) continue;
      float4 v = *(const float4*)(base + (size_t)(h2 * 14 + w2) * DM + d0);
      int t = kh * 3 + kw;
      ax += v.x * w9[0][t]; ay += v.y * w9[1][t];
      az += v.z * w9[2][t]; aw += v.w * w9[3][t];
    }
  }
  float4 o = {ax, ay, az, aw};
  *(float4*)(T1 + (size_t)b * NPOS * DM + (size_t)n * DM + d0) = o;
}

// ---------------------------------------------------------------------------
// LayerNorm(384) f32 -> bf16, one wave per row (float2-vectorized)
// ---------------------------------------------------------------------------
__global__ __launch_bounds__(256) void ln_k(
    const float* __restrict__ in, const float* __restrict__ w,
    const float* __restrict__ bb, u16* __restrict__ out)
{
  int row = blockIdx.x * 4 + (threadIdx.x >> 6);
  int ln = threadIdx.x & 63;
  const float2* r = (const float2*)(in + (size_t)row * DM);
  float2 v[3]; float s = 0.f, sq = 0.f;
#pragma unroll
  for (int j = 0; j < 3; j++) {
    v[j] = r[ln + 64 * j];
    s += v[j].x + v[j].y; sq += v[j].x * v[j].x + v[j].y * v[j].y;
  }
#pragma unroll
  for (int o = 1; o < 64; o <<= 1) { s += __shfl_xor(s, o, 64); sq += __shfl_xor(sq, o, 64); }
  float mu = s * (1.f / 384.f);
  float var = sq * (1.f / 384.f) - mu * mu;
  float rs = rsqrtf(var + 1e-5f);
  uint32_t* orow = (uint32_t*)(out + (size_t)row * DM);
#pragma unroll
  for (int j = 0; j < 3; j++) {
    int d = (ln + 64 * j) * 2;
    float a = (v[j].x - mu) * rs * w[d] + bb[d];
    float bq = (v[j].y - mu) * rs * w[d + 1] + bb[d + 1];
    orow[ln + 64 * j] = (uint32_t)f2bf(a) | ((uint32_t)f2bf(bq) << 16);
  }
}

// ---------------------------------------------------------------------------
// BN1 over (batch, dmodel) per position n: two-stage stats
// ---------------------------------------------------------------------------
__global__ __launch_bounds__(256) void bn1_partial_k(
    const float* __restrict__ T3, float* __restrict__ part)
{
  int n = blockIdx.x >> 3, g = blockIdx.x & 7;
  int tid = threadIdx.x;
  float s = 0.f, sq = 0.f;
  for (int b2 = g * 16; b2 < g * 16 + 16; b2++) {
    const float* p = T3 + ((size_t)b2 * NPOS + n) * DM;
    for (int d = tid; d < DM; d += 256) { float v = p[d]; s += v; sq += v * v; }
  }
#pragma unroll
  for (int o = 1; o < 64; o <<= 1) { s += __shfl_xor(s, o, 64); sq += __shfl_xor(sq, o, 64); }
  __shared__ float ls[4], lq[4];
  int wv = tid >> 6, ln = tid & 63;
  if (ln == 0) { ls[wv] = s; lq[wv] = sq; }
  __syncthreads();
  if (tid == 0) {
    part[blockIdx.x * 2]     = ls[0] + ls[1] + ls[2] + ls[3];
    part[blockIdx.x * 2 + 1] = lq[0] + lq[1] + lq[2] + lq[3];
  }
}

__global__ __launch_bounds__(256) void bn1_finish_k(
    const float* __restrict__ part, const float* __restrict__ bw,
    const float* __restrict__ bbb, float* __restrict__ scaleArr,
    float* __restrict__ shiftArr)
{
  int n = threadIdx.x;
  if (n >= NPOS) return;
  float S = 0.f, Q = 0.f;
#pragma unroll
  for (int g = 0; g < 8; g++) { S += part[(n * 8 + g) * 2]; Q += part[(n * 8 + g) * 2 + 1]; }
  float mu = S / 49152.f;
  float var = Q / 49152.f - mu * mu;
  float rs = rsqrtf(var + 2e-5f);
  float sc = rs * bw[n];
  scaleArr[n] = sc;
  shiftArr[n] = bbb[n] - mu * sc;
}

__global__ __launch_bounds__(256) void bn1_apply_k(
    const float* __restrict__ T3, const float* __restrict__ scaleArr,
    const float* __restrict__ shiftArr, u16* __restrict__ outb)
{
  int idx = blockIdx.x * 256 + threadIdx.x;           // float4 index
  if (idx >= MT * DM / 4) return;
  int n = (idx / 96) % NPOS;
  float4 v = *(const float4*)(T3 + (size_t)idx * 4);
  float sc = scaleArr[n], sh = shiftArr[n];
  uint32_t p0 = (uint32_t)f2bf(v.x * sc + sh) | ((uint32_t)f2bf(v.y * sc + sh) << 16);
  uint32_t p1 = (uint32_t)f2bf(v.z * sc + sh) | ((uint32_t)f2bf(v.w * sc + sh) << 16);
  ((uint2*)outb)[idx] = make_uint2(p0, p1);
}

// ---------------------------------------------------------------------------
// split-K reduce for lin head + bias
// ---------------------------------------------------------------------------
__global__ __launch_bounds__(256) void lin_reduce_k(
    const float* __restrict__ part, const float* __restrict__ lb,
    float* __restrict__ y)
{
  int idx = blockIdx.x * 256 + threadIdx.x;
  if (idx >= 128 * DM) return;
  int col = idx % DM;
  float s = lb[col];
#pragma unroll
  for (int sp = 0; sp < 49; sp++) s += part[(size_t)sp * (128 * DM) + idx];
  y[idx] = s;
}

// ---------------------------------------------------------------------------
// BN2 over batch (128) per feature col, in-place on y
// ---------------------------------------------------------------------------
__global__ __launch_bounds__(64) void bn2_k(
    float* __restrict__ y, const float* __restrict__ w,
    const float* __restrict__ bb)
{
  int col = blockIdx.x; int ln = threadIdx.x;
  float v0 = y[(size_t)ln * DM + col];
  float v1 = y[(size_t)(ln + 64) * DM + col];
  float s = v0 + v1, sq = v0 * v0 + v1 * v1;
#pragma unroll
  for (int o = 1; o < 64; o <<= 1) { s += __shfl_xor(s, o, 64); sq += __shfl_xor(sq, o, 64); }
  float mu = s / 128.f;
  float var = sq / 128.f - mu * mu;
  float rs = rsqrtf(var + 2e-5f);
  float sc = rs * w[col], sh = bb[col] - mu * sc;
  y[(size_t)ln * DM + col] = v0 * sc + sh;
  y[(size_t)(ln + 64) * DM + col] = v1 * sc + sh;
}

// ---------------------------------------------------------------------------
// merged f32 -> bf16 cast for the six small weight matrices
// ---------------------------------------------------------------------------
__global__ __launch_bounds__(256) void castall_k(
    const float* __restrict__ s0, u16* __restrict__ d0,
    const float* __restrict__ s1, u16* __restrict__ d1,
    const float* __restrict__ s2, u16* __restrict__ d2,
    const float* __restrict__ s3, u16* __restrict__ d3,
    const float* __restrict__ s4, u16* __restrict__ d4,
    const float* __restrict__ s5, u16* __restrict__ d5)
{
  const int b0 = 262144, b1 = b0 + 98304, b2 = b1 + 110592,
            b3 = b2 + 36864, b4 = b3 + 147456, b5 = b4 + 147456; // 802816
  int idx = blockIdx.x * 256 + threadIdx.x;
  int stride = gridDim.x * 256;
  for (; idx < b5; idx += stride) {
    const float* s; u16* d; int l;
    if      (idx < b0) { s = s0; d = d0; l = idx; }
    else if (idx < b1) { s = s1; d = d1; l = idx - b0; }
    else if (idx < b2) { s = s2; d = d2; l = idx - b1; }
    else if (idx < b3) { s = s3; d = d3; l = idx - b2; }
    else if (idx < b4) { s = s4; d = d4; l = idx - b3; }
    else               { s = s5; d = d5; l = idx - b4; }
    float4 v = *(const float4*)(s + (size_t)l * 4);
    uint32_t p0 = (uint32_t)f2bf(v.x) | ((uint32_t)f2bf(v.y) << 16);
    uint32_t p1 = (uint32_t)f2bf(v.z) | ((uint32_t)f2bf(v.w) << 16);
    ((uint2*)d)[l] = make_uint2(p0, p1);
  }
}

// ---------------------------------------------------------------------------
// Orchestration
// ---------------------------------------------------------------------------
extern "C" void kernel_launch(void* const* d_in, const int* in_sizes, int n_in,
                              void* d_out, int out_size, void* d_ws, size_t ws_size,
                              hipStream_t stream)
{
  (void)in_sizes; (void)n_in; (void)out_size;
  const float* x    = (const float*)d_in[0];
  const float* fc1w = (const float*)d_in[1];
  const float* fc1b = (const float*)d_in[2];
  const float* fc2w = (const float*)d_in[3];
  const float* fc2b = (const float*)d_in[4];
  const float* pcw  = (const float*)d_in[5];
  const float* pcb  = (const float*)d_in[6];
  const float* ln1w = (const float*)d_in[7];
  const float* ln1b = (const float*)d_in[8];
  const float* qkvw = (const float*)d_in[9];
  const float* rpet = (const float*)d_in[10];
  const float* projw= (const float*)d_in[11];
  const float* projb= (const float*)d_in[12];
  const float* ln2w = (const float*)d_in[13];
  const float* ln2b = (const float*)d_in[14];
  const float* m1w  = (const float*)d_in[15];
  const float* m1b  = (const float*)d_in[16];
  const float* m2w  = (const float*)d_in[17];
  const float* m2b  = (const float*)d_in[18];
  const float* bn1w = (const float*)d_in[19];
  const float* bn1b = (const float*)d_in[20];
  const float* linw = (const float*)d_in[21];
  const float* linb = (const float*)d_in[22];
  const float* bn2w = (const float*)d_in[23];
  const float* bn2b = (const float*)d_in[24];
  float* y = (float*)d_out;

  // -------- aliased workspace layout (regions share by liveness) ----------
  const size_t RA = 0;                      // At / MLP1
  const size_t RB = 77070336;               // U / QKV / T3nb
  const size_t RC = RB + 57802752;          // H / AO / H2
  const size_t RD = RC + 19267584;          // T0 / T2
  const size_t RE = RD + 38535168;          // T1 / T3
  const size_t RF = RE + 38535168;          // PART (lin split-K)
  const size_t RG = RF + 9633792;           // small bf16 weights
  const size_t RS = RG + 6422528;           // bn1 scale/shift + partials + lut
  const size_t NEED = RS + 2048 + 16384 + 45056;
  if (ws_size < NEED) return;

  char* ws = (char*)d_ws;
  u16*   At    = (u16*)(ws + RA);
  u16*   MLP1  = (u16*)(ws + RA);
  u16*   U     = (u16*)(ws + RB);
  u16*   QKV   = (u16*)(ws + RB);
  u16*   T3nb  = (u16*)(ws + RB);
  u16*   H     = (u16*)(ws + RC);
  u16*   AO    = (u16*)(ws + RC);
  u16*   H2    = (u16*)(ws + RC);
  float* T0    = (float*)(ws + RD);
  float* T2    = (float*)(ws + RD);
  float* T1    = (float*)(ws + RE);
  float* T3    = (float*)(ws + RE);
  float* PART  = (float*)(ws + RF);
  u16*   wb_fc1 = (u16*)(ws + RG);
  u16*   wb_fc2 = wb_fc1 + 1048576;
  u16*   wb_qkv = wb_fc2 + 393216;
  u16*   wb_proj= wb_qkv + 442368;
  u16*   wb_m1  = wb_proj + 147456;
  u16*   wb_m2  = wb_m1 + 589824;
  float* bnS   = (float*)(ws + RS);
  float* bnSh  = bnS + 196;
  float* bnP   = (float*)(ws + RS + 2048);
  uint8_t* blut = (uint8_t*)(ws + RS + 2048 + 16384);

  // weight casts (f32 -> bf16), one merged kernel + bucket LUT
  castall_k<<<1024, 256, 0, stream>>>(fc1w, wb_fc1, fc2w, wb_fc2, qkvw, wb_qkv,
                                      projw, wb_proj, m1w, wb_m1, m2w, wb_m2);
  blut_k<<<196, 224, 0, stream>>>(blut);

  // x (B,CIN,N) -> At (B*N, CIN) bf16
  transpose_cast_k<<<dim3(32, 7, 128), dim3(32, 8), 0, stream>>>(x, At);

  // embed fc1: U = relu6(At @ fc1w^T + b)   [25088 x 1024]
  gemm_k<0><<<196 * 8, 256, 0, stream>>>(At, wb_fc1, fc1b, nullptr, U,
                                          MT, 1024, 1024, 1024, 1024, 8, 0);
  // embed fc2: T0 = U @ fc2w^T + b          [25088 x 384] f32
  gemm_k<1><<<196 * 3, 256, 0, stream>>>(U, wb_fc2, fc2b, nullptr, T0,
                                          MT, 384, 1024, 1024, 1024, 3, 0);
  // depthwise conv + bias + residual -> T1
  conv_res_k<<<(B_ * NPOS * 96 + 255) / 256, 256, 0, stream>>>(T0, pcw, pcb, T1);
  // LN1 -> H (bf16)
  ln_k<<<MT / 4, 256, 0, stream>>>(T1, ln1w, ln1b, H);
  // qkv: QKV = H @ qkvw^T (no bias)          [25088 x 1152] bf16
  gemm_k<2><<<196 * 9, 256, 0, stream>>>(H, wb_qkv, nullptr, nullptr, QKV,
                                          MT, 1152, 384, 384, 384, 9, 0);
  // fused attention (rpe in-kernel, flash-style, LUT bias) -> AO (bf16)
  attn_k<<<1536, 256, 0, stream>>>(QKV, rpet, blut, AO);
  // proj + residual(T1) -> T2 (f32)
  gemm_k<3><<<196 * 3, 256, 0, stream>>>(AO, wb_proj, projb, T1, T2,
                                          MT, 384, 384, 384, 384, 3, 0);
  // LN2 -> H2 (bf16)
  ln_k<<<MT / 4, 256, 0, stream>>>(T2, ln2w, ln2b, H2);
  // mlp fc1: MLP1 = relu6(H2 @ m1w^T + b)    [25088 x 1536] bf16
  gemm_k<0><<<196 * 12, 256, 0, stream>>>(H2, wb_m1, m1b, nullptr, MLP1,
                                           MT, 1536, 384, 384, 384, 12, 0);
  // mlp fc2 + residual(T2) -> T3 (f32)
  gemm_k<3><<<196 * 3, 256, 0, stream>>>(MLP1, wb_m2, m2b, T2, T3,
                                          MT, 384, 1536, 1536, 1536, 3, 0);
  // BN1 (per position) -> T3nb (bf16)
  bn1_partial_k<<<196 * 8, 256, 0, stream>>>(T3, bnP);
  bn1_finish_k<<<1, 256, 0, stream>>>(bnP, bn1w, bn1b, bnS, bnSh);
  bn1_apply_k<<<(MT * DM / 4 + 255) / 256, 256, 0, stream>>>(T3, bnS, bnSh, T3nb);
  // lin head: y = T3nb(128 x 75264) @ linw^T, split-K 49 x 1536 (W f32 direct)
  gemm_k<4><<<3 * 49, 256, 0, stream>>>(T3nb, linw, nullptr, nullptr, PART,
                                         128, 384, 1536, 75264, 75264, 3, 1536);
  lin_reduce_k<<<192, 256, 0, stream>>>(PART, linb, y);
  // BN2 (per feature over batch), in place on d_out
  bn2_k<<<384, 64, 0, stream>>>(y, bn2w, bn2b);
}

// Round 12
// 705.287 us; speedup vs baseline: 1.3690x; 1.0133x over previous
//
#include <hip/hip_runtime.h>
#include <cstdint>

// ---------------------------------------------------------------------------
// Problem constants
// ---------------------------------------------------------------------------
#define B_    128
#define CIN   1024
#define NPOS  196          // 14*14
#define DM    384
#define NH_   12
#define HD_   32
#define DFF_  1536
#define MT    25088        // B_*NPOS
#define SCALE_Q 0.17677669529663687f   // 1/sqrt(32)

typedef unsigned short u16;
typedef __attribute__((ext_vector_type(8))) short  short8;   // 8 bf16 (4 VGPR)
typedef __attribute__((ext_vector_type(4))) float  f32x4;    // MFMA C/D

__device__ __forceinline__ u16 f2bf(float f) {
  union { float f; uint32_t u; } v; v.f = f;
  uint32_t u = v.u;
  return (u16)((u + 0x7fffu + ((u >> 16) & 1u)) >> 16);
}
__device__ __forceinline__ float bf2f(u16 h) {
  union { uint32_t u; float f; } v; v.u = ((uint32_t)h) << 16;
  return v.f;
}

#define GLDS16(g, l)                                                           \
  __builtin_amdgcn_global_load_lds(                                            \
      (const __attribute__((address_space(1))) void*)(g),                      \
      (__attribute__((address_space(3))) void*)(l), 16, 0, 0)

// ---------------------------------------------------------------------------
// Generic bf16 MFMA GEMM:  out = epi( A[M x K] * W[N x K]^T )
// 128x128 tile, 4 waves, BK=32 (r12: was BK=64/64KB LDS -> 2 blocks/CU;
// m132 lesson — 32KB dbuf restores 4 blocks/CU = 16 waves/CU).
// Counted-vmcnt pipeline: tile t's frags -> regs, barrier, STAGE(t+2) into
// the freed buffer, 16 MFMA, vmcnt(4) (t+1 done, t+2 in flight), barrier.
// XCD-chunked bijective blockIdx swizzle (A-band L2 reuse).
// MODE: 0 = bias+relu6 -> bf16 | 1 = bias -> f32 | 2 = plain -> bf16
//       3 = bias+res -> f32    | 4 = split-K partial -> f32 (W f32 in staging)
// ---------------------------------------------------------------------------
template <int MODE>
__global__ __launch_bounds__(256) void gemm_k(
    const u16* __restrict__ A, const void* __restrict__ Wv,
    const float* __restrict__ bias, const float* __restrict__ res,
    void* __restrict__ outp,
    int M, int N, int K, int lda, int ldw, int nTN, int splitK)
{
  __shared__ __align__(16) u16 As[2][4 * 128 * 8];   // dbuf [s][r][8], 16KB ea
  __shared__ __align__(16) u16 Bs[2][4 * 128 * 8];

  // ---- bijective XCD-chunked swizzle ----
  int nwg = gridDim.x;
  int bid0 = blockIdx.x;
  int qq = nwg >> 3, rr = nwg & 7;
  int xcd = bid0 & 7, idx = bid0 >> 3;
  int bid = (xcd < rr ? xcd * (qq + 1) : rr * (qq + 1) + (xcd - rr) * qq) + idx;

  int split = 0, mT, nT;
  if (MODE == 4) { split = bid / nTN; nT = bid % nTN; mT = 0; }
  else           { mT = bid / nTN;    nT = bid % nTN; }

  const u16* Ab = A + (size_t)split * splitK;
  float* outF = (float*)outp + ((MODE == 4) ? (size_t)split * (size_t)M * N : (size_t)0);
  u16*   outU = (u16*)outp;

  int tid = threadIdx.x;
  int wv = tid >> 6, ln = tid & 63;
  int q = ln >> 4, c = ln & 15;
  int wr = wv >> 1, wc = wv & 1;
  int mBase = mT * 128, nBase = nT * 128;

  f32x4 acc[4][4];
#pragma unroll
  for (int i = 0; i < 4; i++)
#pragma unroll
    for (int j = 0; j < 4; j++) acc[i][j] = (f32x4){0.f, 0.f, 0.f, 0.f};

  const u16* Ag = Ab + (size_t)mBase * lda;
  const u16*  Wg16 = (const u16*)Wv + (size_t)split * splitK + (size_t)nBase * ldw;
  const float* Wg32 = (const float*)Wv + (size_t)split * splitK + (size_t)nBase * ldw;

  auto STAGE = [&](int t, int buf) {
    int k0 = t * 32;
#pragma unroll
    for (int i = 0; i < 2; i++) {
      int ch = wv * 2 + i;             // chunk 0..7 (1024B each)
      int s = ch >> 1;                 // k-slot (8 bf16), 0..3
      int r = (ch & 1) * 64 + ln;      // tile row
      GLDS16(Ag + (size_t)r * lda + (k0 + s * 8), &As[buf][ch * 512]);
      if constexpr (MODE == 4) {
        const float* wp = Wg32 + (size_t)r * ldw + (k0 + s * 8);
        float4 f0 = *(const float4*)wp, f1 = *(const float4*)(wp + 4);
        short8 pk;
        pk[0] = (short)f2bf(f0.x); pk[1] = (short)f2bf(f0.y);
        pk[2] = (short)f2bf(f0.z); pk[3] = (short)f2bf(f0.w);
        pk[4] = (short)f2bf(f1.x); pk[5] = (short)f2bf(f1.y);
        pk[6] = (short)f2bf(f1.z); pk[7] = (short)f2bf(f1.w);
        *(short8*)&Bs[buf][ch * 512 + ln * 8] = pk;
      } else {
        GLDS16(Wg16 + (size_t)r * ldw + (k0 + s * 8), &Bs[buf][ch * 512]);
      }
    }
  };

  int NT = K >> 5;   // K-steps of 32 (all K are multiples of 32)

  // ---- prologue ----
  if constexpr (MODE == 4) {
    STAGE(0, 0);
    asm volatile("s_waitcnt vmcnt(0) lgkmcnt(0)" ::: "memory");
  } else {
    STAGE(0, 0);
    if (NT > 1) {
      STAGE(1, 1);
      asm volatile("s_waitcnt vmcnt(4)" ::: "memory");   // tile 0 complete
    } else {
      asm volatile("s_waitcnt vmcnt(0)" ::: "memory");
    }
  }
  __builtin_amdgcn_s_barrier();

  int cur = 0;
  for (int t = 0; t < NT; ++t) {
    // ---- all fragments of tile t -> registers (frees LDS buffer early) ----
    short8 afr[4], bfr[4];
#pragma unroll
    for (int mt2 = 0; mt2 < 4; mt2++)
      afr[mt2] = *(const short8*)&As[cur][((q * 128) + wr * 64 + mt2 * 16 + c) * 8];
#pragma unroll
    for (int nt2 = 0; nt2 < 4; nt2++)
      bfr[nt2] = *(const short8*)&Bs[cur][((q * 128) + wc * 64 + nt2 * 16 + c) * 8];
    asm volatile("s_waitcnt lgkmcnt(0)" ::: "memory");
    __builtin_amdgcn_sched_barrier(0);
    __builtin_amdgcn_s_barrier();          // all waves done reading buffer cur

    if constexpr (MODE == 4) {
      if (t + 1 < NT) STAGE(t + 1, cur ^ 1);
      __builtin_amdgcn_sched_barrier(0);
#pragma unroll
      for (int mt2 = 0; mt2 < 4; mt2++)
#pragma unroll
        for (int nt2 = 0; nt2 < 4; nt2++)
          acc[mt2][nt2] = __builtin_amdgcn_mfma_f32_16x16x32_bf16(
              afr[mt2], bfr[nt2], acc[mt2][nt2], 0, 0, 0);
      if (t + 1 < NT) {
        asm volatile("s_waitcnt vmcnt(0) lgkmcnt(0)" ::: "memory");
        __builtin_amdgcn_s_barrier();
        cur ^= 1;
      }
    } else {
      if (t + 2 < NT) STAGE(t + 2, cur);   // refill the buffer just freed
      __builtin_amdgcn_sched_barrier(0);
#pragma unroll
      for (int mt2 = 0; mt2 < 4; mt2++)
#pragma unroll
        for (int nt2 = 0; nt2 < 4; nt2++)
          acc[mt2][nt2] = __builtin_amdgcn_mfma_f32_16x16x32_bf16(
              afr[mt2], bfr[nt2], acc[mt2][nt2], 0, 0, 0);
      if (t + 1 < NT) {
        if (t + 2 < NT)
          asm volatile("s_waitcnt vmcnt(4)" ::: "memory");  // t+1 done; t+2 in flight
        else
          asm volatile("s_waitcnt vmcnt(0)" ::: "memory");
        __builtin_amdgcn_s_barrier();
        cur ^= 1;
      }
    }
  }

  // ---- epilogue ----
#pragma unroll
  for (int mt2 = 0; mt2 < 4; mt2++) {
    int row0 = mBase + wr * 64 + mt2 * 16 + q * 4;
#pragma unroll
    for (int nt2 = 0; nt2 < 4; nt2++) {
      int col = nBase + wc * 64 + nt2 * 16 + c;
      float bv = (MODE == 0 || MODE == 1 || MODE == 3) ? bias[col] : 0.f;
      f32x4 v = acc[mt2][nt2];
#pragma unroll
      for (int e = 0; e < 4; e++) {
        int row = row0 + e;
        float x = v[e] + bv;
        if (MODE == 0) x = fminf(fmaxf(x, 0.f), 6.f);
        if (MODE == 3) x += res[(size_t)row * N + col];
        if (MODE == 0 || MODE == 2) outU[(size_t)row * N + col] = f2bf(x);
        else                        outF[(size_t)row * N + col] = x;
      }
    }
  }
}

// ---------------------------------------------------------------------------
// Bucket LUT: lut[i][j] (u8, stride 224) = rp bucket 0..48 for j<196, 49
// (sentinel -> Rw[..][49] = -inf) for j in [196,224). Same for all (b,h).
// ---------------------------------------------------------------------------
__global__ __launch_bounds__(224) void blut_k(uint8_t* __restrict__ lut)
{
  int i = blockIdx.x;          // 0..195
  int j = threadIdx.x;         // 0..223
  uint8_t v = 49;
  if (j < 196) {
    int ri = i / 14, ci = i - ri * 14;
    int rj = j / 14, cj = j - rj * 14;
    int dr = ri - rj, dc = ci - cj;
    int adr = dr < 0 ? -dr : dr, adc = dc < 0 ? -dc : dc;
    int tr = adr <= 1 ? adr : (adr <= 3 ? 2 : 3);
    int tc = adc <= 1 ? adc : (adc <= 3 ? 2 : 3);
    int fr = dr < 0 ? -tr : tr, fc = dc < 0 ? -tc : tc;
    v = (uint8_t)(fr * 7 + fc + 24);
  }
  lut[i * 224 + j] = v;
}

// ---------------------------------------------------------------------------
// Fused attention per (b,h), flash-style over 7 j-chunks of 32.
// (unchanged from r11 — below GEMMs in the profile)
// ---------------------------------------------------------------------------
__global__ __launch_bounds__(256) void attn_k(
    const u16* __restrict__ QKV, const float* __restrict__ tabG,
    const uint8_t* __restrict__ lutG, u16* __restrict__ AO)
{
  __shared__ __align__(16) u16 Ks[4 * 196 * 8];     // [s][j][e] K fragments
  __shared__ __align__(16) u16 Vt[32 * 228];        // [d][j], pad j>=196 zero
  __shared__ __align__(16) u16 Pc4[4][4 * 16 * 8];  // per-wave P chunk (16x32)
  __shared__ __align__(16) u16 Ts[49 * 32];         // rpe table, [t][k] bf16
  __shared__ __align__(16) u16 Rw4[4][16 * 50];     // per-wave rpe scores bf16
  int bh = blockIdx.x; int b = bh / NH_, h = bh % NH_;
  int tid = threadIdx.x;
  int wv = tid >> 6, ln = tid & 63;
  int q = ln >> 4, c = ln & 15;
  size_t rowbase = (size_t)b * NPOS * 1152 + h * 32;

  // ---- stage K fragments via global_load_lds (wave-uniform dest) ----
  for (int cb = wv * 64; cb < 784; cb += 256) {
    int ch = cb + ln;
    if (ch < 784) {
      int s = ch / 196, j = ch - s * 196;
      GLDS16(QKV + rowbase + 384 + (size_t)j * 1152 + s * 8, &Ks[cb * 8]);
    }
  }
  // ---- stage rpe table transposed to [t][k] bf16 (once per block) ----
  for (int t = tid; t < 49 * 32; t += 256) {
    int tt = t >> 5, k = t & 31;
    Ts[t] = f2bf(tabG[k * 49 + tt]);
  }
  // ---- stage V transposed (vectorized) ----
  for (int t = tid; t < 784; t += 256) {
    int nn = t >> 2, d0 = (t & 3) * 8;
    short8 v = *(const short8*)(QKV + rowbase + 768 + (size_t)nn * 1152 + d0);
#pragma unroll
    for (int j = 0; j < 8; j++) Vt[(d0 + j) * 228 + nn] = (u16)v[j];
  }
  for (int t = tid; t < 32 * 32; t += 256) {
    int d = t >> 5, jj = 196 + (t & 31);
    Vt[d * 228 + jj] = 0;
  }
  __syncthreads();

  u16* Pw = Pc4[wv];
  u16* Rw = Rw4[wv];

  for (int mt = wv; mt < 13; mt += 4) {
    int mb = mt * 16;
    int irow = mb + c; if (irow > 195) irow = 195;
    short8 afrag = *(const short8*)(QKV + rowbase + (size_t)irow * 1152 + q * 8);
    int i0 = mb + q * 4;

    // ---- rpe scores via MFMA -> Rw; sentinel col 49 = -inf ----
#pragma unroll
    for (int nt = 0; nt < 4; nt++) {
      int t = nt * 16 + c;
      int tt = t < 49 ? t : 48;
      short8 tb = *(const short8*)&Ts[tt * 32 + q * 8];
      f32x4 z = {0.f, 0.f, 0.f, 0.f};
      f32x4 rr = __builtin_amdgcn_mfma_f32_16x16x32_bf16(afrag, tb, z, 0, 0, 0);
      if (t < 49) {
#pragma unroll
        for (int e = 0; e < 4; e++)
          Rw[(q * 4 + e) * 50 + t] = f2bf(rr[e] * SCALE_Q);
      }
    }
    if (c == 0) {
#pragma unroll
      for (int e = 0; e < 4; e++)
        Rw[(q * 4 + e) * 50 + 49] = 0xFF80;   // bf16 -inf
    }

    // per-row lut/Rw offsets (rows >=196 clamp to 195; results discarded)
    int lutOff[4], rwOff[4];
#pragma unroll
    for (int e = 0; e < 4; e++) {
      int i = i0 + e; if (i > 195) i = 195;
      lutOff[e] = i * 224;
      rwOff[e] = (q * 4 + e) * 50;
    }

    float m = -INFINITY;
    float l4[4] = {0.f, 0.f, 0.f, 0.f};
    f32x4 oacc[2];
    oacc[0] = (f32x4){0.f, 0.f, 0.f, 0.f};
    oacc[1] = (f32x4){0.f, 0.f, 0.f, 0.f};

    // ---- online softmax over 7 chunks of 32 j ----
    for (int ck = 0; ck < 7; ck++) {
      // 2 QK MFMAs from Ks LDS
      f32x4 s01[2];
#pragma unroll
      for (int t = 0; t < 2; t++) {
        int j = (ck * 2 + t) * 16 + c;
        int jc = j > 195 ? 195 : j;
        short8 bfrag = *(const short8*)&Ks[(q * 196 + jc) * 8];
        f32x4 z = {0.f, 0.f, 0.f, 0.f};
        s01[t] = __builtin_amdgcn_mfma_f32_16x16x32_bf16(afrag, bfrag, z, 0, 0, 0);
      }
      // bucket LUT loads (coalesced u8) -> Rw gather (mask folded in)
      uint8_t bk[2][4];
#pragma unroll
      for (int t = 0; t < 2; t++) {
        int jj = ck * 32 + t * 16 + c;
#pragma unroll
        for (int e = 0; e < 4; e++) bk[t][e] = lutG[lutOff[e] + jj];
      }
#pragma unroll
      for (int t = 0; t < 2; t++)
#pragma unroll
        for (int e = 0; e < 4; e++)
          s01[t][e] = s01[t][e] * SCALE_Q + bf2f(Rw[rwOff[e] + bk[t][e]]);

      // shared chunk max per 16-lane q-group (common shift cancels per row)
      float mc = s01[0][0];
#pragma unroll
      for (int t = 0; t < 2; t++)
#pragma unroll
        for (int e = 0; e < 4; e++) mc = fmaxf(mc, s01[t][e]);
#pragma unroll
      for (int o = 1; o < 16; o <<= 1) mc = fmaxf(mc, __shfl_xor(mc, o, 64));
      float mn = fmaxf(m, mc);
      float sc = __expf(m - mn);
      m = mn;
#pragma unroll
      for (int t = 0; t < 2; t++)
#pragma unroll
        for (int e = 0; e < 4; e++) s01[t][e] = __expf(s01[t][e] - mn);
#pragma unroll
      for (int e = 0; e < 4; e++) {
        l4[e] = l4[e] * sc + s01[0][e] + s01[1][e];
        oacc[0][e] *= sc; oacc[1][e] *= sc;
      }
      // P chunk store, truncating bf16, A-frag layout
#pragma unroll
      for (int t = 0; t < 2; t++) {
        int sl = t * 2 + (c >> 3);
#pragma unroll
        for (int e = 0; e < 4; e++) {
          union { float f; uint32_t u; } pv; pv.f = s01[t][e];
          Pw[(sl * 16 + q * 4 + e) * 8 + (c & 7)] = (u16)(pv.u >> 16);
        }
      }
      // PV: 2 MFMAs (d halves)
#pragma unroll
      for (int n2 = 0; n2 < 2; n2++) {
        short8 pa = *(const short8*)&Pw[(q * 16 + c) * 8];
        short8 vb = *(const short8*)&Vt[(n2 * 16 + c) * 228 + ck * 32 + q * 8];
        oacc[n2] = __builtin_amdgcn_mfma_f32_16x16x32_bf16(pa, vb, oacc[n2], 0, 0, 0);
      }
    }

    // final 1/l and store
    float inv[4];
#pragma unroll
    for (int e = 0; e < 4; e++) {
      float s2 = l4[e];
#pragma unroll
      for (int o = 1; o < 16; o <<= 1) s2 += __shfl_xor(s2, o, 64);
      inv[e] = 1.f / s2;
    }
#pragma unroll
    for (int n2 = 0; n2 < 2; n2++) {
#pragma unroll
      for (int e = 0; e < 4; e++) {
        int i = i0 + e;
        if (i < 196) {
          int d = n2 * 16 + c;
          AO[((size_t)b * NPOS + i) * DM + h * 32 + d] = f2bf(oacc[n2][e] * inv[e]);
        }
      }
    }
  }
}

// ---------------------------------------------------------------------------
// x (B, CIN, HW, HW) f32  ->  A_t (B*NPOS, CIN) bf16
// ---------------------------------------------------------------------------
__global__ __launch_bounds__(256) void transpose_cast_k(
    const float* __restrict__ x, u16* __restrict__ At)
{
  __shared__ float t[32][33];
  int c0 = blockIdx.x * 32, n0 = blockIdx.y * 32, b = blockIdx.z;
  int tx = threadIdx.x, ty = threadIdx.y;
  const float* xb = x + (size_t)b * CIN * NPOS;
#pragma unroll
  for (int i = 0; i < 4; i++) {
    int cc = c0 + ty + i * 8, nn = n0 + tx;
    t[ty + i * 8][tx] = (nn < NPOS) ? xb[(size_t)cc * NPOS + nn] : 0.f;
  }
  __syncthreads();
  u16* Ab = At + (size_t)b * NPOS * CIN;
#pragma unroll
  for (int i = 0; i < 4; i++) {
    int nn = n0 + ty + i * 8, cc = c0 + tx;
    if (nn < NPOS) Ab[(size_t)nn * CIN + cc] = f2bf(t[tx][ty + i * 8]);
  }
}

// ---------------------------------------------------------------------------
// depthwise 3x3 SAME conv + bias + identity residual (fp32)
// ---------------------------------------------------------------------------
__global__ __launch_bounds__(256) void conv_res_k(
    const float* __restrict__ T0, const float* __restrict__ pcw,
    const float* __restrict__ pcb, float* __restrict__ T1)
{
  int idx = blockIdx.x * 256 + threadIdx.x;
  if (idx >= B_ * NPOS * 96) return;
  int d4 = idx % 96; int rem = idx / 96;
  int n = rem % NPOS; int b = rem / NPOS;
  int hh = n / 14, ww = n % 14;
  int d0 = d4 * 4;
  float w9[4][9];
#pragma unroll
  for (int j = 0; j < 4; j++)
#pragma unroll
    for (int t = 0; t < 9; t++) w9[j][t] = pcw[(d0 + j) * 9 + t];
  const float* base = T0 + (size_t)b * NPOS * DM;
  float4 ctr = *(const float4*)(base + (size_t)n * DM + d0);
  float ax = ctr.x + pcb[d0], ay = ctr.y + pcb[d0 + 1];
  float az = ctr.z + pcb[d0 + 2], aw = ctr.w + pcb[d0 + 3];
#pragma unroll
  for (int kh = 0; kh < 3; kh++) {
    int h2 = hh + kh - 1;
    if (h2 < 0 || h2 >= 14) continue;
#pragma unroll
    for (int kw = 0; kw < 3; kw++) {
      int w2 = ww + kw - 1;
      if (w2 < 0 || w2 >= 14) continue;
      float4 v = *(const float4*)(base + (size_t)(h2 * 14 + w2) * DM + d0);
      int t = kh * 3 + kw;
      ax += v.x * w9[0][t]; ay += v.y * w9[1][t];
      az += v.z * w9[2][t]; aw += v.w * w9[3][t];
    }
  }
  float4 o = {ax, ay, az, aw};
  *(float4*)(T1 + (size_t)b * NPOS * DM + (size_t)n * DM + d0) = o;
}

// ---------------------------------------------------------------------------
// LayerNorm(384) f32 -> bf16, one wave per row (float2-vectorized)
// ---------------------------------------------------------------------------
__global__ __launch_bounds__(256) void ln_k(
    const float* __restrict__ in, const float* __restrict__ w,
    const float* __restrict__ bb, u16* __restrict__ out)
{
  int row = blockIdx.x * 4 + (threadIdx.x >> 6);
  int ln = threadIdx.x & 63;
  const float2* r = (const float2*)(in + (size_t)row * DM);
  float2 v[3]; float s = 0.f, sq = 0.f;
#pragma unroll
  for (int j = 0; j < 3; j++) {
    v[j] = r[ln + 64 * j];
    s += v[j].x + v[j].y; sq += v[j].x * v[j].x + v[j].y * v[j].y;
  }
#pragma unroll
  for (int o = 1; o < 64; o <<= 1) { s += __shfl_xor(s, o, 64); sq += __shfl_xor(sq, o, 64); }
  float mu = s * (1.f / 384.f);
  float var = sq * (1.f / 384.f) - mu * mu;
  float rs = rsqrtf(var + 1e-5f);
  uint32_t* orow = (uint32_t*)(out + (size_t)row * DM);
#pragma unroll
  for (int j = 0; j < 3; j++) {
    int d = (ln + 64 * j) * 2;
    float a = (v[j].x - mu) * rs * w[d] + bb[d];
    float bq = (v[j].y - mu) * rs * w[d + 1] + bb[d + 1];
    orow[ln + 64 * j] = (uint32_t)f2bf(a) | ((uint32_t)f2bf(bq) << 16);
  }
}

// ---------------------------------------------------------------------------
// BN1 over (batch, dmodel) per position n: two-stage stats
// ---------------------------------------------------------------------------
__global__ __launch_bounds__(256) void bn1_partial_k(
    const float* __restrict__ T3, float* __restrict__ part)
{
  int n = blockIdx.x >> 3, g = blockIdx.x & 7;
  int tid = threadIdx.x;
  float s = 0.f, sq = 0.f;
  for (int b2 = g * 16; b2 < g * 16 + 16; b2++) {
    const float* p = T3 + ((size_t)b2 * NPOS + n) * DM;
    for (int d = tid; d < DM; d += 256) { float v = p[d]; s += v; sq += v * v; }
  }
#pragma unroll
  for (int o = 1; o < 64; o <<= 1) { s += __shfl_xor(s, o, 64); sq += __shfl_xor(sq, o, 64); }
  __shared__ float ls[4], lq[4];
  int wv = tid >> 6, ln = tid & 63;
  if (ln == 0) { ls[wv] = s; lq[wv] = sq; }
  __syncthreads();
  if (tid == 0) {
    part[blockIdx.x * 2]     = ls[0] + ls[1] + ls[2] + ls[3];
    part[blockIdx.x * 2 + 1] = lq[0] + lq[1] + lq[2] + lq[3];
  }
}

__global__ __launch_bounds__(256) void bn1_finish_k(
    const float* __restrict__ part, const float* __restrict__ bw,
    const float* __restrict__ bbb, float* __restrict__ scaleArr,
    float* __restrict__ shiftArr)
{
  int n = threadIdx.x;
  if (n >= NPOS) return;
  float S = 0.f, Q = 0.f;
#pragma unroll
  for (int g = 0; g < 8; g++) { S += part[(n * 8 + g) * 2]; Q += part[(n * 8 + g) * 2 + 1]; }
  float mu = S / 49152.f;
  float var = Q / 49152.f - mu * mu;
  float rs = rsqrtf(var + 2e-5f);
  float sc = rs * bw[n];
  scaleArr[n] = sc;
  shiftArr[n] = bbb[n] - mu * sc;
}

__global__ __launch_bounds__(256) void bn1_apply_k(
    const float* __restrict__ T3, const float* __restrict__ scaleArr,
    const float* __restrict__ shiftArr, u16* __restrict__ outb)
{
  int idx = blockIdx.x * 256 + threadIdx.x;           // float4 index
  if (idx >= MT * DM / 4) return;
  int n = (idx / 96) % NPOS;
  float4 v = *(const float4*)(T3 + (size_t)idx * 4);
  float sc = scaleArr[n], sh = shiftArr[n];
  uint32_t p0 = (uint32_t)f2bf(v.x * sc + sh) | ((uint32_t)f2bf(v.y * sc + sh) << 16);
  uint32_t p1 = (uint32_t)f2bf(v.z * sc + sh) | ((uint32_t)f2bf(v.w * sc + sh) << 16);
  ((uint2*)outb)[idx] = make_uint2(p0, p1);
}

// ---------------------------------------------------------------------------
// split-K reduce for lin head + bias
// ---------------------------------------------------------------------------
__global__ __launch_bounds__(256) void lin_reduce_k(
    const float* __restrict__ part, const float* __restrict__ lb,
    float* __restrict__ y)
{
  int idx = blockIdx.x * 256 + threadIdx.x;
  if (idx >= 128 * DM) return;
  int col = idx % DM;
  float s = lb[col];
#pragma unroll
  for (int sp = 0; sp < 49; sp++) s += part[(size_t)sp * (128 * DM) + idx];
  y[idx] = s;
}

// ---------------------------------------------------------------------------
// BN2 over batch (128) per feature col, in-place on y
// ---------------------------------------------------------------------------
__global__ __launch_bounds__(64) void bn2_k(
    float* __restrict__ y, const float* __restrict__ w,
    const float* __restrict__ bb)
{
  int col = blockIdx.x; int ln = threadIdx.x;
  float v0 = y[(size_t)ln * DM + col];
  float v1 = y[(size_t)(ln + 64) * DM + col];
  float s = v0 + v1, sq = v0 * v0 + v1 * v1;
#pragma unroll
  for (int o = 1; o < 64; o <<= 1) { s += __shfl_xor(s, o, 64); sq += __shfl_xor(sq, o, 64); }
  float mu = s / 128.f;
  float var = sq / 128.f - mu * mu;
  float rs = rsqrtf(var + 2e-5f);
  float sc = rs * w[col], sh = bb[col] - mu * sc;
  y[(size_t)ln * DM + col] = v0 * sc + sh;
  y[(size_t)(ln + 64) * DM + col] = v1 * sc + sh;
}

// ---------------------------------------------------------------------------
// merged f32 -> bf16 cast for the six small weight matrices
// ---------------------------------------------------------------------------
__global__ __launch_bounds__(256) void castall_k(
    const float* __restrict__ s0, u16* __restrict__ d0,
    const float* __restrict__ s1, u16* __restrict__ d1,
    const float* __restrict__ s2, u16* __restrict__ d2,
    const float* __restrict__ s3, u16* __restrict__ d3,
    const float* __restrict__ s4, u16* __restrict__ d4,
    const float* __restrict__ s5, u16* __restrict__ d5)
{
  const int b0 = 262144, b1 = b0 + 98304, b2 = b1 + 110592,
            b3 = b2 + 36864, b4 = b3 + 147456, b5 = b4 + 147456; // 802816
  int idx = blockIdx.x * 256 + threadIdx.x;
  int stride = gridDim.x * 256;
  for (; idx < b5; idx += stride) {
    const float* s; u16* d; int l;
    if      (idx < b0) { s = s0; d = d0; l = idx; }
    else if (idx < b1) { s = s1; d = d1; l = idx - b0; }
    else if (idx < b2) { s = s2; d = d2; l = idx - b1; }
    else if (idx < b3) { s = s3; d = d3; l = idx - b2; }
    else if (idx < b4) { s = s4; d = d4; l = idx - b3; }
    else               { s = s5; d = d5; l = idx - b4; }
    float4 v = *(const float4*)(s + (size_t)l * 4);
    uint32_t p0 = (uint32_t)f2bf(v.x) | ((uint32_t)f2bf(v.y) << 16);
    uint32_t p1 = (uint32_t)f2bf(v.z) | ((uint32_t)f2bf(v.w) << 16);
    ((uint2*)d)[l] = make_uint2(p0, p1);
  }
}

// ---------------------------------------------------------------------------
// Orchestration
// ---------------------------------------------------------------------------
extern "C" void kernel_launch(void* const* d_in, const int* in_sizes, int n_in,
                              void* d_out, int out_size, void* d_ws, size_t ws_size,
                              hipStream_t stream)
{
  (void)in_sizes; (void)n_in; (void)out_size;
  const float* x    = (const float*)d_in[0];
  const float* fc1w = (const float*)d_in[1];
  const float* fc1b = (const float*)d_in[2];
  const float* fc2w = (const float*)d_in[3];
  const float* fc2b = (const float*)d_in[4];
  const float* pcw  = (const float*)d_in[5];
  const float* pcb  = (const float*)d_in[6];
  const float* ln1w = (const float*)d_in[7];
  const float* ln1b = (const float*)d_in[8];
  const float* qkvw = (const float*)d_in[9];
  const float* rpet = (const float*)d_in[10];
  const float* projw= (const float*)d_in[11];
  const float* projb= (const float*)d_in[12];
  const float* ln2w = (const float*)d_in[13];
  const float* ln2b = (const float*)d_in[14];
  const float* m1w  = (const float*)d_in[15];
  const float* m1b  = (const float*)d_in[16];
  const float* m2w  = (const float*)d_in[17];
  const float* m2b  = (const float*)d_in[18];
  const float* bn1w = (const float*)d_in[19];
  const float* bn1b = (const float*)d_in[20];
  const float* linw = (const float*)d_in[21];
  const float* linb = (const float*)d_in[22];
  const float* bn2w = (const float*)d_in[23];
  const float* bn2b = (const float*)d_in[24];
  float* y = (float*)d_out;

  // -------- aliased workspace layout (regions share by liveness) ----------
  const size_t RA = 0;                      // At / MLP1
  const size_t RB = 77070336;               // U / QKV / T3nb
  const size_t RC = RB + 57802752;          // H / AO / H2
  const size_t RD = RC + 19267584;          // T0 / T2
  const size_t RE = RD + 38535168;          // T1 / T3
  const size_t RF = RE + 38535168;          // PART (lin split-K)
  const size_t RG = RF + 9633792;           // small bf16 weights
  const size_t RS = RG + 6422528;           // bn1 scale/shift + partials + lut
  const size_t NEED = RS + 2048 + 16384 + 45056;
  if (ws_size < NEED) return;

  char* ws = (char*)d_ws;
  u16*   At    = (u16*)(ws + RA);
  u16*   MLP1  = (u16*)(ws + RA);
  u16*   U     = (u16*)(ws + RB);
  u16*   QKV   = (u16*)(ws + RB);
  u16*   T3nb  = (u16*)(ws + RB);
  u16*   H     = (u16*)(ws + RC);
  u16*   AO    = (u16*)(ws + RC);
  u16*   H2    = (u16*)(ws + RC);
  float* T0    = (float*)(ws + RD);
  float* T2    = (float*)(ws + RD);
  float* T1    = (float*)(ws + RE);
  float* T3    = (float*)(ws + RE);
  float* PART  = (float*)(ws + RF);
  u16*   wb_fc1 = (u16*)(ws + RG);
  u16*   wb_fc2 = wb_fc1 + 1048576;
  u16*   wb_qkv = wb_fc2 + 393216;
  u16*   wb_proj= wb_qkv + 442368;
  u16*   wb_m1  = wb_proj + 147456;
  u16*   wb_m2  = wb_m1 + 589824;
  float* bnS   = (float*)(ws + RS);
  float* bnSh  = bnS + 196;
  float* bnP   = (float*)(ws + RS + 2048);
  uint8_t* blut = (uint8_t*)(ws + RS + 2048 + 16384);

  // weight casts (f32 -> bf16), one merged kernel + bucket LUT
  castall_k<<<1024, 256, 0, stream>>>(fc1w, wb_fc1, fc2w, wb_fc2, qkvw, wb_qkv,
                                      projw, wb_proj, m1w, wb_m1, m2w, wb_m2);
  blut_k<<<196, 224, 0, stream>>>(blut);

  // x (B,CIN,N) -> At (B*N, CIN) bf16
  transpose_cast_k<<<dim3(32, 7, 128), dim3(32, 8), 0, stream>>>(x, At);

  // embed fc1: U = relu6(At @ fc1w^T + b)   [25088 x 1024]
  gemm_k<0><<<196 * 8, 256, 0, stream>>>(At, wb_fc1, fc1b, nullptr, U,
                                          MT, 1024, 1024, 1024, 1024, 8, 0);
  // embed fc2: T0 = U @ fc2w^T + b          [25088 x 384] f32
  gemm_k<1><<<196 * 3, 256, 0, stream>>>(U, wb_fc2, fc2b, nullptr, T0,
                                          MT, 384, 1024, 1024, 1024, 3, 0);
  // depthwise conv + bias + residual -> T1
  conv_res_k<<<(B_ * NPOS * 96 + 255) / 256, 256, 0, stream>>>(T0, pcw, pcb, T1);
  // LN1 -> H (bf16)
  ln_k<<<MT / 4, 256, 0, stream>>>(T1, ln1w, ln1b, H);
  // qkv: QKV = H @ qkvw^T (no bias)          [25088 x 1152] bf16
  gemm_k<2><<<196 * 9, 256, 0, stream>>>(H, wb_qkv, nullptr, nullptr, QKV,
                                          MT, 1152, 384, 384, 384, 9, 0);
  // fused attention (rpe in-kernel, flash-style, LUT bias) -> AO (bf16)
  attn_k<<<1536, 256, 0, stream>>>(QKV, rpet, blut, AO);
  // proj + residual(T1) -> T2 (f32)
  gemm_k<3><<<196 * 3, 256, 0, stream>>>(AO, wb_proj, projb, T1, T2,
                                          MT, 384, 384, 384, 384, 3, 0);
  // LN2 -> H2 (bf16)
  ln_k<<<MT / 4, 256, 0, stream>>>(T2, ln2w, ln2b, H2);
  // mlp fc1: MLP1 = relu6(H2 @ m1w^T + b)    [25088 x 1536] bf16
  gemm_k<0><<<196 * 12, 256, 0, stream>>>(H2, wb_m1, m1b, nullptr, MLP1,
                                           MT, 1536, 384, 384, 384, 12, 0);
  // mlp fc2 + residual(T2) -> T3 (f32)
  gemm_k<3><<<196 * 3, 256, 0, stream>>>(MLP1, wb_m2, m2b, T2, T3,
                                          MT, 384, 1536, 1536, 1536, 3, 0);
  // BN1 (per position) -> T3nb (bf16)
  bn1_partial_k<<<196 * 8, 256, 0, stream>>>(T3, bnP);
  bn1_finish_k<<<1, 256, 0, stream>>>(bnP, bn1w, bn1b, bnS, bnSh);
  bn1_apply_k<<<(MT * DM / 4 + 255) / 256, 256, 0, stream>>>(T3, bnS, bnSh, T3nb);
  // lin head: y = T3nb(128 x 75264) @ linw^T, split-K 49 x 1536 (W f32 direct)
  gemm_k<4><<<3 * 49, 256, 0, stream>>>(T3nb, linw, nullptr, nullptr, PART,
                                         128, 384, 1536, 75264, 75264, 3, 1536);
  lin_reduce_k<<<192, 256, 0, stream>>>(PART, linb, y);
  // BN2 (per feature over batch), in place on d_out
  bn2_k<<<384, 64, 0, stream>>>(y, bn2w, bn2b);
}

// Round 13
// 564.146 us; speedup vs baseline: 1.7115x; 1.2502x over previous
//
#include <hip/hip_runtime.h>
#include <cstdint>

// ---------------------------------------------------------------------------
// Problem constants
// ---------------------------------------------------------------------------
#define B_    128
#define CIN   1024
#define NPOS  196          // 14*14
#define DM    384
#define NH_   12
#define HD_   32
#define DFF_  1536
#define MT    25088        // B_*NPOS
#define SCALE_Q 0.17677669529663687f   // 1/sqrt(32)

typedef unsigned short u16;
typedef __attribute__((ext_vector_type(8))) short  short8;   // 8 bf16 (4 VGPR)
typedef __attribute__((ext_vector_type(4))) float  f32x4;    // MFMA C/D

__device__ __forceinline__ u16 f2bf(float f) {
  union { float f; uint32_t u; } v; v.f = f;
  uint32_t u = v.u;
  return (u16)((u + 0x7fffu + ((u >> 16) & 1u)) >> 16);
}
__device__ __forceinline__ float bf2f(u16 h) {
  union { uint32_t u; float f; } v; v.u = ((uint32_t)h) << 16;
  return v.f;
}

#define GLDS16(g, l)                                                           \
  __builtin_amdgcn_global_load_lds(                                            \
      (const __attribute__((address_space(1))) void*)(g),                      \
      (__attribute__((address_space(3))) void*)(l), 16, 0, 0)

// ---------------------------------------------------------------------------
// Generic bf16 MFMA GEMM:  out = epi( A[M x K] * W[N x K]^T )
// 128x128 tile, 4 waves, BK=32, dbuf 32KB.
// r13: COALESCED register staging (r12 was TA/txn-bound: global_load_lds
//   chunks had 64 lanes hitting 64 different 2KB-strided rows = ~64 txns
//   per instr, ~1024 txns per block-K-step -> ~6k cy/step critical path).
//   Now lane l loads 16B at (row base+l/4, kslot l&3): 4 lanes cover a
//   row's full 64B -> 16 lines/instr, 4x fewer txns, no repeated lines.
//   ds_write_b128 into the same [s][r][8] layout (reads unchanged,
//   conflict-free; writes a benign 4-way).
//   Schedule, 1 barrier per K-step: WRITE(t+1) -> frags(cur) ->
//   LOADREG(t+2) -> MFMA -> lgkmcnt(0) -> s_barrier.  Loads span a full
//   iteration; compiler inserts the vmcnt before WRITE's reg use.
// XCD-chunked bijective blockIdx swizzle (A-band L2 reuse).
// MODE: 0 = bias+relu6 -> bf16 | 1 = bias -> f32 | 2 = plain -> bf16
//       3 = bias+res -> f32    | 4 = split-K partial -> f32 (W f32, converted)
// ---------------------------------------------------------------------------
template <int MODE>
__global__ __launch_bounds__(256) void gemm_k(
    const u16* __restrict__ A, const void* __restrict__ Wv,
    const float* __restrict__ bias, const float* __restrict__ res,
    void* __restrict__ outp,
    int M, int N, int K, int lda, int ldw, int nTN, int splitK)
{
  __shared__ __align__(16) u16 As[2][4 * 128 * 8];   // dbuf [s][r][8], 16KB ea
  __shared__ __align__(16) u16 Bs[2][4 * 128 * 8];

  // ---- bijective XCD-chunked swizzle ----
  int nwg = gridDim.x;
  int bid0 = blockIdx.x;
  int qq = nwg >> 3, rr = nwg & 7;
  int xcd = bid0 & 7, idx = bid0 >> 3;
  int bid = (xcd < rr ? xcd * (qq + 1) : rr * (qq + 1) + (xcd - rr) * qq) + idx;

  int split = 0, mT, nT;
  if (MODE == 4) { split = bid / nTN; nT = bid % nTN; mT = 0; }
  else           { mT = bid / nTN;    nT = bid % nTN; }

  const u16* Ab = A + (size_t)split * splitK;
  float* outF = (float*)outp + ((MODE == 4) ? (size_t)split * (size_t)M * N : (size_t)0);
  u16*   outU = (u16*)outp;

  int tid = threadIdx.x;
  int wv = tid >> 6, ln = tid & 63;
  int q = ln >> 4, c = ln & 15;
  int wr = wv >> 1, wc = wv & 1;
  int mBase = mT * 128, nBase = nT * 128;

  f32x4 acc[4][4];
#pragma unroll
  for (int i = 0; i < 4; i++)
#pragma unroll
    for (int j = 0; j < 4; j++) acc[i][j] = (f32x4){0.f, 0.f, 0.f, 0.f};

  const u16* Ag = Ab + (size_t)mBase * lda;
  const u16*  Wg16 = (const u16*)Wv + (size_t)split * splitK + (size_t)nBase * ldw;
  const float* Wg32 = (const float*)Wv + (size_t)split * splitK + (size_t)nBase * ldw;

  int sl = ln & 3, rsub = ln >> 2;       // staging: lane -> (kslot, row-in-16)

  short8 ra[2], rb16[2];
  float4 rbf[2][2];                      // MODE 4: raw f32 W held in regs

  auto LOADREG = [&](int t) {
    int k0 = t * 32;
#pragma unroll
    for (int i = 0; i < 2; i++) {
      int r = wv * 32 + i * 16 + rsub;
      ra[i] = *(const short8*)(Ag + (size_t)r * lda + k0 + sl * 8);
      if constexpr (MODE == 4) {
        const float* wp = Wg32 + (size_t)r * ldw + k0 + sl * 8;
        rbf[i][0] = *(const float4*)wp;
        rbf[i][1] = *(const float4*)(wp + 4);
      } else {
        rb16[i] = *(const short8*)(Wg16 + (size_t)r * ldw + k0 + sl * 8);
      }
    }
  };
  auto WRITE = [&](int buf) {
#pragma unroll
    for (int i = 0; i < 2; i++) {
      int r = wv * 32 + i * 16 + rsub;
      *(short8*)&As[buf][(sl * 128 + r) * 8] = ra[i];
      if constexpr (MODE == 4) {
        short8 pk;
        pk[0] = (short)f2bf(rbf[i][0].x); pk[1] = (short)f2bf(rbf[i][0].y);
        pk[2] = (short)f2bf(rbf[i][0].z); pk[3] = (short)f2bf(rbf[i][0].w);
        pk[4] = (short)f2bf(rbf[i][1].x); pk[5] = (short)f2bf(rbf[i][1].y);
        pk[6] = (short)f2bf(rbf[i][1].z); pk[7] = (short)f2bf(rbf[i][1].w);
        *(short8*)&Bs[buf][(sl * 128 + r) * 8] = pk;
      } else {
        *(short8*)&Bs[buf][(sl * 128 + r) * 8] = rb16[i];
      }
    }
  };

  int NT = K >> 5;   // K-steps of 32 (all K are multiples of 32)

  // ---- prologue: t0 -> regs -> LDS buf0; t1 -> regs (in flight) ----
  LOADREG(0);
  WRITE(0);
  if (NT > 1) LOADREG(1);
  asm volatile("s_waitcnt lgkmcnt(0)" ::: "memory");
  __builtin_amdgcn_s_barrier();

  int cur = 0;
  for (int t = 0; t < NT; ++t) {
    // tile t+1 regs -> LDS (buffer cur^1 was fully consumed in iter t-1)
    if (t + 1 < NT) WRITE(cur ^ 1);
    // fragments of tile t -> registers
    short8 afr[4], bfr[4];
#pragma unroll
    for (int mt2 = 0; mt2 < 4; mt2++)
      afr[mt2] = *(const short8*)&As[cur][((q * 128) + wr * 64 + mt2 * 16 + c) * 8];
#pragma unroll
    for (int nt2 = 0; nt2 < 4; nt2++)
      bfr[nt2] = *(const short8*)&Bs[cur][((q * 128) + wc * 64 + nt2 * 16 + c) * 8];
    // issue tile t+2 global loads (full iteration in flight)
    if (t + 2 < NT) LOADREG(t + 2);
    __builtin_amdgcn_sched_barrier(0);
#pragma unroll
    for (int mt2 = 0; mt2 < 4; mt2++)
#pragma unroll
      for (int nt2 = 0; nt2 < 4; nt2++)
        acc[mt2][nt2] = __builtin_amdgcn_mfma_f32_16x16x32_bf16(
            afr[mt2], bfr[nt2], acc[mt2][nt2], 0, 0, 0);
    asm volatile("s_waitcnt lgkmcnt(0)" ::: "memory");
    __builtin_amdgcn_s_barrier();
    cur ^= 1;
  }

  // ---- epilogue ----
#pragma unroll
  for (int mt2 = 0; mt2 < 4; mt2++) {
    int row0 = mBase + wr * 64 + mt2 * 16 + q * 4;
#pragma unroll
    for (int nt2 = 0; nt2 < 4; nt2++) {
      int col = nBase + wc * 64 + nt2 * 16 + c;
      float bv = (MODE == 0 || MODE == 1 || MODE == 3) ? bias[col] : 0.f;
      f32x4 v = acc[mt2][nt2];
#pragma unroll
      for (int e = 0; e < 4; e++) {
        int row = row0 + e;
        float x = v[e] + bv;
        if (MODE == 0) x = fminf(fmaxf(x, 0.f), 6.f);
        if (MODE == 3) x += res[(size_t)row * N + col];
        if (MODE == 0 || MODE == 2) outU[(size_t)row * N + col] = f2bf(x);
        else                        outF[(size_t)row * N + col] = x;
      }
    }
  }
}

// ---------------------------------------------------------------------------
// Bucket LUT: lut[i][j] (u8, stride 224) = rp bucket 0..48 for j<196, 49
// (sentinel -> Rw[..][49] = -inf) for j in [196,224). Same for all (b,h).
// ---------------------------------------------------------------------------
__global__ __launch_bounds__(224) void blut_k(uint8_t* __restrict__ lut)
{
  int i = blockIdx.x;          // 0..195
  int j = threadIdx.x;         // 0..223
  uint8_t v = 49;
  if (j < 196) {
    int ri = i / 14, ci = i - ri * 14;
    int rj = j / 14, cj = j - rj * 14;
    int dr = ri - rj, dc = ci - cj;
    int adr = dr < 0 ? -dr : dr, adc = dc < 0 ? -dc : dc;
    int tr = adr <= 1 ? adr : (adr <= 3 ? 2 : 3);
    int tc = adc <= 1 ? adc : (adc <= 3 ? 2 : 3);
    int fr = dr < 0 ? -tr : tr, fc = dc < 0 ? -tc : tc;
    v = (uint8_t)(fr * 7 + fc + 24);
  }
  lut[i * 224 + j] = v;
}

// ---------------------------------------------------------------------------
// Fused attention per (b,h), flash-style over 7 j-chunks of 32.
// (unchanged from r11 — below GEMMs in the profile)
// ---------------------------------------------------------------------------
__global__ __launch_bounds__(256) void attn_k(
    const u16* __restrict__ QKV, const float* __restrict__ tabG,
    const uint8_t* __restrict__ lutG, u16* __restrict__ AO)
{
  __shared__ __align__(16) u16 Ks[4 * 196 * 8];     // [s][j][e] K fragments
  __shared__ __align__(16) u16 Vt[32 * 228];        // [d][j], pad j>=196 zero
  __shared__ __align__(16) u16 Pc4[4][4 * 16 * 8];  // per-wave P chunk (16x32)
  __shared__ __align__(16) u16 Ts[49 * 32];         // rpe table, [t][k] bf16
  __shared__ __align__(16) u16 Rw4[4][16 * 50];     // per-wave rpe scores bf16
  int bh = blockIdx.x; int b = bh / NH_, h = bh % NH_;
  int tid = threadIdx.x;
  int wv = tid >> 6, ln = tid & 63;
  int q = ln >> 4, c = ln & 15;
  size_t rowbase = (size_t)b * NPOS * 1152 + h * 32;

  // ---- stage K fragments via global_load_lds (wave-uniform dest) ----
  for (int cb = wv * 64; cb < 784; cb += 256) {
    int ch = cb + ln;
    if (ch < 784) {
      int s = ch / 196, j = ch - s * 196;
      GLDS16(QKV + rowbase + 384 + (size_t)j * 1152 + s * 8, &Ks[cb * 8]);
    }
  }
  // ---- stage rpe table transposed to [t][k] bf16 (once per block) ----
  for (int t = tid; t < 49 * 32; t += 256) {
    int tt = t >> 5, k = t & 31;
    Ts[t] = f2bf(tabG[k * 49 + tt]);
  }
  // ---- stage V transposed (vectorized) ----
  for (int t = tid; t < 784; t += 256) {
    int nn = t >> 2, d0 = (t & 3) * 8;
    short8 v = *(const short8*)(QKV + rowbase + 768 + (size_t)nn * 1152 + d0);
#pragma unroll
    for (int j = 0; j < 8; j++) Vt[(d0 + j) * 228 + nn] = (u16)v[j];
  }
  for (int t = tid; t < 32 * 32; t += 256) {
    int d = t >> 5, jj = 196 + (t & 31);
    Vt[d * 228 + jj] = 0;
  }
  __syncthreads();

  u16* Pw = Pc4[wv];
  u16* Rw = Rw4[wv];

  for (int mt = wv; mt < 13; mt += 4) {
    int mb = mt * 16;
    int irow = mb + c; if (irow > 195) irow = 195;
    short8 afrag = *(const short8*)(QKV + rowbase + (size_t)irow * 1152 + q * 8);
    int i0 = mb + q * 4;

    // ---- rpe scores via MFMA -> Rw; sentinel col 49 = -inf ----
#pragma unroll
    for (int nt = 0; nt < 4; nt++) {
      int t = nt * 16 + c;
      int tt = t < 49 ? t : 48;
      short8 tb = *(const short8*)&Ts[tt * 32 + q * 8];
      f32x4 z = {0.f, 0.f, 0.f, 0.f};
      f32x4 rr = __builtin_amdgcn_mfma_f32_16x16x32_bf16(afrag, tb, z, 0, 0, 0);
      if (t < 49) {
#pragma unroll
        for (int e = 0; e < 4; e++)
          Rw[(q * 4 + e) * 50 + t] = f2bf(rr[e] * SCALE_Q);
      }
    }
    if (c == 0) {
#pragma unroll
      for (int e = 0; e < 4; e++)
        Rw[(q * 4 + e) * 50 + 49] = 0xFF80;   // bf16 -inf
    }

    // per-row lut/Rw offsets (rows >=196 clamp to 195; results discarded)
    int lutOff[4], rwOff[4];
#pragma unroll
    for (int e = 0; e < 4; e++) {
      int i = i0 + e; if (i > 195) i = 195;
      lutOff[e] = i * 224;
      rwOff[e] = (q * 4 + e) * 50;
    }

    float m = -INFINITY;
    float l4[4] = {0.f, 0.f, 0.f, 0.f};
    f32x4 oacc[2];
    oacc[0] = (f32x4){0.f, 0.f, 0.f, 0.f};
    oacc[1] = (f32x4){0.f, 0.f, 0.f, 0.f};

    // ---- online softmax over 7 chunks of 32 j ----
    for (int ck = 0; ck < 7; ck++) {
      // 2 QK MFMAs from Ks LDS
      f32x4 s01[2];
#pragma unroll
      for (int t = 0; t < 2; t++) {
        int j = (ck * 2 + t) * 16 + c;
        int jc = j > 195 ? 195 : j;
        short8 bfrag = *(const short8*)&Ks[(q * 196 + jc) * 8];
        f32x4 z = {0.f, 0.f, 0.f, 0.f};
        s01[t] = __builtin_amdgcn_mfma_f32_16x16x32_bf16(afrag, bfrag, z, 0, 0, 0);
      }
      // bucket LUT loads (coalesced u8) -> Rw gather (mask folded in)
      uint8_t bk[2][4];
#pragma unroll
      for (int t = 0; t < 2; t++) {
        int jj = ck * 32 + t * 16 + c;
#pragma unroll
        for (int e = 0; e < 4; e++) bk[t][e] = lutG[lutOff[e] + jj];
      }
#pragma unroll
      for (int t = 0; t < 2; t++)
#pragma unroll
        for (int e = 0; e < 4; e++)
          s01[t][e] = s01[t][e] * SCALE_Q + bf2f(Rw[rwOff[e] + bk[t][e]]);

      // shared chunk max per 16-lane q-group (common shift cancels per row)
      float mc = s01[0][0];
#pragma unroll
      for (int t = 0; t < 2; t++)
#pragma unroll
        for (int e = 0; e < 4; e++) mc = fmaxf(mc, s01[t][e]);
#pragma unroll
      for (int o = 1; o < 16; o <<= 1) mc = fmaxf(mc, __shfl_xor(mc, o, 64));
      float mn = fmaxf(m, mc);
      float sc = __expf(m - mn);
      m = mn;
#pragma unroll
      for (int t = 0; t < 2; t++)
#pragma unroll
        for (int e = 0; e < 4; e++) s01[t][e] = __expf(s01[t][e] - mn);
#pragma unroll
      for (int e = 0; e < 4; e++) {
        l4[e] = l4[e] * sc + s01[0][e] + s01[1][e];
        oacc[0][e] *= sc; oacc[1][e] *= sc;
      }
      // P chunk store, truncating bf16, A-frag layout
#pragma unroll
      for (int t = 0; t < 2; t++) {
        int sl2 = t * 2 + (c >> 3);
#pragma unroll
        for (int e = 0; e < 4; e++) {
          union { float f; uint32_t u; } pv; pv.f = s01[t][e];
          Pw[(sl2 * 16 + q * 4 + e) * 8 + (c & 7)] = (u16)(pv.u >> 16);
        }
      }
      // PV: 2 MFMAs (d halves)
#pragma unroll
      for (int n2 = 0; n2 < 2; n2++) {
        short8 pa = *(const short8*)&Pw[(q * 16 + c) * 8];
        short8 vb = *(const short8*)&Vt[(n2 * 16 + c) * 228 + ck * 32 + q * 8];
        oacc[n2] = __builtin_amdgcn_mfma_f32_16x16x32_bf16(pa, vb, oacc[n2], 0, 0, 0);
      }
    }

    // final 1/l and store
    float inv[4];
#pragma unroll
    for (int e = 0; e < 4; e++) {
      float s2 = l4[e];
#pragma unroll
      for (int o = 1; o < 16; o <<= 1) s2 += __shfl_xor(s2, o, 64);
      inv[e] = 1.f / s2;
    }
#pragma unroll
    for (int n2 = 0; n2 < 2; n2++) {
#pragma unroll
      for (int e = 0; e < 4; e++) {
        int i = i0 + e;
        if (i < 196) {
          int d = n2 * 16 + c;
          AO[((size_t)b * NPOS + i) * DM + h * 32 + d] = f2bf(oacc[n2][e] * inv[e]);
        }
      }
    }
  }
}

// ---------------------------------------------------------------------------
// x (B, CIN, HW, HW) f32  ->  A_t (B*NPOS, CIN) bf16
// ---------------------------------------------------------------------------
__global__ __launch_bounds__(256) void transpose_cast_k(
    const float* __restrict__ x, u16* __restrict__ At)
{
  __shared__ float t[32][33];
  int c0 = blockIdx.x * 32, n0 = blockIdx.y * 32, b = blockIdx.z;
  int tx = threadIdx.x, ty = threadIdx.y;
  const float* xb = x + (size_t)b * CIN * NPOS;
#pragma unroll
  for (int i = 0; i < 4; i++) {
    int cc = c0 + ty + i * 8, nn = n0 + tx;
    t[ty + i * 8][tx] = (nn < NPOS) ? xb[(size_t)cc * NPOS + nn] : 0.f;
  }
  __syncthreads();
  u16* Ab = At + (size_t)b * NPOS * CIN;
#pragma unroll
  for (int i = 0; i < 4; i++) {
    int nn = n0 + ty + i * 8, cc = c0 + tx;
    if (nn < NPOS) Ab[(size_t)nn * CIN + cc] = f2bf(t[tx][ty + i * 8]);
  }
}

// ---------------------------------------------------------------------------
// depthwise 3x3 SAME conv + bias + identity residual (fp32)
// ---------------------------------------------------------------------------
__global__ __launch_bounds__(256) void conv_res_k(
    const float* __restrict__ T0, const float* __restrict__ pcw,
    const float* __restrict__ pcb, float* __restrict__ T1)
{
  int idx = blockIdx.x * 256 + threadIdx.x;
  if (idx >= B_ * NPOS * 96) return;
  int d4 = idx % 96; int rem = idx / 96;
  int n = rem % NPOS; int b = rem / NPOS;
  int hh = n / 14, ww = n % 14;
  int d0 = d4 * 4;
  float w9[4][9];
#pragma unroll
  for (int j = 0; j < 4; j++)
#pragma unroll
    for (int t = 0; t < 9; t++) w9[j][t] = pcw[(d0 + j) * 9 + t];
  const float* base = T0 + (size_t)b * NPOS * DM;
  float4 ctr = *(const float4*)(base + (size_t)n * DM + d0);
  float ax = ctr.x + pcb[d0], ay = ctr.y + pcb[d0 + 1];
  float az = ctr.z + pcb[d0 + 2], aw = ctr.w + pcb[d0 + 3];
#pragma unroll
  for (int kh = 0; kh < 3; kh++) {
    int h2 = hh + kh - 1;
    if (h2 < 0 || h2 >= 14) continue;
#pragma unroll
    for (int kw = 0; kw < 3; kw++) {
      int w2 = ww + kw - 1;
      if (w2 < 0 || w2 >= 14) continue;
      float4 v = *(const float4*)(base + (size_t)(h2 * 14 + w2) * DM + d0);
      int t = kh * 3 + kw;
      ax += v.x * w9[0][t]; ay += v.y * w9[1][t];
      az += v.z * w9[2][t]; aw += v.w * w9[3][t];
    }
  }
  float4 o = {ax, ay, az, aw};
  *(float4*)(T1 + (size_t)b * NPOS * DM + (size_t)n * DM + d0) = o;
}

// ---------------------------------------------------------------------------
// LayerNorm(384) f32 -> bf16, one wave per row (float2-vectorized)
// ---------------------------------------------------------------------------
__global__ __launch_bounds__(256) void ln_k(
    const float* __restrict__ in, const float* __restrict__ w,
    const float* __restrict__ bb, u16* __restrict__ out)
{
  int row = blockIdx.x * 4 + (threadIdx.x >> 6);
  int ln = threadIdx.x & 63;
  const float2* r = (const float2*)(in + (size_t)row * DM);
  float2 v[3]; float s = 0.f, sq = 0.f;
#pragma unroll
  for (int j = 0; j < 3; j++) {
    v[j] = r[ln + 64 * j];
    s += v[j].x + v[j].y; sq += v[j].x * v[j].x + v[j].y * v[j].y;
  }
#pragma unroll
  for (int o = 1; o < 64; o <<= 1) { s += __shfl_xor(s, o, 64); sq += __shfl_xor(sq, o, 64); }
  float mu = s * (1.f / 384.f);
  float var = sq * (1.f / 384.f) - mu * mu;
  float rs = rsqrtf(var + 1e-5f);
  uint32_t* orow = (uint32_t*)(out + (size_t)row * DM);
#pragma unroll
  for (int j = 0; j < 3; j++) {
    int d = (ln + 64 * j) * 2;
    float a = (v[j].x - mu) * rs * w[d] + bb[d];
    float bq = (v[j].y - mu) * rs * w[d + 1] + bb[d + 1];
    orow[ln + 64 * j] = (uint32_t)f2bf(a) | ((uint32_t)f2bf(bq) << 16);
  }
}

// ---------------------------------------------------------------------------
// BN1 over (batch, dmodel) per position n: two-stage stats
// ---------------------------------------------------------------------------
__global__ __launch_bounds__(256) void bn1_partial_k(
    const float* __restrict__ T3, float* __restrict__ part)
{
  int n = blockIdx.x >> 3, g = blockIdx.x & 7;
  int tid = threadIdx.x;
  float s = 0.f, sq = 0.f;
  for (int b2 = g * 16; b2 < g * 16 + 16; b2++) {
    const float* p = T3 + ((size_t)b2 * NPOS + n) * DM;
    for (int d = tid; d < DM; d += 256) { float v = p[d]; s += v; sq += v * v; }
  }
#pragma unroll
  for (int o = 1; o < 64; o <<= 1) { s += __shfl_xor(s, o, 64); sq += __shfl_xor(sq, o, 64); }
  __shared__ float ls[4], lq[4];
  int wv = tid >> 6, ln = tid & 63;
  if (ln == 0) { ls[wv] = s; lq[wv] = sq; }
  __syncthreads();
  if (tid == 0) {
    part[blockIdx.x * 2]     = ls[0] + ls[1] + ls[2] + ls[3];
    part[blockIdx.x * 2 + 1] = lq[0] + lq[1] + lq[2] + lq[3];
  }
}

__global__ __launch_bounds__(256) void bn1_finish_k(
    const float* __restrict__ part, const float* __restrict__ bw,
    const float* __restrict__ bbb, float* __restrict__ scaleArr,
    float* __restrict__ shiftArr)
{
  int n = threadIdx.x;
  if (n >= NPOS) return;
  float S = 0.f, Q = 0.f;
#pragma unroll
  for (int g = 0; g < 8; g++) { S += part[(n * 8 + g) * 2]; Q += part[(n * 8 + g) * 2 + 1]; }
  float mu = S / 49152.f;
  float var = Q / 49152.f - mu * mu;
  float rs = rsqrtf(var + 2e-5f);
  float sc = rs * bw[n];
  scaleArr[n] = sc;
  shiftArr[n] = bbb[n] - mu * sc;
}

__global__ __launch_bounds__(256) void bn1_apply_k(
    const float* __restrict__ T3, const float* __restrict__ scaleArr,
    const float* __restrict__ shiftArr, u16* __restrict__ outb)
{
  int idx = blockIdx.x * 256 + threadIdx.x;           // float4 index
  if (idx >= MT * DM / 4) return;
  int n = (idx / 96) % NPOS;
  float4 v = *(const float4*)(T3 + (size_t)idx * 4);
  float sc = scaleArr[n], sh = shiftArr[n];
  uint32_t p0 = (uint32_t)f2bf(v.x * sc + sh) | ((uint32_t)f2bf(v.y * sc + sh) << 16);
  uint32_t p1 = (uint32_t)f2bf(v.z * sc + sh) | ((uint32_t)f2bf(v.w * sc + sh) << 16);
  ((uint2*)outb)[idx] = make_uint2(p0, p1);
}

// ---------------------------------------------------------------------------
// split-K reduce for lin head + bias
// ---------------------------------------------------------------------------
__global__ __launch_bounds__(256) void lin_reduce_k(
    const float* __restrict__ part, const float* __restrict__ lb,
    float* __restrict__ y)
{
  int idx = blockIdx.x * 256 + threadIdx.x;
  if (idx >= 128 * DM) return;
  int col = idx % DM;
  float s = lb[col];
#pragma unroll
  for (int sp = 0; sp < 49; sp++) s += part[(size_t)sp * (128 * DM) + idx];
  y[idx] = s;
}

// ---------------------------------------------------------------------------
// BN2 over batch (128) per feature col, in-place on y
// ---------------------------------------------------------------------------
__global__ __launch_bounds__(64) void bn2_k(
    float* __restrict__ y, const float* __restrict__ w,
    const float* __restrict__ bb)
{
  int col = blockIdx.x; int ln = threadIdx.x;
  float v0 = y[(size_t)ln * DM + col];
  float v1 = y[(size_t)(ln + 64) * DM + col];
  float s = v0 + v1, sq = v0 * v0 + v1 * v1;
#pragma unroll
  for (int o = 1; o < 64; o <<= 1) { s += __shfl_xor(s, o, 64); sq += __shfl_xor(sq, o, 64); }
  float mu = s / 128.f;
  float var = sq / 128.f - mu * mu;
  float rs = rsqrtf(var + 2e-5f);
  float sc = rs * w[col], sh = bb[col] - mu * sc;
  y[(size_t)ln * DM + col] = v0 * sc + sh;
  y[(size_t)(ln + 64) * DM + col] = v1 * sc + sh;
}

// ---------------------------------------------------------------------------
// merged f32 -> bf16 cast for the six small weight matrices
// ---------------------------------------------------------------------------
__global__ __launch_bounds__(256) void castall_k(
    const float* __restrict__ s0, u16* __restrict__ d0,
    const float* __restrict__ s1, u16* __restrict__ d1,
    const float* __restrict__ s2, u16* __restrict__ d2,
    const float* __restrict__ s3, u16* __restrict__ d3,
    const float* __restrict__ s4, u16* __restrict__ d4,
    const float* __restrict__ s5, u16* __restrict__ d5)
{
  const int b0 = 262144, b1 = b0 + 98304, b2 = b1 + 110592,
            b3 = b2 + 36864, b4 = b3 + 147456, b5 = b4 + 147456; // 802816
  int idx = blockIdx.x * 256 + threadIdx.x;
  int stride = gridDim.x * 256;
  for (; idx < b5; idx += stride) {
    const float* s; u16* d; int l;
    if      (idx < b0) { s = s0; d = d0; l = idx; }
    else if (idx < b1) { s = s1; d = d1; l = idx - b0; }
    else if (idx < b2) { s = s2; d = d2; l = idx - b1; }
    else if (idx < b3) { s = s3; d = d3; l = idx - b2; }
    else if (idx < b4) { s = s4; d = d4; l = idx - b3; }
    else               { s = s5; d = d5; l = idx - b4; }
    float4 v = *(const float4*)(s + (size_t)l * 4);
    uint32_t p0 = (uint32_t)f2bf(v.x) | ((uint32_t)f2bf(v.y) << 16);
    uint32_t p1 = (uint32_t)f2bf(v.z) | ((uint32_t)f2bf(v.w) << 16);
    ((uint2*)d)[l] = make_uint2(p0, p1);
  }
}

// ---------------------------------------------------------------------------
// Orchestration
// ---------------------------------------------------------------------------
extern "C" void kernel_launch(void* const* d_in, const int* in_sizes, int n_in,
                              void* d_out, int out_size, void* d_ws, size_t ws_size,
                              hipStream_t stream)
{
  (void)in_sizes; (void)n_in; (void)out_size;
  const float* x    = (const float*)d_in[0];
  const float* fc1w = (const float*)d_in[1];
  const float* fc1b = (const float*)d_in[2];
  const float* fc2w = (const float*)d_in[3];
  const float* fc2b = (const float*)d_in[4];
  const float* pcw  = (const float*)d_in[5];
  const float* pcb  = (const float*)d_in[6];
  const float* ln1w = (const float*)d_in[7];
  const float* ln1b = (const float*)d_in[8];
  const float* qkvw = (const float*)d_in[9];
  const float* rpet = (const float*)d_in[10];
  const float* projw= (const float*)d_in[11];
  const float* projb= (const float*)d_in[12];
  const float* ln2w = (const float*)d_in[13];
  const float* ln2b = (const float*)d_in[14];
  const float* m1w  = (const float*)d_in[15];
  const float* m1b  = (const float*)d_in[16];
  const float* m2w  = (const float*)d_in[17];
  const float* m2b  = (const float*)d_in[18];
  const float* bn1w = (const float*)d_in[19];
  const float* bn1b = (const float*)d_in[20];
  const float* linw = (const float*)d_in[21];
  const float* linb = (const float*)d_in[22];
  const float* bn2w = (const float*)d_in[23];
  const float* bn2b = (const float*)d_in[24];
  float* y = (float*)d_out;

  // -------- aliased workspace layout (regions share by liveness) ----------
  const size_t RA = 0;                      // At / MLP1
  const size_t RB = 77070336;               // U / QKV / T3nb
  const size_t RC = RB + 57802752;          // H / AO / H2
  const size_t RD = RC + 19267584;          // T0 / T2
  const size_t RE = RD + 38535168;          // T1 / T3
  const size_t RF = RE + 38535168;          // PART (lin split-K)
  const size_t RG = RF + 9633792;           // small bf16 weights
  const size_t RS = RG + 6422528;           // bn1 scale/shift + partials + lut
  const size_t NEED = RS + 2048 + 16384 + 45056;
  if (ws_size < NEED) return;

  char* ws = (char*)d_ws;
  u16*   At    = (u16*)(ws + RA);
  u16*   MLP1  = (u16*)(ws + RA);
  u16*   U     = (u16*)(ws + RB);
  u16*   QKV   = (u16*)(ws + RB);
  u16*   T3nb  = (u16*)(ws + RB);
  u16*   H     = (u16*)(ws + RC);
  u16*   AO    = (u16*)(ws + RC);
  u16*   H2    = (u16*)(ws + RC);
  float* T0    = (float*)(ws + RD);
  float* T2    = (float*)(ws + RD);
  float* T1    = (float*)(ws + RE);
  float* T3    = (float*)(ws + RE);
  float* PART  = (float*)(ws + RF);
  u16*   wb_fc1 = (u16*)(ws + RG);
  u16*   wb_fc2 = wb_fc1 + 1048576;
  u16*   wb_qkv = wb_fc2 + 393216;
  u16*   wb_proj= wb_qkv + 442368;
  u16*   wb_m1  = wb_proj + 147456;
  u16*   wb_m2  = wb_m1 + 589824;
  float* bnS   = (float*)(ws + RS);
  float* bnSh  = bnS + 196;
  float* bnP   = (float*)(ws + RS + 2048);
  uint8_t* blut = (uint8_t*)(ws + RS + 2048 + 16384);

  // weight casts (f32 -> bf16), one merged kernel + bucket LUT
  castall_k<<<1024, 256, 0, stream>>>(fc1w, wb_fc1, fc2w, wb_fc2, qkvw, wb_qkv,
                                      projw, wb_proj, m1w, wb_m1, m2w, wb_m2);
  blut_k<<<196, 224, 0, stream>>>(blut);

  // x (B,CIN,N) -> At (B*N, CIN) bf16
  transpose_cast_k<<<dim3(32, 7, 128), dim3(32, 8), 0, stream>>>(x, At);

  // embed fc1: U = relu6(At @ fc1w^T + b)   [25088 x 1024]
  gemm_k<0><<<196 * 8, 256, 0, stream>>>(At, wb_fc1, fc1b, nullptr, U,
                                          MT, 1024, 1024, 1024, 1024, 8, 0);
  // embed fc2: T0 = U @ fc2w^T + b          [25088 x 384] f32
  gemm_k<1><<<196 * 3, 256, 0, stream>>>(U, wb_fc2, fc2b, nullptr, T0,
                                          MT, 384, 1024, 1024, 1024, 3, 0);
  // depthwise conv + bias + residual -> T1
  conv_res_k<<<(B_ * NPOS * 96 + 255) / 256, 256, 0, stream>>>(T0, pcw, pcb, T1);
  // LN1 -> H (bf16)
  ln_k<<<MT / 4, 256, 0, stream>>>(T1, ln1w, ln1b, H);
  // qkv: QKV = H @ qkvw^T (no bias)          [25088 x 1152] bf16
  gemm_k<2><<<196 * 9, 256, 0, stream>>>(H, wb_qkv, nullptr, nullptr, QKV,
                                          MT, 1152, 384, 384, 384, 9, 0);
  // fused attention (rpe in-kernel, flash-style, LUT bias) -> AO (bf16)
  attn_k<<<1536, 256, 0, stream>>>(QKV, rpet, blut, AO);
  // proj + residual(T1) -> T2 (f32)
  gemm_k<3><<<196 * 3, 256, 0, stream>>>(AO, wb_proj, projb, T1, T2,
                                          MT, 384, 384, 384, 384, 3, 0);
  // LN2 -> H2 (bf16)
  ln_k<<<MT / 4, 256, 0, stream>>>(T2, ln2w, ln2b, H2);
  // mlp fc1: MLP1 = relu6(H2 @ m1w^T + b)    [25088 x 1536] bf16
  gemm_k<0><<<196 * 12, 256, 0, stream>>>(H2, wb_m1, m1b, nullptr, MLP1,
                                           MT, 1536, 384, 384, 384, 12, 0);
  // mlp fc2 + residual(T2) -> T3 (f32)
  gemm_k<3><<<196 * 3, 256, 0, stream>>>(MLP1, wb_m2, m2b, T2, T3,
                                          MT, 384, 1536, 1536, 1536, 3, 0);
  // BN1 (per position) -> T3nb (bf16)
  bn1_partial_k<<<196 * 8, 256, 0, stream>>>(T3, bnP);
  bn1_finish_k<<<1, 256, 0, stream>>>(bnP, bn1w, bn1b, bnS, bnSh);
  bn1_apply_k<<<(MT * DM / 4 + 255) / 256, 256, 0, stream>>>(T3, bnS, bnSh, T3nb);
  // lin head: y = T3nb(128 x 75264) @ linw^T, split-K 49 x 1536 (W f32 direct)
  gemm_k<4><<<3 * 49, 256, 0, stream>>>(T3nb, linw, nullptr, nullptr, PART,
                                         128, 384, 1536, 75264, 75264, 3, 1536);
  lin_reduce_k<<<192, 256, 0, stream>>>(PART, linb, y);
  // BN2 (per feature over batch), in place on d_out
  bn2_k<<<384, 64, 0, stream>>>(y, bn2w, bn2b);
}

// Round 14
// 552.482 us; speedup vs baseline: 1.7476x; 1.0211x over previous
//
#include <hip/hip_runtime.h>
#include <cstdint>

// ---------------------------------------------------------------------------
// Problem constants
// ---------------------------------------------------------------------------
#define B_    128
#define CIN   1024
#define NPOS  196          // 14*14
#define DM    384
#define NH_   12
#define HD_   32
#define DFF_  1536
#define MT    25088        // B_*NPOS
#define SCALE_Q 0.17677669529663687f   // 1/sqrt(32)

typedef unsigned short u16;
typedef __attribute__((ext_vector_type(8))) short  short8;   // 8 bf16 (4 VGPR)
typedef __attribute__((ext_vector_type(4))) float  f32x4;    // MFMA C/D

__device__ __forceinline__ u16 f2bf(float f) {
  union { float f; uint32_t u; } v; v.f = f;
  uint32_t u = v.u;
  return (u16)((u + 0x7fffu + ((u >> 16) & 1u)) >> 16);
}
__device__ __forceinline__ float bf2f(u16 h) {
  union { uint32_t u; float f; } v; v.u = ((uint32_t)h) << 16;
  return v.f;
}

#define GLDS16(g, l)                                                           \
  __builtin_amdgcn_global_load_lds(                                            \
      (const __attribute__((address_space(1))) void*)(g),                      \
      (__attribute__((address_space(3))) void*)(l), 16, 0, 0)

// ---------------------------------------------------------------------------
// Generic bf16 MFMA GEMM (unchanged from r13: coalesced register staging,
// 1-barrier K-step pipeline, XCD swizzle). All GEMMs below attn in profile.
// MODE: 0 = bias+relu6 -> bf16 | 1 = bias -> f32 | 2 = plain -> bf16
//       3 = bias+res -> f32    | 4 = split-K partial -> f32 (W f32, converted)
// ---------------------------------------------------------------------------
template <int MODE>
__global__ __launch_bounds__(256) void gemm_k(
    const u16* __restrict__ A, const void* __restrict__ Wv,
    const float* __restrict__ bias, const float* __restrict__ res,
    void* __restrict__ outp,
    int M, int N, int K, int lda, int ldw, int nTN, int splitK)
{
  __shared__ __align__(16) u16 As[2][4 * 128 * 8];   // dbuf [s][r][8], 16KB ea
  __shared__ __align__(16) u16 Bs[2][4 * 128 * 8];

  // ---- bijective XCD-chunked swizzle ----
  int nwg = gridDim.x;
  int bid0 = blockIdx.x;
  int qq = nwg >> 3, rr = nwg & 7;
  int xcd = bid0 & 7, idx = bid0 >> 3;
  int bid = (xcd < rr ? xcd * (qq + 1) : rr * (qq + 1) + (xcd - rr) * qq) + idx;

  int split = 0, mT, nT;
  if (MODE == 4) { split = bid / nTN; nT = bid % nTN; mT = 0; }
  else           { mT = bid / nTN;    nT = bid % nTN; }

  const u16* Ab = A + (size_t)split * splitK;
  float* outF = (float*)outp + ((MODE == 4) ? (size_t)split * (size_t)M * N : (size_t)0);
  u16*   outU = (u16*)outp;

  int tid = threadIdx.x;
  int wv = tid >> 6, ln = tid & 63;
  int q = ln >> 4, c = ln & 15;
  int wr = wv >> 1, wc = wv & 1;
  int mBase = mT * 128, nBase = nT * 128;

  f32x4 acc[4][4];
#pragma unroll
  for (int i = 0; i < 4; i++)
#pragma unroll
    for (int j = 0; j < 4; j++) acc[i][j] = (f32x4){0.f, 0.f, 0.f, 0.f};

  const u16* Ag = Ab + (size_t)mBase * lda;
  const u16*  Wg16 = (const u16*)Wv + (size_t)split * splitK + (size_t)nBase * ldw;
  const float* Wg32 = (const float*)Wv + (size_t)split * splitK + (size_t)nBase * ldw;

  int sl = ln & 3, rsub = ln >> 2;       // staging: lane -> (kslot, row-in-16)

  short8 ra[2], rb16[2];
  float4 rbf[2][2];                      // MODE 4: raw f32 W held in regs

  auto LOADREG = [&](int t) {
    int k0 = t * 32;
#pragma unroll
    for (int i = 0; i < 2; i++) {
      int r = wv * 32 + i * 16 + rsub;
      ra[i] = *(const short8*)(Ag + (size_t)r * lda + k0 + sl * 8);
      if constexpr (MODE == 4) {
        const float* wp = Wg32 + (size_t)r * ldw + k0 + sl * 8;
        rbf[i][0] = *(const float4*)wp;
        rbf[i][1] = *(const float4*)(wp + 4);
      } else {
        rb16[i] = *(const short8*)(Wg16 + (size_t)r * ldw + k0 + sl * 8);
      }
    }
  };
  auto WRITE = [&](int buf) {
#pragma unroll
    for (int i = 0; i < 2; i++) {
      int r = wv * 32 + i * 16 + rsub;
      *(short8*)&As[buf][(sl * 128 + r) * 8] = ra[i];
      if constexpr (MODE == 4) {
        short8 pk;
        pk[0] = (short)f2bf(rbf[i][0].x); pk[1] = (short)f2bf(rbf[i][0].y);
        pk[2] = (short)f2bf(rbf[i][0].z); pk[3] = (short)f2bf(rbf[i][0].w);
        pk[4] = (short)f2bf(rbf[i][1].x); pk[5] = (short)f2bf(rbf[i][1].y);
        pk[6] = (short)f2bf(rbf[i][1].z); pk[7] = (short)f2bf(rbf[i][1].w);
        *(short8*)&Bs[buf][(sl * 128 + r) * 8] = pk;
      } else {
        *(short8*)&Bs[buf][(sl * 128 + r) * 8] = rb16[i];
      }
    }
  };

  int NT = K >> 5;   // K-steps of 32 (all K are multiples of 32)

  // ---- prologue: t0 -> regs -> LDS buf0; t1 -> regs (in flight) ----
  LOADREG(0);
  WRITE(0);
  if (NT > 1) LOADREG(1);
  asm volatile("s_waitcnt lgkmcnt(0)" ::: "memory");
  __builtin_amdgcn_s_barrier();

  int cur = 0;
  for (int t = 0; t < NT; ++t) {
    // tile t+1 regs -> LDS (buffer cur^1 was fully consumed in iter t-1)
    if (t + 1 < NT) WRITE(cur ^ 1);
    // fragments of tile t -> registers
    short8 afr[4], bfr[4];
#pragma unroll
    for (int mt2 = 0; mt2 < 4; mt2++)
      afr[mt2] = *(const short8*)&As[cur][((q * 128) + wr * 64 + mt2 * 16 + c) * 8];
#pragma unroll
    for (int nt2 = 0; nt2 < 4; nt2++)
      bfr[nt2] = *(const short8*)&Bs[cur][((q * 128) + wc * 64 + nt2 * 16 + c) * 8];
    // issue tile t+2 global loads (full iteration in flight)
    if (t + 2 < NT) LOADREG(t + 2);
    __builtin_amdgcn_sched_barrier(0);
#pragma unroll
    for (int mt2 = 0; mt2 < 4; mt2++)
#pragma unroll
      for (int nt2 = 0; nt2 < 4; nt2++)
        acc[mt2][nt2] = __builtin_amdgcn_mfma_f32_16x16x32_bf16(
            afr[mt2], bfr[nt2], acc[mt2][nt2], 0, 0, 0);
    asm volatile("s_waitcnt lgkmcnt(0)" ::: "memory");
    __builtin_amdgcn_s_barrier();
    cur ^= 1;
  }

  // ---- epilogue ----
#pragma unroll
  for (int mt2 = 0; mt2 < 4; mt2++) {
    int row0 = mBase + wr * 64 + mt2 * 16 + q * 4;
#pragma unroll
    for (int nt2 = 0; nt2 < 4; nt2++) {
      int col = nBase + wc * 64 + nt2 * 16 + c;
      float bv = (MODE == 0 || MODE == 1 || MODE == 3) ? bias[col] : 0.f;
      f32x4 v = acc[mt2][nt2];
#pragma unroll
      for (int e = 0; e < 4; e++) {
        int row = row0 + e;
        float x = v[e] + bv;
        if (MODE == 0) x = fminf(fmaxf(x, 0.f), 6.f);
        if (MODE == 3) x += res[(size_t)row * N + col];
        if (MODE == 0 || MODE == 2) outU[(size_t)row * N + col] = f2bf(x);
        else                        outF[(size_t)row * N + col] = x;
      }
    }
  }
}

// ---------------------------------------------------------------------------
// Bucket LUT: lut[i][j] (u8, stride 224) = rp bucket 0..48 for j<196, 49
// (sentinel -> Rw[..][49] = -inf) for j in [196,224). Same for all (b,h).
// ---------------------------------------------------------------------------
__global__ __launch_bounds__(224) void blut_k(uint8_t* __restrict__ lut)
{
  int i = blockIdx.x;          // 0..195
  int j = threadIdx.x;         // 0..223
  uint8_t v = 49;
  if (j < 196) {
    int ri = i / 14, ci = i - ri * 14;
    int rj = j / 14, cj = j - rj * 14;
    int dr = ri - rj, dc = ci - cj;
    int adr = dr < 0 ? -dr : dr, adc = dc < 0 ? -dc : dc;
    int tr = adr <= 1 ? adr : (adr <= 3 ? 2 : 3);
    int tc = adc <= 1 ? adc : (adc <= 3 ? 2 : 3);
    int fr = dr < 0 ? -tr : tr, fc = dc < 0 ? -tc : tc;
    v = (uint8_t)(fr * 7 + fc + 24);
  }
  lut[i * 224 + j] = v;
}

// ---------------------------------------------------------------------------
// Fused attention per (b,h), flash-style over 7 j-chunks of 32.
// r14: 2-tile ILP — each wave processes TWO m-tiles simultaneously
//   (pairs (wv, wv+4) then (wv+8, wv+12)); the two online-softmax chains
//   are independent so tile B fills tile A's latency stalls, while the
//   K/V/rpe-table fragments are SHARED (loaded once, used twice).
//   Was: MfmaUtil 4%, VALUBusy 33% @ 97 us — pure chain-latency-bound.
// LDS = 12544(Ks) + 14592(Vt) + 8192(Pc x2) + 3136(Ts) + 12800(Rw x2)
//     = 51264 -> 3 blocks/CU.
// ---------------------------------------------------------------------------
__global__ __launch_bounds__(256) void attn_k(
    const u16* __restrict__ QKV, const float* __restrict__ tabG,
    const uint8_t* __restrict__ lutG, u16* __restrict__ AO)
{
  __shared__ __align__(16) u16 Ks[4 * 196 * 8];      // [s][j][e] K fragments
  __shared__ __align__(16) u16 Vt[32 * 228];         // [d][j], pad j>=196 zero
  __shared__ __align__(16) u16 Pc4[4][2][512];       // per-wave, per-tile P chunk
  __shared__ __align__(16) u16 Ts[49 * 32];          // rpe table, [t][k] bf16
  __shared__ __align__(16) u16 Rw4[4][2][16 * 50];   // per-wave, per-tile rpe
  int bh = blockIdx.x; int b = bh / NH_, h = bh % NH_;
  int tid = threadIdx.x;
  int wv = tid >> 6, ln = tid & 63;
  int q = ln >> 4, c = ln & 15;
  size_t rowbase = (size_t)b * NPOS * 1152 + h * 32;

  // ---- stage K fragments via global_load_lds (wave-uniform dest) ----
  for (int cb = wv * 64; cb < 784; cb += 256) {
    int ch = cb + ln;
    if (ch < 784) {
      int s = ch / 196, j = ch - s * 196;
      GLDS16(QKV + rowbase + 384 + (size_t)j * 1152 + s * 8, &Ks[cb * 8]);
    }
  }
  // ---- stage rpe table transposed to [t][k] bf16 (once per block) ----
  for (int t = tid; t < 49 * 32; t += 256) {
    int tt = t >> 5, k = t & 31;
    Ts[t] = f2bf(tabG[k * 49 + tt]);
  }
  // ---- stage V transposed (vectorized) ----
  for (int t = tid; t < 784; t += 256) {
    int nn = t >> 2, d0 = (t & 3) * 8;
    short8 v = *(const short8*)(QKV + rowbase + 768 + (size_t)nn * 1152 + d0);
#pragma unroll
    for (int j = 0; j < 8; j++) Vt[(d0 + j) * 228 + nn] = (u16)v[j];
  }
  for (int t = tid; t < 32 * 32; t += 256) {
    int d = t >> 5, jj = 196 + (t & 31);
    Vt[d * 228 + jj] = 0;
  }
  __syncthreads();

  for (int it = 0; it < 2; ++it) {
    int mtA = wv + it * 8;                 // always < 13 (wv<=3 -> <=11)
    bool vB = (mtA + 4) < 13;
    int mbx[2];
    mbx[0] = mtA * 16;
    mbx[1] = (vB ? (mtA + 4) : 12) * 16;   // clamp; discarded if !vB

    short8 afrag[2];
    int i0x[2], lutOff[2][4];
#pragma unroll
    for (int x = 0; x < 2; x++) {
      int irow = mbx[x] + c; if (irow > 195) irow = 195;
      afrag[x] = *(const short8*)(QKV + rowbase + (size_t)irow * 1152 + q * 8);
      i0x[x] = mbx[x] + q * 4;
#pragma unroll
      for (int e = 0; e < 4; e++) {
        int i = i0x[x] + e; if (i > 195) i = 195;
        lutOff[x][e] = i * 224;
      }
    }
    int rwOff[4];
#pragma unroll
    for (int e = 0; e < 4; e++) rwOff[e] = (q * 4 + e) * 50;

    // ---- rpe scores via MFMA -> Rw (table frags shared by both tiles) ----
#pragma unroll
    for (int nt = 0; nt < 4; nt++) {
      int t = nt * 16 + c;
      int tt = t < 49 ? t : 48;
      short8 tb = *(const short8*)&Ts[tt * 32 + q * 8];
#pragma unroll
      for (int x = 0; x < 2; x++) {
        f32x4 z = {0.f, 0.f, 0.f, 0.f};
        f32x4 rr = __builtin_amdgcn_mfma_f32_16x16x32_bf16(afrag[x], tb, z, 0, 0, 0);
        if (t < 49) {
#pragma unroll
          for (int e = 0; e < 4; e++)
            Rw4[wv][x][rwOff[e] + t] = f2bf(rr[e] * SCALE_Q);
        }
      }
    }
    if (c == 0) {
#pragma unroll
      for (int x = 0; x < 2; x++)
#pragma unroll
        for (int e = 0; e < 4; e++)
          Rw4[wv][x][rwOff[e] + 49] = 0xFF80;   // bf16 -inf
    }

    float mr[2] = {-INFINITY, -INFINITY};
    float l4[2][4] = {{0.f,0.f,0.f,0.f},{0.f,0.f,0.f,0.f}};
    f32x4 oacc[2][2];
#pragma unroll
    for (int x = 0; x < 2; x++) {
      oacc[x][0] = (f32x4){0.f, 0.f, 0.f, 0.f};
      oacc[x][1] = (f32x4){0.f, 0.f, 0.f, 0.f};
    }

    // ---- online softmax over 7 chunks of 32 j, two tiles interleaved ----
    for (int ck = 0; ck < 7; ck++) {
      // shared K fragments for both tiles
      short8 bfr[2];
#pragma unroll
      for (int t = 0; t < 2; t++) {
        int j = (ck * 2 + t) * 16 + c;
        int jc = j > 195 ? 195 : j;
        bfr[t] = *(const short8*)&Ks[(q * 196 + jc) * 8];
      }
      f32x4 s01[2][2];
#pragma unroll
      for (int x = 0; x < 2; x++) {
        f32x4 z = {0.f, 0.f, 0.f, 0.f};
        s01[x][0] = __builtin_amdgcn_mfma_f32_16x16x32_bf16(afrag[x], bfr[0], z, 0, 0, 0);
        s01[x][1] = __builtin_amdgcn_mfma_f32_16x16x32_bf16(afrag[x], bfr[1], z, 0, 0, 0);
      }
      // bucket LUT loads -> Rw gather (mask folded in via sentinel)
      uint8_t bk[2][2][4];
#pragma unroll
      for (int t = 0; t < 2; t++) {
        int jj = ck * 32 + t * 16 + c;
#pragma unroll
        for (int x = 0; x < 2; x++)
#pragma unroll
          for (int e = 0; e < 4; e++) bk[x][t][e] = lutG[lutOff[x][e] + jj];
      }
#pragma unroll
      for (int x = 0; x < 2; x++)
#pragma unroll
        for (int t = 0; t < 2; t++)
#pragma unroll
          for (int e = 0; e < 4; e++)
            s01[x][t][e] = s01[x][t][e] * SCALE_Q + bf2f(Rw4[wv][x][rwOff[e] + bk[x][t][e]]);

      // per-tile shared chunk max + online update + P store
#pragma unroll
      for (int x = 0; x < 2; x++) {
        float mc = s01[x][0][0];
#pragma unroll
        for (int t = 0; t < 2; t++)
#pragma unroll
          for (int e = 0; e < 4; e++) mc = fmaxf(mc, s01[x][t][e]);
#pragma unroll
        for (int o = 1; o < 16; o <<= 1) mc = fmaxf(mc, __shfl_xor(mc, o, 64));
        float mn = fmaxf(mr[x], mc);
        float sc = __expf(mr[x] - mn);
        mr[x] = mn;
#pragma unroll
        for (int t = 0; t < 2; t++)
#pragma unroll
          for (int e = 0; e < 4; e++) s01[x][t][e] = __expf(s01[x][t][e] - mn);
#pragma unroll
        for (int e = 0; e < 4; e++) {
          l4[x][e] = l4[x][e] * sc + s01[x][0][e] + s01[x][1][e];
          oacc[x][0][e] *= sc; oacc[x][1][e] *= sc;
        }
#pragma unroll
        for (int t = 0; t < 2; t++) {
          int sl2 = t * 2 + (c >> 3);
#pragma unroll
          for (int e = 0; e < 4; e++) {
            union { float f; uint32_t u; } pv; pv.f = s01[x][t][e];
            Pc4[wv][x][(sl2 * 16 + q * 4 + e) * 8 + (c & 7)] = (u16)(pv.u >> 16);
          }
        }
      }
      // PV: shared V fragment, 2 MFMAs per tile
#pragma unroll
      for (int n2 = 0; n2 < 2; n2++) {
        short8 vb = *(const short8*)&Vt[(n2 * 16 + c) * 228 + ck * 32 + q * 8];
#pragma unroll
        for (int x = 0; x < 2; x++) {
          short8 pa = *(const short8*)&Pc4[wv][x][(q * 16 + c) * 8];
          oacc[x][n2] = __builtin_amdgcn_mfma_f32_16x16x32_bf16(pa, vb, oacc[x][n2], 0, 0, 0);
        }
      }
    }

    // ---- final 1/l and store per tile ----
#pragma unroll
    for (int x = 0; x < 2; x++) {
      if (x == 1 && !vB) continue;
      float inv[4];
#pragma unroll
      for (int e = 0; e < 4; e++) {
        float s2 = l4[x][e];
#pragma unroll
        for (int o = 1; o < 16; o <<= 1) s2 += __shfl_xor(s2, o, 64);
        inv[e] = 1.f / s2;
      }
#pragma unroll
      for (int n2 = 0; n2 < 2; n2++) {
#pragma unroll
        for (int e = 0; e < 4; e++) {
          int i = i0x[x] + e;
          if (i < 196) {
            int d = n2 * 16 + c;
            AO[((size_t)b * NPOS + i) * DM + h * 32 + d] = f2bf(oacc[x][n2][e] * inv[e]);
          }
        }
      }
    }
  }
}

// ---------------------------------------------------------------------------
// x (B, CIN, HW, HW) f32  ->  A_t (B*NPOS, CIN) bf16
// ---------------------------------------------------------------------------
__global__ __launch_bounds__(256) void transpose_cast_k(
    const float* __restrict__ x, u16* __restrict__ At)
{
  __shared__ float t[32][33];
  int c0 = blockIdx.x * 32, n0 = blockIdx.y * 32, b = blockIdx.z;
  int tx = threadIdx.x, ty = threadIdx.y;
  const float* xb = x + (size_t)b * CIN * NPOS;
#pragma unroll
  for (int i = 0; i < 4; i++) {
    int cc = c0 + ty + i * 8, nn = n0 + tx;
    t[ty + i * 8][tx] = (nn < NPOS) ? xb[(size_t)cc * NPOS + nn] : 0.f;
  }
  __syncthreads();
  u16* Ab = At + (size_t)b * NPOS * CIN;
#pragma unroll
  for (int i = 0; i < 4; i++) {
    int nn = n0 + ty + i * 8, cc = c0 + tx;
    if (nn < NPOS) Ab[(size_t)nn * CIN + cc] = f2bf(t[tx][ty + i * 8]);
  }
}

// ---------------------------------------------------------------------------
// depthwise 3x3 SAME conv + bias + identity residual (fp32)
// ---------------------------------------------------------------------------
__global__ __launch_bounds__(256) void conv_res_k(
    const float* __restrict__ T0, const float* __restrict__ pcw,
    const float* __restrict__ pcb, float* __restrict__ T1)
{
  int idx = blockIdx.x * 256 + threadIdx.x;
  if (idx >= B_ * NPOS * 96) return;
  int d4 = idx % 96; int rem = idx / 96;
  int n = rem % NPOS; int b = rem / NPOS;
  int hh = n / 14, ww = n % 14;
  int d0 = d4 * 4;
  float w9[4][9];
#pragma unroll
  for (int j = 0; j < 4; j++)
#pragma unroll
    for (int t = 0; t < 9; t++) w9[j][t] = pcw[(d0 + j) * 9 + t];
  const float* base = T0 + (size_t)b * NPOS * DM;
  float4 ctr = *(const float4*)(base + (size_t)n * DM + d0);
  float ax = ctr.x + pcb[d0], ay = ctr.y + pcb[d0 + 1];
  float az = ctr.z + pcb[d0 + 2], aw = ctr.w + pcb[d0 + 3];
#pragma unroll
  for (int kh = 0; kh < 3; kh++) {
    int h2 = hh + kh - 1;
    if (h2 < 0 || h2 >= 14) continue;
#pragma unroll
    for (int kw = 0; kw < 3; kw++) {
      int w2 = ww + kw - 1;
      if (w2 < 0 || w2 >= 14) continue;
      float4 v = *(const float4*)(base + (size_t)(h2 * 14 + w2) * DM + d0);
      int t = kh * 3 + kw;
      ax += v.x * w9[0][t]; ay += v.y * w9[1][t];
      az += v.z * w9[2][t]; aw += v.w * w9[3][t];
    }
  }
  float4 o = {ax, ay, az, aw};
  *(float4*)(T1 + (size_t)b * NPOS * DM + (size_t)n * DM + d0) = o;
}

// ---------------------------------------------------------------------------
// LayerNorm(384) f32 -> bf16, one wave per row (float2-vectorized)
// ---------------------------------------------------------------------------
__global__ __launch_bounds__(256) void ln_k(
    const float* __restrict__ in, const float* __restrict__ w,
    const float* __restrict__ bb, u16* __restrict__ out)
{
  int row = blockIdx.x * 4 + (threadIdx.x >> 6);
  int ln = threadIdx.x & 63;
  const float2* r = (const float2*)(in + (size_t)row * DM);
  float2 v[3]; float s = 0.f, sq = 0.f;
#pragma unroll
  for (int j = 0; j < 3; j++) {
    v[j] = r[ln + 64 * j];
    s += v[j].x + v[j].y; sq += v[j].x * v[j].x + v[j].y * v[j].y;
  }
#pragma unroll
  for (int o = 1; o < 64; o <<= 1) { s += __shfl_xor(s, o, 64); sq += __shfl_xor(sq, o, 64); }
  float mu = s * (1.f / 384.f);
  float var = sq * (1.f / 384.f) - mu * mu;
  float rs = rsqrtf(var + 1e-5f);
  uint32_t* orow = (uint32_t*)(out + (size_t)row * DM);
#pragma unroll
  for (int j = 0; j < 3; j++) {
    int d = (ln + 64 * j) * 2;
    float a = (v[j].x - mu) * rs * w[d] + bb[d];
    float bq = (v[j].y - mu) * rs * w[d + 1] + bb[d + 1];
    orow[ln + 64 * j] = (uint32_t)f2bf(a) | ((uint32_t)f2bf(bq) << 16);
  }
}

// ---------------------------------------------------------------------------
// BN1 over (batch, dmodel) per position n: two-stage stats
// ---------------------------------------------------------------------------
__global__ __launch_bounds__(256) void bn1_partial_k(
    const float* __restrict__ T3, float* __restrict__ part)
{
  int n = blockIdx.x >> 3, g = blockIdx.x & 7;
  int tid = threadIdx.x;
  float s = 0.f, sq = 0.f;
  for (int b2 = g * 16; b2 < g * 16 + 16; b2++) {
    const float* p = T3 + ((size_t)b2 * NPOS + n) * DM;
    for (int d = tid; d < DM; d += 256) { float v = p[d]; s += v; sq += v * v; }
  }
#pragma unroll
  for (int o = 1; o < 64; o <<= 1) { s += __shfl_xor(s, o, 64); sq += __shfl_xor(sq, o, 64); }
  __shared__ float ls[4], lq[4];
  int wv = tid >> 6, ln = tid & 63;
  if (ln == 0) { ls[wv] = s; lq[wv] = sq; }
  __syncthreads();
  if (tid == 0) {
    part[blockIdx.x * 2]     = ls[0] + ls[1] + ls[2] + ls[3];
    part[blockIdx.x * 2 + 1] = lq[0] + lq[1] + lq[2] + lq[3];
  }
}

__global__ __launch_bounds__(256) void bn1_finish_k(
    const float* __restrict__ part, const float* __restrict__ bw,
    const float* __restrict__ bbb, float* __restrict__ scaleArr,
    float* __restrict__ shiftArr)
{
  int n = threadIdx.x;
  if (n >= NPOS) return;
  float S = 0.f, Q = 0.f;
#pragma unroll
  for (int g = 0; g < 8; g++) { S += part[(n * 8 + g) * 2]; Q += part[(n * 8 + g) * 2 + 1]; }
  float mu = S / 49152.f;
  float var = Q / 49152.f - mu * mu;
  float rs = rsqrtf(var + 2e-5f);
  float sc = rs * bw[n];
  scaleArr[n] = sc;
  shiftArr[n] = bbb[n] - mu * sc;
}

__global__ __launch_bounds__(256) void bn1_apply_k(
    const float* __restrict__ T3, const float* __restrict__ scaleArr,
    const float* __restrict__ shiftArr, u16* __restrict__ outb)
{
  int idx = blockIdx.x * 256 + threadIdx.x;           // float4 index
  if (idx >= MT * DM / 4) return;
  int n = (idx / 96) % NPOS;
  float4 v = *(const float4*)(T3 + (size_t)idx * 4);
  float sc = scaleArr[n], sh = shiftArr[n];
  uint32_t p0 = (uint32_t)f2bf(v.x * sc + sh) | ((uint32_t)f2bf(v.y * sc + sh) << 16);
  uint32_t p1 = (uint32_t)f2bf(v.z * sc + sh) | ((uint32_t)f2bf(v.w * sc + sh) << 16);
  ((uint2*)outb)[idx] = make_uint2(p0, p1);
}

// ---------------------------------------------------------------------------
// split-K reduce for lin head + bias
// ---------------------------------------------------------------------------
__global__ __launch_bounds__(256) void lin_reduce_k(
    const float* __restrict__ part, const float* __restrict__ lb,
    float* __restrict__ y)
{
  int idx = blockIdx.x * 256 + threadIdx.x;
  if (idx >= 128 * DM) return;
  int col = idx % DM;
  float s = lb[col];
#pragma unroll
  for (int sp = 0; sp < 49; sp++) s += part[(size_t)sp * (128 * DM) + idx];
  y[idx] = s;
}

// ---------------------------------------------------------------------------
// BN2 over batch (128) per feature col, in-place on y
// ---------------------------------------------------------------------------
__global__ __launch_bounds__(64) void bn2_k(
    float* __restrict__ y, const float* __restrict__ w,
    const float* __restrict__ bb)
{
  int col = blockIdx.x; int ln = threadIdx.x;
  float v0 = y[(size_t)ln * DM + col];
  float v1 = y[(size_t)(ln + 64) * DM + col];
  float s = v0 + v1, sq = v0 * v0 + v1 * v1;
#pragma unroll
  for (int o = 1; o < 64; o <<= 1) { s += __shfl_xor(s, o, 64); sq += __shfl_xor(sq, o, 64); }
  float mu = s / 128.f;
  float var = sq / 128.f - mu * mu;
  float rs = rsqrtf(var + 2e-5f);
  float sc = rs * w[col], sh = bb[col] - mu * sc;
  y[(size_t)ln * DM + col] = v0 * sc + sh;
  y[(size_t)(ln + 64) * DM + col] = v1 * sc + sh;
}

// ---------------------------------------------------------------------------
// merged f32 -> bf16 cast for the six small weight matrices
// ---------------------------------------------------------------------------
__global__ __launch_bounds__(256) void castall_k(
    const float* __restrict__ s0, u16* __restrict__ d0,
    const float* __restrict__ s1, u16* __restrict__ d1,
    const float* __restrict__ s2, u16* __restrict__ d2,
    const float* __restrict__ s3, u16* __restrict__ d3,
    const float* __restrict__ s4, u16* __restrict__ d4,
    const float* __restrict__ s5, u16* __restrict__ d5)
{
  const int b0 = 262144, b1 = b0 + 98304, b2 = b1 + 110592,
            b3 = b2 + 36864, b4 = b3 + 147456, b5 = b4 + 147456; // 802816
  int idx = blockIdx.x * 256 + threadIdx.x;
  int stride = gridDim.x * 256;
  for (; idx < b5; idx += stride) {
    const float* s; u16* d; int l;
    if      (idx < b0) { s = s0; d = d0; l = idx; }
    else if (idx < b1) { s = s1; d = d1; l = idx - b0; }
    else if (idx < b2) { s = s2; d = d2; l = idx - b1; }
    else if (idx < b3) { s = s3; d = d3; l = idx - b2; }
    else if (idx < b4) { s = s4; d = d4; l = idx - b3; }
    else               { s = s5; d = d5; l = idx - b4; }
    float4 v = *(const float4*)(s + (size_t)l * 4);
    uint32_t p0 = (uint32_t)f2bf(v.x) | ((uint32_t)f2bf(v.y) << 16);
    uint32_t p1 = (uint32_t)f2bf(v.z) | ((uint32_t)f2bf(v.w) << 16);
    ((uint2*)d)[l] = make_uint2(p0, p1);
  }
}

// ---------------------------------------------------------------------------
// Orchestration
// ---------------------------------------------------------------------------
extern "C" void kernel_launch(void* const* d_in, const int* in_sizes, int n_in,
                              void* d_out, int out_size, void* d_ws, size_t ws_size,
                              hipStream_t stream)
{
  (void)in_sizes; (void)n_in; (void)out_size;
  const float* x    = (const float*)d_in[0];
  const float* fc1w = (const float*)d_in[1];
  const float* fc1b = (const float*)d_in[2];
  const float* fc2w = (const float*)d_in[3];
  const float* fc2b = (const float*)d_in[4];
  const float* pcw  = (const float*)d_in[5];
  const float* pcb  = (const float*)d_in[6];
  const float* ln1w = (const float*)d_in[7];
  const float* ln1b = (const float*)d_in[8];
  const float* qkvw = (const float*)d_in[9];
  const float* rpet = (const float*)d_in[10];
  const float* projw= (const float*)d_in[11];
  const float* projb= (const float*)d_in[12];
  const float* ln2w = (const float*)d_in[13];
  const float* ln2b = (const float*)d_in[14];
  const float* m1w  = (const float*)d_in[15];
  const float* m1b  = (const float*)d_in[16];
  const float* m2w  = (const float*)d_in[17];
  const float* m2b  = (const float*)d_in[18];
  const float* bn1w = (const float*)d_in[19];
  const float* bn1b = (const float*)d_in[20];
  const float* linw = (const float*)d_in[21];
  const float* linb = (const float*)d_in[22];
  const float* bn2w = (const float*)d_in[23];
  const float* bn2b = (const float*)d_in[24];
  float* y = (float*)d_out;

  // -------- aliased workspace layout (regions share by liveness) ----------
  const size_t RA = 0;                      // At / MLP1
  const size_t RB = 77070336;               // U / QKV / T3nb
  const size_t RC = RB + 57802752;          // H / AO / H2
  const size_t RD = RC + 19267584;          // T0 / T2
  const size_t RE = RD + 38535168;          // T1 / T3
  const size_t RF = RE + 38535168;          // PART (lin split-K)
  const size_t RG = RF + 9633792;           // small bf16 weights
  const size_t RS = RG + 6422528;           // bn1 scale/shift + partials + lut
  const size_t NEED = RS + 2048 + 16384 + 45056;
  if (ws_size < NEED) return;

  char* ws = (char*)d_ws;
  u16*   At    = (u16*)(ws + RA);
  u16*   MLP1  = (u16*)(ws + RA);
  u16*   U     = (u16*)(ws + RB);
  u16*   QKV   = (u16*)(ws + RB);
  u16*   T3nb  = (u16*)(ws + RB);
  u16*   H     = (u16*)(ws + RC);
  u16*   AO    = (u16*)(ws + RC);
  u16*   H2    = (u16*)(ws + RC);
  float* T0    = (float*)(ws + RD);
  float* T2    = (float*)(ws + RD);
  float* T1    = (float*)(ws + RE);
  float* T3    = (float*)(ws + RE);
  float* PART  = (float*)(ws + RF);
  u16*   wb_fc1 = (u16*)(ws + RG);
  u16*   wb_fc2 = wb_fc1 + 1048576;
  u16*   wb_qkv = wb_fc2 + 393216;
  u16*   wb_proj= wb_qkv + 442368;
  u16*   wb_m1  = wb_proj + 147456;
  u16*   wb_m2  = wb_m1 + 589824;
  float* bnS   = (float*)(ws + RS);
  float* bnSh  = bnS + 196;
  float* bnP   = (float*)(ws + RS + 2048);
  uint8_t* blut = (uint8_t*)(ws + RS + 2048 + 16384);

  // weight casts (f32 -> bf16), one merged kernel + bucket LUT
  castall_k<<<1024, 256, 0, stream>>>(fc1w, wb_fc1, fc2w, wb_fc2, qkvw, wb_qkv,
                                      projw, wb_proj, m1w, wb_m1, m2w, wb_m2);
  blut_k<<<196, 224, 0, stream>>>(blut);

  // x (B,CIN,N) -> At (B*N, CIN) bf16
  transpose_cast_k<<<dim3(32, 7, 128), dim3(32, 8), 0, stream>>>(x, At);

  // embed fc1: U = relu6(At @ fc1w^T + b)   [25088 x 1024]
  gemm_k<0><<<196 * 8, 256, 0, stream>>>(At, wb_fc1, fc1b, nullptr, U,
                                          MT, 1024, 1024, 1024, 1024, 8, 0);
  // embed fc2: T0 = U @ fc2w^T + b          [25088 x 384] f32
  gemm_k<1><<<196 * 3, 256, 0, stream>>>(U, wb_fc2, fc2b, nullptr, T0,
                                          MT, 384, 1024, 1024, 1024, 3, 0);
  // depthwise conv + bias + residual -> T1
  conv_res_k<<<(B_ * NPOS * 96 + 255) / 256, 256, 0, stream>>>(T0, pcw, pcb, T1);
  // LN1 -> H (bf16)
  ln_k<<<MT / 4, 256, 0, stream>>>(T1, ln1w, ln1b, H);
  // qkv: QKV = H @ qkvw^T (no bias)          [25088 x 1152] bf16
  gemm_k<2><<<196 * 9, 256, 0, stream>>>(H, wb_qkv, nullptr, nullptr, QKV,
                                          MT, 1152, 384, 384, 384, 9, 0);
  // fused attention (rpe in-kernel, flash-style, LUT bias, 2-tile ILP) -> AO
  attn_k<<<1536, 256, 0, stream>>>(QKV, rpet, blut, AO);
  // proj + residual(T1) -> T2 (f32)
  gemm_k<3><<<196 * 3, 256, 0, stream>>>(AO, wb_proj, projb, T1, T2,
                                          MT, 384, 384, 384, 384, 3, 0);
  // LN2 -> H2 (bf16)
  ln_k<<<MT / 4, 256, 0, stream>>>(T2, ln2w, ln2b, H2);
  // mlp fc1: MLP1 = relu6(H2 @ m1w^T + b)    [25088 x 1536] bf16
  gemm_k<0><<<196 * 12, 256, 0, stream>>>(H2, wb_m1, m1b, nullptr, MLP1,
                                           MT, 1536, 384, 384, 384, 12, 0);
  // mlp fc2 + residual(T2) -> T3 (f32)
  gemm_k<3><<<196 * 3, 256, 0, stream>>>(MLP1, wb_m2, m2b, T2, T3,
                                          MT, 384, 1536, 1536, 1536, 3, 0);
  // BN1 (per position) -> T3nb (bf16)
  bn1_partial_k<<<196 * 8, 256, 0, stream>>>(T3, bnP);
  bn1_finish_k<<<1, 256, 0, stream>>>(bnP, bn1w, bn1b, bnS, bnSh);
  bn1_apply_k<<<(MT * DM / 4 + 255) / 256, 256, 0, stream>>>(T3, bnS, bnSh, T3nb);
  // lin head: y = T3nb(128 x 75264) @ linw^T, split-K 49 x 1536 (W f32 direct)
  gemm_k<4><<<3 * 49, 256, 0, stream>>>(T3nb, linw, nullptr, nullptr, PART,
                                         128, 384, 1536, 75264, 75264, 3, 1536);
  lin_reduce_k<<<192, 256, 0, stream>>>(PART, linb, y);
  // BN2 (per feature over batch), in place on d_out
  bn2_k<<<384, 64, 0, stream>>>(y, bn2w, bn2b);
}